// Round 11
// baseline (491.878 us; speedup 1.0000x reference)
//
#include <hip/hip_runtime.h>
#include <hip/hip_bf16.h>
#include <math.h>

// Problem dims
#define SDIM 256
#define HDIM 768
#define EDIM 1536
#define NDIM 16
#define KCONV 4
#define RDIM 48
#define NLAYER 2
#define LSEQ 1024

#define NCHUNK 64
#define CHLEN (LSEQ / NCHUNK)   // 16
#define KSPLIT 8
#define KCH (EDIM / KSPLIT)     // 192

typedef __hip_bfloat16 bf16;
typedef __attribute__((ext_vector_type(8))) short short8;
typedef __attribute__((ext_vector_type(4))) float f32x4;

__device__ __forceinline__ float softplusf(float x) {
    return (x > 20.f) ? x : log1pf(expf(x));
}
__device__ __forceinline__ float siluf(float x) {
    return x / (1.f + expf(-x));
}

// ---------------- combined fp32 -> bf16 conversion: 5 segments, one launch ----------------
struct F2BSegs {
    const float* src[5];
    bf16*        dst[5];
    int          n[5];      // element counts (each % 4 == 0)
};

__global__ __launch_bounds__(256) void f2b_all(F2BSegs segs)
{
    for (int s = 0; s < 5; s++) {
        const float* __restrict__ in = segs.src[s];
        bf16* __restrict__ out = segs.dst[s];
        const int n = segs.n[s];
        for (int i = (blockIdx.x * 256 + threadIdx.x) * 4; i < n; i += gridDim.x * 256 * 4) {
            float4 v = *(const float4*)(in + i);
            out[i + 0] = (bf16)v.x; out[i + 1] = (bf16)v.y;
            out[i + 2] = (bf16)v.z; out[i + 3] = (bf16)v.w;
        }
    }
}

// ---------------- MFMA bf16 GEMM 64x64 tile ----------------
__global__ __launch_bounds__(256) void k_gemm(const bf16* __restrict__ A, int lda,
                                              const bf16* __restrict__ W, int ldw,
                                              const float* __restrict__ bias,
                                              float* __restrict__ out, bf16* __restrict__ outb,
                                              int N, int Kd, int useBias, int useOutb)
{
    __shared__ __align__(16) short As[64][72];   // +8 pad: 2-way bank alias only (free, m136)
    __shared__ __align__(16) short Ws[64][72];

    const int tid  = threadIdx.x;
    const int lane = tid & 63, wid = tid >> 6;
    const int wm = wid >> 1, wn = wid & 1;
    const int row0 = blockIdx.y * 64, col0 = blockIdx.x * 64;
    const int quad = lane >> 4, l16 = lane & 15;

    f32x4 acc[2][2] = {};
    for (int k0 = 0; k0 < Kd; k0 += 64) {
        #pragma unroll
        for (int i = 0; i < 2; i++) {
            int id = tid + i * 256;
            int r = id >> 3, g = id & 7;
            *(uint4*)&As[r][g * 8] = *(const uint4*)(A + (size_t)(row0 + r) * lda + k0 + g * 8);
            *(uint4*)&Ws[r][g * 8] = *(const uint4*)(W + (size_t)(col0 + r) * ldw + k0 + g * 8);
        }
        __syncthreads();
        #pragma unroll
        for (int ks = 0; ks < 64; ks += 32) {
            short8 af[2], bfr[2];
            #pragma unroll
            for (int i = 0; i < 2; i++) af[i] = *(const short8*)&As[wm * 32 + i * 16 + l16][ks + quad * 8];
            #pragma unroll
            for (int j = 0; j < 2; j++) bfr[j] = *(const short8*)&Ws[wn * 32 + j * 16 + l16][ks + quad * 8];
            #pragma unroll
            for (int i = 0; i < 2; i++)
                #pragma unroll
                for (int j = 0; j < 2; j++)
                    acc[i][j] = __builtin_amdgcn_mfma_f32_16x16x32_bf16(af[i], bfr[j], acc[i][j], 0, 0, 0);
        }
        __syncthreads();
    }
    // C layout: col = lane&15, row = quad*4 + reg
    #pragma unroll
    for (int i = 0; i < 2; i++) {
        #pragma unroll
        for (int j = 0; j < 2; j++) {
            int gn = col0 + wn * 32 + j * 16 + l16;
            int gm0 = row0 + wm * 32 + i * 16 + quad * 4;
            #pragma unroll
            for (int r = 0; r < 4; r++) {
                float v = acc[i][j][r];
                if (useBias) v += bias[gn];
                size_t o = (size_t)(gm0 + r) * N + gn;
                out[o] = v;
                if (useOutb) outb[o] = (bf16)v;
            }
        }
    }
}

// ---------------- xproj fused with conv+silu ----------------
// grid (2, 16, KSPLIT). A-tile = u rows computed on the fly from xz;
// bx==0 blocks also write u to global (each (by,bz) covers a distinct 64x192 slice).
__global__ __launch_bounds__(256) void k_xproj_conv(
    const float* __restrict__ xz, const float* __restrict__ cw,
    const float* __restrict__ cb, float* __restrict__ u,
    const float* __restrict__ xw, float* __restrict__ part)
{
    __shared__ float AsF[16][68];
    __shared__ float WsF[16][68];
    const int tid = threadIdx.x;
    const int tx = tid & 15, ty = tid >> 4;
    const int tx4 = tx * 4, ty4 = ty * 4;
    const int row0 = blockIdx.y * 64, col0 = blockIdx.x * 64;
    const int kbase = blockIdx.z * KCH;
    const bool writeU = (blockIdx.x == 0);

    float acc[4][4] = {};
    for (int k0 = 0; k0 < KCH; k0 += 16) {
        // stage A = u[row0:+64][kbase+k0:+16], computing conv+silu on the fly
        #pragma unroll
        for (int i = 0; i < 4; i++) {
            int idx = tid + i * 256;
            int m = idx >> 4, kk = idx & 15;
            int t = row0 + m;
            int e = kbase + k0 + kk;
            float s = cb[e];
            #pragma unroll
            for (int j = 0; j < KCONV; j++) {
                int tt = t - (KCONV - 1) + j;
                if (tt >= 0) s += cw[e * KCONV + j] * xz[(size_t)tt * (2 * EDIM) + e];
            }
            float uv = siluf(s);
            AsF[kk][m] = uv;
            if (writeU) u[(size_t)t * EDIM + e] = uv;
        }
        #pragma unroll
        for (int i = 0; i < 4; i++) {
            int idx = tid + i * 256;
            int nn = idx >> 4, kk = idx & 15;
            int gn = col0 + nn;
            WsF[kk][nn] = (gn < 80) ? xw[(size_t)gn * EDIM + kbase + k0 + kk] : 0.f;
        }
        __syncthreads();
        #pragma unroll
        for (int kk = 0; kk < 16; kk++) {
            float av[4], bv[4];
            #pragma unroll
            for (int i = 0; i < 4; i++) av[i] = AsF[kk][ty4 + i];
            #pragma unroll
            for (int j = 0; j < 4; j++) bv[j] = WsF[kk][tx4 + j];
            #pragma unroll
            for (int i = 0; i < 4; i++)
                #pragma unroll
                for (int j = 0; j < 4; j++)
                    acc[i][j] += av[i] * bv[j];
        }
        __syncthreads();
    }

    float* pdst = part + (size_t)blockIdx.z * (LSEQ * 80);
    #pragma unroll
    for (int i = 0; i < 4; i++) {
        int gm = row0 + ty4 + i;
        #pragma unroll
        for (int j = 0; j < 4; j++) {
            int gn = col0 + tx4 + j;
            if (gn < 80) pdst[(size_t)gm * 80 + gn] = acc[i][j];
        }
    }
}

// ---------------- dt GEMM fused with split-K reduce ----------------
// grid (24, 16). A-tile = sum of 8 partials of dbc[:, :48] (reduced during staging).
// bx==0 blocks also reduce+write dbc[:, 48:80] (B/C) to global for the scans.
__global__ __launch_bounds__(256) void k_dt_red(
    const float* __restrict__ part, const float* __restrict__ dtw,
    const float* __restrict__ dtbb, float* __restrict__ out,
    float* __restrict__ dbc)
{
    __shared__ float AsF[16][68];
    __shared__ float WsF[16][68];
    const int tid = threadIdx.x;
    const int tx = tid & 15, ty = tid >> 4;
    const int tx4 = tx * 4, ty4 = ty * 4;
    const int row0 = blockIdx.y * 64, col0 = blockIdx.x * 64;

    // bx==0: reduce + write B/C columns (48..79) for this block's 64 rows
    if (blockIdx.x == 0) {
        for (int idx = tid; idx < 64 * 32; idx += 256) {
            int m = idx >> 5, c = 48 + (idx & 31);
            size_t o = (size_t)(row0 + m) * 80 + c;
            float s = 0.f;
            #pragma unroll
            for (int p = 0; p < KSPLIT; p++) s += part[(size_t)p * (LSEQ * 80) + o];
            dbc[o] = s;
        }
    }

    float acc[4][4] = {};
    for (int k0 = 0; k0 < RDIM; k0 += 16) {
        #pragma unroll
        for (int i = 0; i < 4; i++) {
            int idx = tid + i * 256;
            int m = idx >> 4, kk = idx & 15;
            size_t o = (size_t)(row0 + m) * 80 + k0 + kk;
            float s = 0.f;
            #pragma unroll
            for (int p = 0; p < KSPLIT; p++) s += part[(size_t)p * (LSEQ * 80) + o];
            AsF[kk][m] = s;
        }
        #pragma unroll
        for (int i = 0; i < 4; i++) {
            int idx = tid + i * 256;
            int nn = idx >> 4, kk = idx & 15;
            WsF[kk][nn] = dtw[(size_t)(col0 + nn) * RDIM + k0 + kk];
        }
        __syncthreads();
        #pragma unroll
        for (int kk = 0; kk < 16; kk++) {
            float av[4], bv[4];
            #pragma unroll
            for (int i = 0; i < 4; i++) av[i] = AsF[kk][ty4 + i];
            #pragma unroll
            for (int j = 0; j < 4; j++) bv[j] = WsF[kk][tx4 + j];
            #pragma unroll
            for (int i = 0; i < 4; i++)
                #pragma unroll
                for (int j = 0; j < 4; j++)
                    acc[i][j] += av[i] * bv[j];
        }
        __syncthreads();
    }
    #pragma unroll
    for (int i = 0; i < 4; i++) {
        int gm = row0 + ty4 + i;
        #pragma unroll
        for (int j = 0; j < 4; j++) {
            int gn = col0 + tx4 + j;
            float v = acc[i][j] + dtbb[gn];
            out[(size_t)gm * EDIM + gn] = softplusf(v);
        }
    }
}

// ---------------- residual + rmsnorm ----------------
__global__ __launch_bounds__(256) void k_rms(const float* __restrict__ h, float* __restrict__ res,
                                             bf16* __restrict__ hnb, const float* __restrict__ w,
                                             int first)
{
    __shared__ float red[4];
    __shared__ float tot;
    const int tid = threadIdx.x;
    const int t = blockIdx.x;
    float v[3]; float ss = 0.f;
    #pragma unroll
    for (int r = 0; r < 3; r++) {
        int j = tid + r * 256;
        float xv = h[(size_t)t * HDIM + j];
        if (!first) xv += res[(size_t)t * HDIM + j];
        v[r] = xv;
        res[(size_t)t * HDIM + j] = xv;
        ss += xv * xv;
    }
    #pragma unroll
    for (int m = 32; m >= 1; m >>= 1) ss += __shfl_down(ss, m);
    int wid = tid >> 6;
    if ((tid & 63) == 0) red[wid] = ss;
    __syncthreads();
    if (tid == 0) tot = red[0] + red[1] + red[2] + red[3];
    __syncthreads();
    float scale = rsqrtf(tot / (float)HDIM + 1e-5f);
    #pragma unroll
    for (int r = 0; r < 3; r++) {
        int j = tid + r * 256;
        hnb[(size_t)t * HDIM + j] = (bf16)(v[r] * scale * w[j]);
    }
}

// ---------------- selective scan (thread per e, 16 states in regs) ----------------
__global__ __launch_bounds__(256) void k_scan1(const float* __restrict__ dt,
                                               const float* __restrict__ u,
                                               const float* __restrict__ dbc,
                                               const float* __restrict__ a_log,
                                               float* __restrict__ chunkS,
                                               float* __restrict__ sumdt)
{
    const int ex = blockIdx.x % 6, c = blockIdx.x / 6;
    const int e = ex * 256 + threadIdx.x;
    float A[16];
    #pragma unroll
    for (int q = 0; q < 4; q++) {
        float4 a4 = *(const float4*)(a_log + e * NDIM + q * 4);
        A[q*4+0] = -__expf(a4.x); A[q*4+1] = -__expf(a4.y);
        A[q*4+2] = -__expf(a4.z); A[q*4+3] = -__expf(a4.w);
    }
    float s[16] = {};
    float sd = 0.f;
    const int t0 = c * CHLEN;
    for (int t = t0; t < t0 + CHLEN; t++) {
        float dtv = dt[(size_t)t * EDIM + e];
        float uv  = u[(size_t)t * EDIM + e];
        float dtu = dtv * uv;
        sd += dtv;
        float4 B4[4];
        #pragma unroll
        for (int q = 0; q < 4; q++) B4[q] = *(const float4*)(dbc + (size_t)t * 80 + RDIM + q * 4);
        const float* B = (const float*)B4;
        #pragma unroll
        for (int n = 0; n < 16; n++) s[n] = s[n] * __expf(dtv * A[n]) + dtu * B[n];
    }
    float* cs = chunkS + ((size_t)c * EDIM + e) * NDIM;
    #pragma unroll
    for (int q = 0; q < 4; q++)
        *(float4*)(cs + q * 4) = make_float4(s[q*4+0], s[q*4+1], s[q*4+2], s[q*4+3]);
    sumdt[(size_t)c * EDIM + e] = sd;
}

__global__ __launch_bounds__(256) void k_scan2(const float* __restrict__ chunkS,
                                               const float* __restrict__ sumdt,
                                               const float* __restrict__ a_log,
                                               float* __restrict__ sInit)
{
    int gid = blockIdx.x * 256 + threadIdx.x;
    if (gid >= EDIM * NDIM) return;
    int n = gid & 15, e = gid >> 4;
    const float Aen = -__expf(a_log[gid]);
    float s = 0.f;
    for (int c = 0; c < NCHUNK; c++) {
        sInit[((size_t)c * EDIM + e) * NDIM + n] = s;
        float P = __expf(Aen * sumdt[(size_t)c * EDIM + e]);
        s = s * P + chunkS[((size_t)c * EDIM + e) * NDIM + n];
    }
}

__global__ __launch_bounds__(256) void k_scan3(const float* __restrict__ dt,
                                               const float* __restrict__ u,
                                               const float* __restrict__ dbc,
                                               const float* __restrict__ xz,
                                               const float* __restrict__ a_log,
                                               const float* __restrict__ Dp,
                                               const float* __restrict__ sInit,
                                               bf16* __restrict__ yzb)
{
    const int ex = blockIdx.x % 6, c = blockIdx.x / 6;
    const int e = ex * 256 + threadIdx.x;
    float A[16];
    #pragma unroll
    for (int q = 0; q < 4; q++) {
        float4 a4 = *(const float4*)(a_log + e * NDIM + q * 4);
        A[q*4+0] = -__expf(a4.x); A[q*4+1] = -__expf(a4.y);
        A[q*4+2] = -__expf(a4.z); A[q*4+3] = -__expf(a4.w);
    }
    const float dv = Dp[e];
    float s[16];
    const float* si = sInit + ((size_t)c * EDIM + e) * NDIM;
    #pragma unroll
    for (int q = 0; q < 4; q++) {
        float4 s4 = *(const float4*)(si + q * 4);
        s[q*4+0] = s4.x; s[q*4+1] = s4.y; s[q*4+2] = s4.z; s[q*4+3] = s4.w;
    }
    const int t0 = c * CHLEN;
    for (int t = t0; t < t0 + CHLEN; t++) {
        float dtv = dt[(size_t)t * EDIM + e];
        float uv  = u[(size_t)t * EDIM + e];
        float zv  = xz[(size_t)t * (2 * EDIM) + EDIM + e];
        float dtu = dtv * uv;
        float4 B4[4], C4[4];
        #pragma unroll
        for (int q = 0; q < 4; q++) {
            B4[q] = *(const float4*)(dbc + (size_t)t * 80 + RDIM + q * 4);
            C4[q] = *(const float4*)(dbc + (size_t)t * 80 + RDIM + NDIM + q * 4);
        }
        const float* B = (const float*)B4;
        const float* C = (const float*)C4;
        float y = 0.f;
        #pragma unroll
        for (int n = 0; n < 16; n++) {
            s[n] = s[n] * __expf(dtv * A[n]) + dtu * B[n];
            y += s[n] * C[n];
        }
        y += uv * dv;
        yzb[(size_t)t * EDIM + e] = (bf16)(y * siluf(zv));
    }
}

extern "C" void kernel_launch(void* const* d_in, const int* in_sizes, int n_in,
                              void* d_out, int out_size, void* d_ws, size_t ws_size,
                              hipStream_t stream)
{
    const float* x        = (const float*)d_in[0];
    const float* emb_w    = (const float*)d_in[1];
    const float* emb_b    = (const float*)d_in[2];
    const float* norm_w   = (const float*)d_in[3];
    const float* in_proj  = (const float*)d_in[4];
    const float* conv_w   = (const float*)d_in[5];
    const float* conv_b   = (const float*)d_in[6];
    const float* x_proj   = (const float*)d_in[7];
    const float* dt_w     = (const float*)d_in[8];
    const float* dt_b     = (const float*)d_in[9];
    const float* A_log    = (const float*)d_in[10];
    const float* Dp       = (const float*)d_in[11];
    const float* out_proj = (const float*)d_in[12];
    const float* head_w   = (const float*)d_in[13];
    const float* head_b   = (const float*)d_in[14];
    float* out = (float*)d_out;

    float* ws = (float*)d_ws;
    size_t off = 0;
    float* h      = ws + off; off += (size_t)LSEQ * HDIM;
    float* res    = ws + off; off += (size_t)LSEQ * HDIM;
    float* xz     = ws + off; off += (size_t)LSEQ * 2 * EDIM;
    float* u      = ws + off; off += (size_t)LSEQ * EDIM;
    float* dbc    = ws + off; off += (size_t)LSEQ * 80;
    float* part   = ws + off; off += (size_t)KSPLIT * LSEQ * 80;
    float* dtb    = ws + off; off += (size_t)LSEQ * EDIM;
    float* chunkS = ws + off; off += (size_t)NCHUNK * EDIM * NDIM;
    float* sumdt  = ws + off; off += (size_t)NCHUNK * EDIM;
    float* sInit  = ws + off; off += (size_t)NCHUNK * EDIM * NDIM;
    bf16* hnb     = (bf16*)(ws + off); off += (size_t)LSEQ * HDIM / 2;
    bf16* yzb     = (bf16*)(ws + off); off += (size_t)LSEQ * EDIM / 2;
    bf16* hb      = (bf16*)(ws + off); off += (size_t)LSEQ * HDIM / 2;
    bf16* xb      = (bf16*)(ws + off); off += (size_t)LSEQ * SDIM / 2;
    bf16* emb_wb  = (bf16*)(ws + off); off += (size_t)HDIM * SDIM / 2;
    bf16* head_wb = (bf16*)(ws + off); off += (size_t)SDIM * HDIM / 2;
    bf16* in_wb   = (bf16*)(ws + off); off += (size_t)NLAYER * 2 * EDIM * HDIM / 2;
    bf16* out_wb  = (bf16*)(ws + off); off += (size_t)NLAYER * HDIM * EDIM / 2;

    // one launch: all fp32->bf16 conversions (x + all weights, both layers)
    F2BSegs segs;
    segs.src[0] = x;        segs.dst[0] = xb;      segs.n[0] = LSEQ * SDIM;
    segs.src[1] = emb_w;    segs.dst[1] = emb_wb;  segs.n[1] = HDIM * SDIM;
    segs.src[2] = head_w;   segs.dst[2] = head_wb; segs.n[2] = SDIM * HDIM;
    segs.src[3] = in_proj;  segs.dst[3] = in_wb;   segs.n[3] = NLAYER * 2 * EDIM * HDIM;
    segs.src[4] = out_proj; segs.dst[4] = out_wb;  segs.n[4] = NLAYER * HDIM * EDIM;
    f2b_all<<<1024, 256, 0, stream>>>(segs);

    // embed: h = x @ emb_w^T + emb_b  (N=768, K=256)
    k_gemm<<<dim3(12, 16), 256, 0, stream>>>(xb, SDIM, emb_wb, SDIM, emb_b,
                                             h, nullptr, HDIM, SDIM, 1, 0);

    for (int l = 0; l < NLAYER; l++) {
        const bf16*  inw  = in_wb  + (size_t)l * 2 * EDIM * HDIM;
        const bf16*  outw = out_wb + (size_t)l * HDIM * EDIM;
        const float* cw   = conv_w + (size_t)l * EDIM * KCONV;
        const float* cb   = conv_b + (size_t)l * EDIM;
        const float* xw   = x_proj + (size_t)l * 80 * EDIM;
        const float* dtw  = dt_w   + (size_t)l * EDIM * RDIM;
        const float* dtbb = dt_b   + (size_t)l * EDIM;
        const float* al   = A_log  + (size_t)l * EDIM * NDIM;
        const float* Dpl  = Dp     + (size_t)l * EDIM;

        k_rms<<<LSEQ, 256, 0, stream>>>(h, res, hnb, norm_w + (size_t)l * HDIM, l == 0);
        k_gemm<<<dim3(48, 16), 256, 0, stream>>>(hnb, HDIM, inw, HDIM, nullptr,
                                                 xz, nullptr, 2 * EDIM, HDIM, 0, 0);
        // conv+silu fused into xproj staging; bx==0 writes u
        k_xproj_conv<<<dim3(2, 16, KSPLIT), 256, 0, stream>>>(xz, cw, cb, u, xw, part);
        // split-K reduce fused into dt staging; bx==0 writes dbc[:,48:80]
        k_dt_red<<<dim3(24, 16), 256, 0, stream>>>(part, dtw, dtbb, dtb, dbc);
        k_scan1<<<6 * NCHUNK, 256, 0, stream>>>(dtb, u, dbc, al, chunkS, sumdt);
        k_scan2<<<96, 256, 0, stream>>>(chunkS, sumdt, al, sInit);
        k_scan3<<<6 * NCHUNK, 256, 0, stream>>>(dtb, u, dbc, xz, al, Dpl, sInit, yzb);
        k_gemm<<<dim3(12, 16), 256, 0, stream>>>(yzb, EDIM, outw, EDIM, nullptr,
                                                 h, hb, HDIM, EDIM, 0, (l == NLAYER - 1) ? 1 : 0);
    }

    // head: out = h @ head_w^T + head_b  (N=256, K=768)
    k_gemm<<<dim3(4, 16), 256, 0, stream>>>(hb, HDIM, head_wb, HDIM, head_b,
                                            out, nullptr, SDIM, HDIM, 1, 0);
}

// Round 12
// 433.186 us; speedup vs baseline: 1.1355x; 1.1355x over previous
//
#include <hip/hip_runtime.h>
#include <hip/hip_bf16.h>
#include <math.h>

// Problem dims
#define SDIM 256
#define HDIM 768
#define EDIM 1536
#define NDIM 16
#define KCONV 4
#define RDIM 48
#define NLAYER 2
#define LSEQ 1024

#define NCHUNK 128
#define CHLEN (LSEQ / NCHUNK)   // 8
#define KSPLIT 8
#define KCH (EDIM / KSPLIT)     // 192

typedef __hip_bfloat16 bf16;
typedef __attribute__((ext_vector_type(8))) short short8;
typedef __attribute__((ext_vector_type(4))) float f32x4;

__device__ __forceinline__ float softplusf(float x) {
    return (x > 20.f) ? x : log1pf(expf(x));
}
__device__ __forceinline__ float siluf(float x) {
    return x / (1.f + expf(-x));
}

// ---------------- combined fp32 -> bf16 conversion: 5 segments, one launch ----------------
struct F2BSegs {
    const float* src[5];
    bf16*        dst[5];
    int          n[5];      // element counts (each % 4 == 0)
};

__global__ __launch_bounds__(256) void f2b_all(F2BSegs segs)
{
    for (int s = 0; s < 5; s++) {
        const float* __restrict__ in = segs.src[s];
        bf16* __restrict__ out = segs.dst[s];
        const int n = segs.n[s];
        for (int i = (blockIdx.x * 256 + threadIdx.x) * 4; i < n; i += gridDim.x * 256 * 4) {
            float4 v = *(const float4*)(in + i);
            out[i + 0] = (bf16)v.x; out[i + 1] = (bf16)v.y;
            out[i + 2] = (bf16)v.z; out[i + 3] = (bf16)v.w;
        }
    }
}

// ---------------- MFMA bf16 GEMM 64x64 tile ----------------
__global__ __launch_bounds__(256) void k_gemm(const bf16* __restrict__ A, int lda,
                                              const bf16* __restrict__ W, int ldw,
                                              const float* __restrict__ bias,
                                              float* __restrict__ out, bf16* __restrict__ outb,
                                              int N, int Kd, int useBias, int useOutb)
{
    __shared__ __align__(16) short As[64][72];   // +8 pad: 2-way bank alias only (free, m136)
    __shared__ __align__(16) short Ws[64][72];

    const int tid  = threadIdx.x;
    const int lane = tid & 63, wid = tid >> 6;
    const int wm = wid >> 1, wn = wid & 1;
    const int row0 = blockIdx.y * 64, col0 = blockIdx.x * 64;
    const int quad = lane >> 4, l16 = lane & 15;

    f32x4 acc[2][2] = {};
    for (int k0 = 0; k0 < Kd; k0 += 64) {
        #pragma unroll
        for (int i = 0; i < 2; i++) {
            int id = tid + i * 256;
            int r = id >> 3, g = id & 7;
            *(uint4*)&As[r][g * 8] = *(const uint4*)(A + (size_t)(row0 + r) * lda + k0 + g * 8);
            *(uint4*)&Ws[r][g * 8] = *(const uint4*)(W + (size_t)(col0 + r) * ldw + k0 + g * 8);
        }
        __syncthreads();
        #pragma unroll
        for (int ks = 0; ks < 64; ks += 32) {
            short8 af[2], bfr[2];
            #pragma unroll
            for (int i = 0; i < 2; i++) af[i] = *(const short8*)&As[wm * 32 + i * 16 + l16][ks + quad * 8];
            #pragma unroll
            for (int j = 0; j < 2; j++) bfr[j] = *(const short8*)&Ws[wn * 32 + j * 16 + l16][ks + quad * 8];
            #pragma unroll
            for (int i = 0; i < 2; i++)
                #pragma unroll
                for (int j = 0; j < 2; j++)
                    acc[i][j] = __builtin_amdgcn_mfma_f32_16x16x32_bf16(af[i], bfr[j], acc[i][j], 0, 0, 0);
        }
        __syncthreads();
    }
    // C layout: col = lane&15, row = quad*4 + reg
    #pragma unroll
    for (int i = 0; i < 2; i++) {
        #pragma unroll
        for (int j = 0; j < 2; j++) {
            int gn = col0 + wn * 32 + j * 16 + l16;
            int gm0 = row0 + wm * 32 + i * 16 + quad * 4;
            #pragma unroll
            for (int r = 0; r < 4; r++) {
                float v = acc[i][j][r];
                if (useBias) v += bias[gn];
                size_t o = (size_t)(gm0 + r) * N + gn;
                out[o] = v;
                if (useOutb) outb[o] = (bf16)v;
            }
        }
    }
}

// ---------------- conv + silu (coalesced grid-stride) ----------------
__global__ __launch_bounds__(256) void k_conv(const float* __restrict__ xz,
                                              const float* __restrict__ cw,
                                              const float* __restrict__ cb,
                                              float* __restrict__ u)
{
    for (int idx = blockIdx.x * 256 + threadIdx.x; idx < LSEQ * EDIM; idx += gridDim.x * 256) {
        int t = idx / EDIM, e = idx - t * EDIM;
        float s = cb[e];
        #pragma unroll
        for (int k = 0; k < KCONV; k++) {
            int tt = t - (KCONV - 1) + k;
            if (tt >= 0) s += cw[e * KCONV + k] * xz[(size_t)tt * (2 * EDIM) + e];
        }
        u[(size_t)t * EDIM + e] = siluf(s);
    }
}

// ---------------- x_proj split-K LDS-tiled fp32 GEMM ----------------
__global__ __launch_bounds__(256) void k_xproj(const float* __restrict__ u,
                                               const float* __restrict__ xw,
                                               float* __restrict__ part)
{
    __shared__ float AsF[16][68];
    __shared__ float WsF[16][68];
    const int tid = threadIdx.x;
    const int tx = tid & 15, ty = tid >> 4;
    const int tx4 = tx * 4, ty4 = ty * 4;
    const int row0 = blockIdx.y * 64, col0 = blockIdx.x * 64;
    const int kbase = blockIdx.z * KCH;

    float acc[4][4] = {};
    for (int k0 = 0; k0 < KCH; k0 += 16) {
        #pragma unroll
        for (int i = 0; i < 4; i++) {
            int idx = tid + i * 256;
            int m = idx >> 4, kk = idx & 15;
            AsF[kk][m] = u[(size_t)(row0 + m) * EDIM + kbase + k0 + kk];
        }
        #pragma unroll
        for (int i = 0; i < 4; i++) {
            int idx = tid + i * 256;
            int nn = idx >> 4, kk = idx & 15;
            int gn = col0 + nn;
            WsF[kk][nn] = (gn < 80) ? xw[(size_t)gn * EDIM + kbase + k0 + kk] : 0.f;
        }
        __syncthreads();
        #pragma unroll
        for (int kk = 0; kk < 16; kk++) {
            float av[4], bv[4];
            #pragma unroll
            for (int i = 0; i < 4; i++) av[i] = AsF[kk][ty4 + i];
            #pragma unroll
            for (int j = 0; j < 4; j++) bv[j] = WsF[kk][tx4 + j];
            #pragma unroll
            for (int i = 0; i < 4; i++)
                #pragma unroll
                for (int j = 0; j < 4; j++)
                    acc[i][j] += av[i] * bv[j];
        }
        __syncthreads();
    }

    float* pdst = part + (size_t)blockIdx.z * (LSEQ * 80);
    #pragma unroll
    for (int i = 0; i < 4; i++) {
        int gm = row0 + ty4 + i;
        #pragma unroll
        for (int j = 0; j < 4; j++) {
            int gn = col0 + tx4 + j;
            if (gn < 80) pdst[(size_t)gm * 80 + gn] = acc[i][j];
        }
    }
}

// ---------------- dt GEMM fused with split-K reduce ----------------
// grid (24, 16). A-tile = sum of 8 partials of dbc[:, :48] (reduced during staging).
// bx==0 blocks also reduce+write dbc[:, 48:80] (B/C) to global for the scans.
__global__ __launch_bounds__(256) void k_dt_red(
    const float* __restrict__ part, const float* __restrict__ dtw,
    const float* __restrict__ dtbb, float* __restrict__ out,
    float* __restrict__ dbc)
{
    __shared__ float AsF[16][68];
    __shared__ float WsF[16][68];
    const int tid = threadIdx.x;
    const int tx = tid & 15, ty = tid >> 4;
    const int tx4 = tx * 4, ty4 = ty * 4;
    const int row0 = blockIdx.y * 64, col0 = blockIdx.x * 64;

    // bx==0: reduce + write B/C columns (48..79) for this block's 64 rows
    if (blockIdx.x == 0) {
        for (int idx = tid; idx < 64 * 32; idx += 256) {
            int m = idx >> 5, c = 48 + (idx & 31);
            size_t o = (size_t)(row0 + m) * 80 + c;
            float s = 0.f;
            #pragma unroll
            for (int p = 0; p < KSPLIT; p++) s += part[(size_t)p * (LSEQ * 80) + o];
            dbc[o] = s;
        }
    }

    float acc[4][4] = {};
    for (int k0 = 0; k0 < RDIM; k0 += 16) {
        #pragma unroll
        for (int i = 0; i < 4; i++) {
            int idx = tid + i * 256;
            int m = idx >> 4, kk = idx & 15;
            size_t o = (size_t)(row0 + m) * 80 + k0 + kk;
            float s = 0.f;
            #pragma unroll
            for (int p = 0; p < KSPLIT; p++) s += part[(size_t)p * (LSEQ * 80) + o];
            AsF[kk][m] = s;
        }
        #pragma unroll
        for (int i = 0; i < 4; i++) {
            int idx = tid + i * 256;
            int nn = idx >> 4, kk = idx & 15;
            WsF[kk][nn] = dtw[(size_t)(col0 + nn) * RDIM + k0 + kk];
        }
        __syncthreads();
        #pragma unroll
        for (int kk = 0; kk < 16; kk++) {
            float av[4], bv[4];
            #pragma unroll
            for (int i = 0; i < 4; i++) av[i] = AsF[kk][ty4 + i];
            #pragma unroll
            for (int j = 0; j < 4; j++) bv[j] = WsF[kk][tx4 + j];
            #pragma unroll
            for (int i = 0; i < 4; i++)
                #pragma unroll
                for (int j = 0; j < 4; j++)
                    acc[i][j] += av[i] * bv[j];
        }
        __syncthreads();
    }
    #pragma unroll
    for (int i = 0; i < 4; i++) {
        int gm = row0 + ty4 + i;
        #pragma unroll
        for (int j = 0; j < 4; j++) {
            int gn = col0 + tx4 + j;
            float v = acc[i][j] + dtbb[gn];
            out[(size_t)gm * EDIM + gn] = softplusf(v);
        }
    }
}

// ---------------- residual + rmsnorm ----------------
__global__ __launch_bounds__(256) void k_rms(const float* __restrict__ h, float* __restrict__ res,
                                             bf16* __restrict__ hnb, const float* __restrict__ w,
                                             int first)
{
    __shared__ float red[4];
    __shared__ float tot;
    const int tid = threadIdx.x;
    const int t = blockIdx.x;
    float v[3]; float ss = 0.f;
    #pragma unroll
    for (int r = 0; r < 3; r++) {
        int j = tid + r * 256;
        float xv = h[(size_t)t * HDIM + j];
        if (!first) xv += res[(size_t)t * HDIM + j];
        v[r] = xv;
        res[(size_t)t * HDIM + j] = xv;
        ss += xv * xv;
    }
    #pragma unroll
    for (int m = 32; m >= 1; m >>= 1) ss += __shfl_down(ss, m);
    int wid = tid >> 6;
    if ((tid & 63) == 0) red[wid] = ss;
    __syncthreads();
    if (tid == 0) tot = red[0] + red[1] + red[2] + red[3];
    __syncthreads();
    float scale = rsqrtf(tot / (float)HDIM + 1e-5f);
    #pragma unroll
    for (int r = 0; r < 3; r++) {
        int j = tid + r * 256;
        hnb[(size_t)t * HDIM + j] = (bf16)(v[r] * scale * w[j]);
    }
}

// ---------------- selective scan (thread per e, 16 states in regs) ----------------
__global__ __launch_bounds__(256) void k_scan1(const float* __restrict__ dt,
                                               const float* __restrict__ u,
                                               const float* __restrict__ dbc,
                                               const float* __restrict__ a_log,
                                               float* __restrict__ chunkS,
                                               float* __restrict__ sumdt)
{
    const int ex = blockIdx.x % 6, c = blockIdx.x / 6;
    const int e = ex * 256 + threadIdx.x;
    float A[16];
    #pragma unroll
    for (int q = 0; q < 4; q++) {
        float4 a4 = *(const float4*)(a_log + e * NDIM + q * 4);
        A[q*4+0] = -__expf(a4.x); A[q*4+1] = -__expf(a4.y);
        A[q*4+2] = -__expf(a4.z); A[q*4+3] = -__expf(a4.w);
    }
    float s[16] = {};
    float sd = 0.f;
    const int t0 = c * CHLEN;
    #pragma unroll
    for (int tt = 0; tt < CHLEN; tt++) {
        int t = t0 + tt;
        float dtv = dt[(size_t)t * EDIM + e];
        float uv  = u[(size_t)t * EDIM + e];
        float dtu = dtv * uv;
        sd += dtv;
        float4 B4[4];
        #pragma unroll
        for (int q = 0; q < 4; q++) B4[q] = *(const float4*)(dbc + (size_t)t * 80 + RDIM + q * 4);
        const float* B = (const float*)B4;
        #pragma unroll
        for (int n = 0; n < 16; n++) s[n] = s[n] * __expf(dtv * A[n]) + dtu * B[n];
    }
    float* cs = chunkS + ((size_t)c * EDIM + e) * NDIM;
    #pragma unroll
    for (int q = 0; q < 4; q++)
        *(float4*)(cs + q * 4) = make_float4(s[q*4+0], s[q*4+1], s[q*4+2], s[q*4+3]);
    sumdt[(size_t)c * EDIM + e] = sd;
}

__global__ __launch_bounds__(256) void k_scan2(const float* __restrict__ chunkS,
                                               const float* __restrict__ sumdt,
                                               const float* __restrict__ a_log,
                                               float* __restrict__ sInit)
{
    int gid = blockIdx.x * 256 + threadIdx.x;
    if (gid >= EDIM * NDIM) return;
    int n = gid & 15, e = gid >> 4;
    const float Aen = -__expf(a_log[gid]);
    float s = 0.f;
    for (int c = 0; c < NCHUNK; c++) {
        sInit[((size_t)c * EDIM + e) * NDIM + n] = s;
        float P = __expf(Aen * sumdt[(size_t)c * EDIM + e]);
        s = s * P + chunkS[((size_t)c * EDIM + e) * NDIM + n];
    }
}

__global__ __launch_bounds__(256) void k_scan3(const float* __restrict__ dt,
                                               const float* __restrict__ u,
                                               const float* __restrict__ dbc,
                                               const float* __restrict__ xz,
                                               const float* __restrict__ a_log,
                                               const float* __restrict__ Dp,
                                               const float* __restrict__ sInit,
                                               bf16* __restrict__ yzb)
{
    const int ex = blockIdx.x % 6, c = blockIdx.x / 6;
    const int e = ex * 256 + threadIdx.x;
    float A[16];
    #pragma unroll
    for (int q = 0; q < 4; q++) {
        float4 a4 = *(const float4*)(a_log + e * NDIM + q * 4);
        A[q*4+0] = -__expf(a4.x); A[q*4+1] = -__expf(a4.y);
        A[q*4+2] = -__expf(a4.z); A[q*4+3] = -__expf(a4.w);
    }
    const float dv = Dp[e];
    float s[16];
    const float* si = sInit + ((size_t)c * EDIM + e) * NDIM;
    #pragma unroll
    for (int q = 0; q < 4; q++) {
        float4 s4 = *(const float4*)(si + q * 4);
        s[q*4+0] = s4.x; s[q*4+1] = s4.y; s[q*4+2] = s4.z; s[q*4+3] = s4.w;
    }
    const int t0 = c * CHLEN;
    #pragma unroll
    for (int tt = 0; tt < CHLEN; tt++) {
        int t = t0 + tt;
        float dtv = dt[(size_t)t * EDIM + e];
        float uv  = u[(size_t)t * EDIM + e];
        float zv  = xz[(size_t)t * (2 * EDIM) + EDIM + e];
        float dtu = dtv * uv;
        float4 B4[4], C4[4];
        #pragma unroll
        for (int q = 0; q < 4; q++) {
            B4[q] = *(const float4*)(dbc + (size_t)t * 80 + RDIM + q * 4);
            C4[q] = *(const float4*)(dbc + (size_t)t * 80 + RDIM + NDIM + q * 4);
        }
        const float* B = (const float*)B4;
        const float* C = (const float*)C4;
        float y = 0.f;
        #pragma unroll
        for (int n = 0; n < 16; n++) {
            s[n] = s[n] * __expf(dtv * A[n]) + dtu * B[n];
            y += s[n] * C[n];
        }
        y += uv * dv;
        yzb[(size_t)t * EDIM + e] = (bf16)(y * siluf(zv));
    }
}

extern "C" void kernel_launch(void* const* d_in, const int* in_sizes, int n_in,
                              void* d_out, int out_size, void* d_ws, size_t ws_size,
                              hipStream_t stream)
{
    const float* x        = (const float*)d_in[0];
    const float* emb_w    = (const float*)d_in[1];
    const float* emb_b    = (const float*)d_in[2];
    const float* norm_w   = (const float*)d_in[3];
    const float* in_proj  = (const float*)d_in[4];
    const float* conv_w   = (const float*)d_in[5];
    const float* conv_b   = (const float*)d_in[6];
    const float* x_proj   = (const float*)d_in[7];
    const float* dt_w     = (const float*)d_in[8];
    const float* dt_b     = (const float*)d_in[9];
    const float* A_log    = (const float*)d_in[10];
    const float* Dp       = (const float*)d_in[11];
    const float* out_proj = (const float*)d_in[12];
    const float* head_w   = (const float*)d_in[13];
    const float* head_b   = (const float*)d_in[14];
    float* out = (float*)d_out;

    float* ws = (float*)d_ws;
    size_t off = 0;
    float* h      = ws + off; off += (size_t)LSEQ * HDIM;
    float* res    = ws + off; off += (size_t)LSEQ * HDIM;
    float* xz     = ws + off; off += (size_t)LSEQ * 2 * EDIM;
    float* u      = ws + off; off += (size_t)LSEQ * EDIM;
    float* dbc    = ws + off; off += (size_t)LSEQ * 80;
    float* part   = ws + off; off += (size_t)KSPLIT * LSEQ * 80;
    float* dtb    = ws + off; off += (size_t)LSEQ * EDIM;
    float* chunkS = ws + off; off += (size_t)NCHUNK * EDIM * NDIM;
    float* sumdt  = ws + off; off += (size_t)NCHUNK * EDIM;
    float* sInit  = ws + off; off += (size_t)NCHUNK * EDIM * NDIM;
    bf16* hnb     = (bf16*)(ws + off); off += (size_t)LSEQ * HDIM / 2;
    bf16* yzb     = (bf16*)(ws + off); off += (size_t)LSEQ * EDIM / 2;
    bf16* hb      = (bf16*)(ws + off); off += (size_t)LSEQ * HDIM / 2;
    bf16* xb      = (bf16*)(ws + off); off += (size_t)LSEQ * SDIM / 2;
    bf16* emb_wb  = (bf16*)(ws + off); off += (size_t)HDIM * SDIM / 2;
    bf16* head_wb = (bf16*)(ws + off); off += (size_t)SDIM * HDIM / 2;
    bf16* in_wb   = (bf16*)(ws + off); off += (size_t)NLAYER * 2 * EDIM * HDIM / 2;
    bf16* out_wb  = (bf16*)(ws + off); off += (size_t)NLAYER * HDIM * EDIM / 2;

    // one launch: all fp32->bf16 conversions (x + all weights, both layers)
    F2BSegs segs;
    segs.src[0] = x;        segs.dst[0] = xb;      segs.n[0] = LSEQ * SDIM;
    segs.src[1] = emb_w;    segs.dst[1] = emb_wb;  segs.n[1] = HDIM * SDIM;
    segs.src[2] = head_w;   segs.dst[2] = head_wb; segs.n[2] = SDIM * HDIM;
    segs.src[3] = in_proj;  segs.dst[3] = in_wb;   segs.n[3] = NLAYER * 2 * EDIM * HDIM;
    segs.src[4] = out_proj; segs.dst[4] = out_wb;  segs.n[4] = NLAYER * HDIM * EDIM;
    f2b_all<<<1024, 256, 0, stream>>>(segs);

    // embed: h = x @ emb_w^T + emb_b  (N=768, K=256)
    k_gemm<<<dim3(12, 16), 256, 0, stream>>>(xb, SDIM, emb_wb, SDIM, emb_b,
                                             h, nullptr, HDIM, SDIM, 1, 0);

    for (int l = 0; l < NLAYER; l++) {
        const bf16*  inw  = in_wb  + (size_t)l * 2 * EDIM * HDIM;
        const bf16*  outw = out_wb + (size_t)l * HDIM * EDIM;
        const float* cw   = conv_w + (size_t)l * EDIM * KCONV;
        const float* cb   = conv_b + (size_t)l * EDIM;
        const float* xw   = x_proj + (size_t)l * 80 * EDIM;
        const float* dtw  = dt_w   + (size_t)l * EDIM * RDIM;
        const float* dtbb = dt_b   + (size_t)l * EDIM;
        const float* al   = A_log  + (size_t)l * EDIM * NDIM;
        const float* Dpl  = Dp     + (size_t)l * EDIM;

        k_rms<<<LSEQ, 256, 0, stream>>>(h, res, hnb, norm_w + (size_t)l * HDIM, l == 0);
        k_gemm<<<dim3(48, 16), 256, 0, stream>>>(hnb, HDIM, inw, HDIM, nullptr,
                                                 xz, nullptr, 2 * EDIM, HDIM, 0, 0);
        k_conv<<<2048, 256, 0, stream>>>(xz, cw, cb, u);
        k_xproj<<<dim3(2, 16, KSPLIT), 256, 0, stream>>>(u, xw, part);
        k_dt_red<<<dim3(24, 16), 256, 0, stream>>>(part, dtw, dtbb, dtb, dbc);
        k_scan1<<<6 * NCHUNK, 256, 0, stream>>>(dtb, u, dbc, al, chunkS, sumdt);
        k_scan2<<<96, 256, 0, stream>>>(chunkS, sumdt, al, sInit);
        k_scan3<<<6 * NCHUNK, 256, 0, stream>>>(dtb, u, dbc, xz, al, Dpl, sInit, yzb);
        k_gemm<<<dim3(12, 16), 256, 0, stream>>>(yzb, EDIM, outw, EDIM, nullptr,
                                                 h, hb, HDIM, EDIM, 0, (l == NLAYER - 1) ? 1 : 0);
    }

    // head: out = h @ head_w^T + head_b  (N=256, K=768)
    k_gemm<<<dim3(4, 16), 256, 0, stream>>>(hb, HDIM, head_wb, HDIM, head_b,
                                            out, nullptr, SDIM, HDIM, 1, 0);
}

// Round 13
// 430.262 us; speedup vs baseline: 1.1432x; 1.0068x over previous
//
#include <hip/hip_runtime.h>
#include <hip/hip_bf16.h>
#include <math.h>

// Problem dims
#define SDIM 256
#define HDIM 768
#define EDIM 1536
#define NDIM 16
#define KCONV 4
#define RDIM 48
#define NLAYER 2
#define LSEQ 1024

#define NCHUNK 128
#define CHLEN (LSEQ / NCHUNK)   // 8
#define KSPLIT 8
#define KCH (EDIM / KSPLIT)     // 192

typedef __hip_bfloat16 bf16;
typedef __attribute__((ext_vector_type(8))) short short8;
typedef __attribute__((ext_vector_type(4))) float f32x4;

__device__ __forceinline__ float softplusf(float x) {
    return (x > 20.f) ? x : log1pf(expf(x));
}
__device__ __forceinline__ float siluf(float x) {
    return x / (1.f + expf(-x));
}

// ---------------- combined fp32 -> bf16 conversion: 5 segments, one launch ----------------
struct F2BSegs {
    const float* src[5];
    bf16*        dst[5];
    int          n[5];      // element counts (each % 4 == 0)
};

__global__ __launch_bounds__(256) void f2b_all(F2BSegs segs)
{
    for (int s = 0; s < 5; s++) {
        const float* __restrict__ in = segs.src[s];
        bf16* __restrict__ out = segs.dst[s];
        const int n = segs.n[s];
        for (int i = (blockIdx.x * 256 + threadIdx.x) * 4; i < n; i += gridDim.x * 256 * 4) {
            float4 v = *(const float4*)(in + i);
            out[i + 0] = (bf16)v.x; out[i + 1] = (bf16)v.y;
            out[i + 2] = (bf16)v.z; out[i + 3] = (bf16)v.w;
        }
    }
}

// ---------------- MFMA bf16 GEMM 64x64 tile (emb/head) ----------------
__global__ __launch_bounds__(256) void k_gemm(const bf16* __restrict__ A, int lda,
                                              const bf16* __restrict__ W, int ldw,
                                              const float* __restrict__ bias,
                                              float* __restrict__ out, bf16* __restrict__ outb,
                                              int N, int Kd, int useBias, int useOutb)
{
    __shared__ __align__(16) short As[64][72];
    __shared__ __align__(16) short Ws[64][72];

    const int tid  = threadIdx.x;
    const int lane = tid & 63, wid = tid >> 6;
    const int wm = wid >> 1, wn = wid & 1;
    const int row0 = blockIdx.y * 64, col0 = blockIdx.x * 64;
    const int quad = lane >> 4, l16 = lane & 15;

    f32x4 acc[2][2] = {};
    for (int k0 = 0; k0 < Kd; k0 += 64) {
        #pragma unroll
        for (int i = 0; i < 2; i++) {
            int id = tid + i * 256;
            int r = id >> 3, g = id & 7;
            *(uint4*)&As[r][g * 8] = *(const uint4*)(A + (size_t)(row0 + r) * lda + k0 + g * 8);
            *(uint4*)&Ws[r][g * 8] = *(const uint4*)(W + (size_t)(col0 + r) * ldw + k0 + g * 8);
        }
        __syncthreads();
        #pragma unroll
        for (int ks = 0; ks < 64; ks += 32) {
            short8 af[2], bfr[2];
            #pragma unroll
            for (int i = 0; i < 2; i++) af[i] = *(const short8*)&As[wm * 32 + i * 16 + l16][ks + quad * 8];
            #pragma unroll
            for (int j = 0; j < 2; j++) bfr[j] = *(const short8*)&Ws[wn * 32 + j * 16 + l16][ks + quad * 8];
            #pragma unroll
            for (int i = 0; i < 2; i++)
                #pragma unroll
                for (int j = 0; j < 2; j++)
                    acc[i][j] = __builtin_amdgcn_mfma_f32_16x16x32_bf16(af[i], bfr[j], acc[i][j], 0, 0, 0);
        }
        __syncthreads();
    }
    #pragma unroll
    for (int i = 0; i < 2; i++) {
        #pragma unroll
        for (int j = 0; j < 2; j++) {
            int gn = col0 + wn * 32 + j * 16 + l16;
            int gm0 = row0 + wm * 32 + i * 16 + quad * 4;
            #pragma unroll
            for (int r = 0; r < 4; r++) {
                float v = acc[i][j][r];
                if (useBias) v += bias[gn];
                size_t o = (size_t)(gm0 + r) * N + gn;
                out[o] = v;
                if (useOutb) outb[o] = (bf16)v;
            }
        }
    }
}

// ---------------- MFMA bf16 GEMM 128x128 tile + global_load_lds (in/out_proj) ----------------
// M,N,K multiples of 128/128/64. 4 waves (2x2), each 64x64 via 4x4 mfma_16x16x32.
// LDS unpadded [128][64]: global_load_lds deposits wave-uniform base + lane*16.
__global__ __launch_bounds__(256) void k_gemm128(
    const bf16* __restrict__ A, int lda,
    const bf16* __restrict__ W, int ldw,
    float* __restrict__ out, bf16* __restrict__ outb,
    int N, int Kd, int useOutb)
{
    __shared__ __align__(16) short As[128][64];   // 16 KB, no pad (required)
    __shared__ __align__(16) short Ws[128][64];   // 16 KB

    const int tid  = threadIdx.x;
    const int lane = tid & 63, wid = tid >> 6;
    const int wm = wid >> 1, wn = wid & 1;
    const int row0 = blockIdx.y * 128, col0 = blockIdx.x * 128;
    const int quad = lane >> 4, l16 = lane & 15;
    const int lr = lane >> 3;          // row within 8-row group
    const int lk = (lane & 7) * 8;     // k-col offset (8 bf16 = 16 B)

    f32x4 acc[4][4] = {};

    for (int k0 = 0; k0 < Kd; k0 += 64) {
        // stage A[128][64] and W[128][64]: each wave-call moves 8 rows (64 lanes x 16 B)
        #pragma unroll
        for (int j = 0; j < 4; j++) {
            int rg = (wid * 4 + j) * 8;   // wave-uniform row-group base
            const bf16* ga = A + (size_t)(row0 + rg + lr) * lda + k0 + lk;
            const bf16* gw = W + (size_t)(col0 + rg + lr) * ldw + k0 + lk;
            __builtin_amdgcn_global_load_lds(
                (const __attribute__((address_space(1))) void*)ga,
                (__attribute__((address_space(3))) void*)&As[rg][0], 16, 0, 0);
            __builtin_amdgcn_global_load_lds(
                (const __attribute__((address_space(1))) void*)gw,
                (__attribute__((address_space(3))) void*)&Ws[rg][0], 16, 0, 0);
        }
        __syncthreads();   // compiler emits vmcnt(0) drain before barrier

        #pragma unroll
        for (int ks = 0; ks < 64; ks += 32) {
            short8 af[4], bfr[4];
            #pragma unroll
            for (int i = 0; i < 4; i++)
                af[i] = *(const short8*)&As[wm * 64 + i * 16 + l16][ks + quad * 8];
            #pragma unroll
            for (int j = 0; j < 4; j++)
                bfr[j] = *(const short8*)&Ws[wn * 64 + j * 16 + l16][ks + quad * 8];
            #pragma unroll
            for (int i = 0; i < 4; i++)
                #pragma unroll
                for (int j = 0; j < 4; j++)
                    acc[i][j] = __builtin_amdgcn_mfma_f32_16x16x32_bf16(af[i], bfr[j], acc[i][j], 0, 0, 0);
        }
        __syncthreads();
    }

    // C layout: col = lane&15, row = quad*4 + reg
    #pragma unroll
    for (int i = 0; i < 4; i++) {
        #pragma unroll
        for (int j = 0; j < 4; j++) {
            int gn = col0 + wn * 64 + j * 16 + l16;
            int gm0 = row0 + wm * 64 + i * 16 + quad * 4;
            #pragma unroll
            for (int r = 0; r < 4; r++) {
                float v = acc[i][j][r];
                size_t o = (size_t)(gm0 + r) * N + gn;
                out[o] = v;
                if (useOutb) outb[o] = (bf16)v;
            }
        }
    }
}

// ---------------- conv + silu (coalesced grid-stride) ----------------
__global__ __launch_bounds__(256) void k_conv(const float* __restrict__ xz,
                                              const float* __restrict__ cw,
                                              const float* __restrict__ cb,
                                              float* __restrict__ u)
{
    for (int idx = blockIdx.x * 256 + threadIdx.x; idx < LSEQ * EDIM; idx += gridDim.x * 256) {
        int t = idx / EDIM, e = idx - t * EDIM;
        float s = cb[e];
        #pragma unroll
        for (int k = 0; k < KCONV; k++) {
            int tt = t - (KCONV - 1) + k;
            if (tt >= 0) s += cw[e * KCONV + k] * xz[(size_t)tt * (2 * EDIM) + e];
        }
        u[(size_t)t * EDIM + e] = siluf(s);
    }
}

// ---------------- x_proj split-K LDS-tiled fp32 GEMM ----------------
__global__ __launch_bounds__(256) void k_xproj(const float* __restrict__ u,
                                               const float* __restrict__ xw,
                                               float* __restrict__ part)
{
    __shared__ float AsF[16][68];
    __shared__ float WsF[16][68];
    const int tid = threadIdx.x;
    const int tx = tid & 15, ty = tid >> 4;
    const int tx4 = tx * 4, ty4 = ty * 4;
    const int row0 = blockIdx.y * 64, col0 = blockIdx.x * 64;
    const int kbase = blockIdx.z * KCH;

    float acc[4][4] = {};
    for (int k0 = 0; k0 < KCH; k0 += 16) {
        #pragma unroll
        for (int i = 0; i < 4; i++) {
            int idx = tid + i * 256;
            int m = idx >> 4, kk = idx & 15;
            AsF[kk][m] = u[(size_t)(row0 + m) * EDIM + kbase + k0 + kk];
        }
        #pragma unroll
        for (int i = 0; i < 4; i++) {
            int idx = tid + i * 256;
            int nn = idx >> 4, kk = idx & 15;
            int gn = col0 + nn;
            WsF[kk][nn] = (gn < 80) ? xw[(size_t)gn * EDIM + kbase + k0 + kk] : 0.f;
        }
        __syncthreads();
        #pragma unroll
        for (int kk = 0; kk < 16; kk++) {
            float av[4], bv[4];
            #pragma unroll
            for (int i = 0; i < 4; i++) av[i] = AsF[kk][ty4 + i];
            #pragma unroll
            for (int j = 0; j < 4; j++) bv[j] = WsF[kk][tx4 + j];
            #pragma unroll
            for (int i = 0; i < 4; i++)
                #pragma unroll
                for (int j = 0; j < 4; j++)
                    acc[i][j] += av[i] * bv[j];
        }
        __syncthreads();
    }

    float* pdst = part + (size_t)blockIdx.z * (LSEQ * 80);
    #pragma unroll
    for (int i = 0; i < 4; i++) {
        int gm = row0 + ty4 + i;
        #pragma unroll
        for (int j = 0; j < 4; j++) {
            int gn = col0 + tx4 + j;
            if (gn < 80) pdst[(size_t)gm * 80 + gn] = acc[i][j];
        }
    }
}

// ---------------- dt GEMM fused with split-K reduce ----------------
__global__ __launch_bounds__(256) void k_dt_red(
    const float* __restrict__ part, const float* __restrict__ dtw,
    const float* __restrict__ dtbb, float* __restrict__ out,
    float* __restrict__ dbc)
{
    __shared__ float AsF[16][68];
    __shared__ float WsF[16][68];
    const int tid = threadIdx.x;
    const int tx = tid & 15, ty = tid >> 4;
    const int tx4 = tx * 4, ty4 = ty * 4;
    const int row0 = blockIdx.y * 64, col0 = blockIdx.x * 64;

    if (blockIdx.x == 0) {
        for (int idx = tid; idx < 64 * 32; idx += 256) {
            int m = idx >> 5, c = 48 + (idx & 31);
            size_t o = (size_t)(row0 + m) * 80 + c;
            float s = 0.f;
            #pragma unroll
            for (int p = 0; p < KSPLIT; p++) s += part[(size_t)p * (LSEQ * 80) + o];
            dbc[o] = s;
        }
    }

    float acc[4][4] = {};
    for (int k0 = 0; k0 < RDIM; k0 += 16) {
        #pragma unroll
        for (int i = 0; i < 4; i++) {
            int idx = tid + i * 256;
            int m = idx >> 4, kk = idx & 15;
            size_t o = (size_t)(row0 + m) * 80 + k0 + kk;
            float s = 0.f;
            #pragma unroll
            for (int p = 0; p < KSPLIT; p++) s += part[(size_t)p * (LSEQ * 80) + o];
            AsF[kk][m] = s;
        }
        #pragma unroll
        for (int i = 0; i < 4; i++) {
            int idx = tid + i * 256;
            int nn = idx >> 4, kk = idx & 15;
            WsF[kk][nn] = dtw[(size_t)(col0 + nn) * RDIM + k0 + kk];
        }
        __syncthreads();
        #pragma unroll
        for (int kk = 0; kk < 16; kk++) {
            float av[4], bv[4];
            #pragma unroll
            for (int i = 0; i < 4; i++) av[i] = AsF[kk][ty4 + i];
            #pragma unroll
            for (int j = 0; j < 4; j++) bv[j] = WsF[kk][tx4 + j];
            #pragma unroll
            for (int i = 0; i < 4; i++)
                #pragma unroll
                for (int j = 0; j < 4; j++)
                    acc[i][j] += av[i] * bv[j];
        }
        __syncthreads();
    }
    #pragma unroll
    for (int i = 0; i < 4; i++) {
        int gm = row0 + ty4 + i;
        #pragma unroll
        for (int j = 0; j < 4; j++) {
            int gn = col0 + tx4 + j;
            float v = acc[i][j] + dtbb[gn];
            out[(size_t)gm * EDIM + gn] = softplusf(v);
        }
    }
}

// ---------------- residual + rmsnorm ----------------
__global__ __launch_bounds__(256) void k_rms(const float* __restrict__ h, float* __restrict__ res,
                                             bf16* __restrict__ hnb, const float* __restrict__ w,
                                             int first)
{
    __shared__ float red[4];
    __shared__ float tot;
    const int tid = threadIdx.x;
    const int t = blockIdx.x;
    float v[3]; float ss = 0.f;
    #pragma unroll
    for (int r = 0; r < 3; r++) {
        int j = tid + r * 256;
        float xv = h[(size_t)t * HDIM + j];
        if (!first) xv += res[(size_t)t * HDIM + j];
        v[r] = xv;
        res[(size_t)t * HDIM + j] = xv;
        ss += xv * xv;
    }
    #pragma unroll
    for (int m = 32; m >= 1; m >>= 1) ss += __shfl_down(ss, m);
    int wid = tid >> 6;
    if ((tid & 63) == 0) red[wid] = ss;
    __syncthreads();
    if (tid == 0) tot = red[0] + red[1] + red[2] + red[3];
    __syncthreads();
    float scale = rsqrtf(tot / (float)HDIM + 1e-5f);
    #pragma unroll
    for (int r = 0; r < 3; r++) {
        int j = tid + r * 256;
        hnb[(size_t)t * HDIM + j] = (bf16)(v[r] * scale * w[j]);
    }
}

// ---------------- selective scan (thread per e, 16 states in regs) ----------------
__global__ __launch_bounds__(256) void k_scan1(const float* __restrict__ dt,
                                               const float* __restrict__ u,
                                               const float* __restrict__ dbc,
                                               const float* __restrict__ a_log,
                                               float* __restrict__ chunkS,
                                               float* __restrict__ sumdt)
{
    const int ex = blockIdx.x % 6, c = blockIdx.x / 6;
    const int e = ex * 256 + threadIdx.x;
    float A[16];
    #pragma unroll
    for (int q = 0; q < 4; q++) {
        float4 a4 = *(const float4*)(a_log + e * NDIM + q * 4);
        A[q*4+0] = -__expf(a4.x); A[q*4+1] = -__expf(a4.y);
        A[q*4+2] = -__expf(a4.z); A[q*4+3] = -__expf(a4.w);
    }
    float s[16] = {};
    float sd = 0.f;
    const int t0 = c * CHLEN;
    #pragma unroll
    for (int tt = 0; tt < CHLEN; tt++) {
        int t = t0 + tt;
        float dtv = dt[(size_t)t * EDIM + e];
        float uv  = u[(size_t)t * EDIM + e];
        float dtu = dtv * uv;
        sd += dtv;
        float4 B4[4];
        #pragma unroll
        for (int q = 0; q < 4; q++) B4[q] = *(const float4*)(dbc + (size_t)t * 80 + RDIM + q * 4);
        const float* B = (const float*)B4;
        #pragma unroll
        for (int n = 0; n < 16; n++) s[n] = s[n] * __expf(dtv * A[n]) + dtu * B[n];
    }
    float* cs = chunkS + ((size_t)c * EDIM + e) * NDIM;
    #pragma unroll
    for (int q = 0; q < 4; q++)
        *(float4*)(cs + q * 4) = make_float4(s[q*4+0], s[q*4+1], s[q*4+2], s[q*4+3]);
    sumdt[(size_t)c * EDIM + e] = sd;
}

__global__ __launch_bounds__(256) void k_scan2(const float* __restrict__ chunkS,
                                               const float* __restrict__ sumdt,
                                               const float* __restrict__ a_log,
                                               float* __restrict__ sInit)
{
    int gid = blockIdx.x * 256 + threadIdx.x;
    if (gid >= EDIM * NDIM) return;
    int n = gid & 15, e = gid >> 4;
    const float Aen = -__expf(a_log[gid]);
    float s = 0.f;
    for (int c = 0; c < NCHUNK; c++) {
        sInit[((size_t)c * EDIM + e) * NDIM + n] = s;
        float P = __expf(Aen * sumdt[(size_t)c * EDIM + e]);
        s = s * P + chunkS[((size_t)c * EDIM + e) * NDIM + n];
    }
}

__global__ __launch_bounds__(256) void k_scan3(const float* __restrict__ dt,
                                               const float* __restrict__ u,
                                               const float* __restrict__ dbc,
                                               const float* __restrict__ xz,
                                               const float* __restrict__ a_log,
                                               const float* __restrict__ Dp,
                                               const float* __restrict__ sInit,
                                               bf16* __restrict__ yzb)
{
    const int ex = blockIdx.x % 6, c = blockIdx.x / 6;
    const int e = ex * 256 + threadIdx.x;
    float A[16];
    #pragma unroll
    for (int q = 0; q < 4; q++) {
        float4 a4 = *(const float4*)(a_log + e * NDIM + q * 4);
        A[q*4+0] = -__expf(a4.x); A[q*4+1] = -__expf(a4.y);
        A[q*4+2] = -__expf(a4.z); A[q*4+3] = -__expf(a4.w);
    }
    const float dv = Dp[e];
    float s[16];
    const float* si = sInit + ((size_t)c * EDIM + e) * NDIM;
    #pragma unroll
    for (int q = 0; q < 4; q++) {
        float4 s4 = *(const float4*)(si + q * 4);
        s[q*4+0] = s4.x; s[q*4+1] = s4.y; s[q*4+2] = s4.z; s[q*4+3] = s4.w;
    }
    const int t0 = c * CHLEN;
    #pragma unroll
    for (int tt = 0; tt < CHLEN; tt++) {
        int t = t0 + tt;
        float dtv = dt[(size_t)t * EDIM + e];
        float uv  = u[(size_t)t * EDIM + e];
        float zv  = xz[(size_t)t * (2 * EDIM) + EDIM + e];
        float dtu = dtv * uv;
        float4 B4[4], C4[4];
        #pragma unroll
        for (int q = 0; q < 4; q++) {
            B4[q] = *(const float4*)(dbc + (size_t)t * 80 + RDIM + q * 4);
            C4[q] = *(const float4*)(dbc + (size_t)t * 80 + RDIM + NDIM + q * 4);
        }
        const float* B = (const float*)B4;
        const float* C = (const float*)C4;
        float y = 0.f;
        #pragma unroll
        for (int n = 0; n < 16; n++) {
            s[n] = s[n] * __expf(dtv * A[n]) + dtu * B[n];
            y += s[n] * C[n];
        }
        y += uv * dv;
        yzb[(size_t)t * EDIM + e] = (bf16)(y * siluf(zv));
    }
}

extern "C" void kernel_launch(void* const* d_in, const int* in_sizes, int n_in,
                              void* d_out, int out_size, void* d_ws, size_t ws_size,
                              hipStream_t stream)
{
    const float* x        = (const float*)d_in[0];
    const float* emb_w    = (const float*)d_in[1];
    const float* emb_b    = (const float*)d_in[2];
    const float* norm_w   = (const float*)d_in[3];
    const float* in_proj  = (const float*)d_in[4];
    const float* conv_w   = (const float*)d_in[5];
    const float* conv_b   = (const float*)d_in[6];
    const float* x_proj   = (const float*)d_in[7];
    const float* dt_w     = (const float*)d_in[8];
    const float* dt_b     = (const float*)d_in[9];
    const float* A_log    = (const float*)d_in[10];
    const float* Dp       = (const float*)d_in[11];
    const float* out_proj = (const float*)d_in[12];
    const float* head_w   = (const float*)d_in[13];
    const float* head_b   = (const float*)d_in[14];
    float* out = (float*)d_out;

    float* ws = (float*)d_ws;
    size_t off = 0;
    float* h      = ws + off; off += (size_t)LSEQ * HDIM;
    float* res    = ws + off; off += (size_t)LSEQ * HDIM;
    float* xz     = ws + off; off += (size_t)LSEQ * 2 * EDIM;
    float* u      = ws + off; off += (size_t)LSEQ * EDIM;
    float* dbc    = ws + off; off += (size_t)LSEQ * 80;
    float* part   = ws + off; off += (size_t)KSPLIT * LSEQ * 80;
    float* dtb    = ws + off; off += (size_t)LSEQ * EDIM;
    float* chunkS = ws + off; off += (size_t)NCHUNK * EDIM * NDIM;
    float* sumdt  = ws + off; off += (size_t)NCHUNK * EDIM;
    float* sInit  = ws + off; off += (size_t)NCHUNK * EDIM * NDIM;
    bf16* hnb     = (bf16*)(ws + off); off += (size_t)LSEQ * HDIM / 2;
    bf16* yzb     = (bf16*)(ws + off); off += (size_t)LSEQ * EDIM / 2;
    bf16* hb      = (bf16*)(ws + off); off += (size_t)LSEQ * HDIM / 2;
    bf16* xb      = (bf16*)(ws + off); off += (size_t)LSEQ * SDIM / 2;
    bf16* emb_wb  = (bf16*)(ws + off); off += (size_t)HDIM * SDIM / 2;
    bf16* head_wb = (bf16*)(ws + off); off += (size_t)SDIM * HDIM / 2;
    bf16* in_wb   = (bf16*)(ws + off); off += (size_t)NLAYER * 2 * EDIM * HDIM / 2;
    bf16* out_wb  = (bf16*)(ws + off); off += (size_t)NLAYER * HDIM * EDIM / 2;

    // one launch: all fp32->bf16 conversions (x + all weights, both layers)
    F2BSegs segs;
    segs.src[0] = x;        segs.dst[0] = xb;      segs.n[0] = LSEQ * SDIM;
    segs.src[1] = emb_w;    segs.dst[1] = emb_wb;  segs.n[1] = HDIM * SDIM;
    segs.src[2] = head_w;   segs.dst[2] = head_wb; segs.n[2] = SDIM * HDIM;
    segs.src[3] = in_proj;  segs.dst[3] = in_wb;   segs.n[3] = NLAYER * 2 * EDIM * HDIM;
    segs.src[4] = out_proj; segs.dst[4] = out_wb;  segs.n[4] = NLAYER * HDIM * EDIM;
    f2b_all<<<1024, 256, 0, stream>>>(segs);

    // embed: h = x @ emb_w^T + emb_b  (N=768, K=256)
    k_gemm<<<dim3(12, 16), 256, 0, stream>>>(xb, SDIM, emb_wb, SDIM, emb_b,
                                             h, nullptr, HDIM, SDIM, 1, 0);

    for (int l = 0; l < NLAYER; l++) {
        const bf16*  inw  = in_wb  + (size_t)l * 2 * EDIM * HDIM;
        const bf16*  outw = out_wb + (size_t)l * HDIM * EDIM;
        const float* cw   = conv_w + (size_t)l * EDIM * KCONV;
        const float* cb   = conv_b + (size_t)l * EDIM;
        const float* xw   = x_proj + (size_t)l * 80 * EDIM;
        const float* dtw  = dt_w   + (size_t)l * EDIM * RDIM;
        const float* dtbb = dt_b   + (size_t)l * EDIM;
        const float* al   = A_log  + (size_t)l * EDIM * NDIM;
        const float* Dpl  = Dp     + (size_t)l * EDIM;

        k_rms<<<LSEQ, 256, 0, stream>>>(h, res, hnb, norm_w + (size_t)l * HDIM, l == 0);
        // in_proj: 128x128 tiles, (3072/128=24, 1024/128=8)
        k_gemm128<<<dim3(24, 8), 256, 0, stream>>>(hnb, HDIM, inw, HDIM,
                                                   xz, nullptr, 2 * EDIM, HDIM, 0);
        k_conv<<<2048, 256, 0, stream>>>(xz, cw, cb, u);
        k_xproj<<<dim3(2, 16, KSPLIT), 256, 0, stream>>>(u, xw, part);
        k_dt_red<<<dim3(24, 16), 256, 0, stream>>>(part, dtw, dtbb, dtb, dbc);
        k_scan1<<<6 * NCHUNK, 256, 0, stream>>>(dtb, u, dbc, al, chunkS, sumdt);
        k_scan2<<<96, 256, 0, stream>>>(chunkS, sumdt, al, sInit);
        k_scan3<<<6 * NCHUNK, 256, 0, stream>>>(dtb, u, dbc, xz, al, Dpl, sInit, yzb);
        // out_proj: 128x128 tiles, (768/128=6, 8)
        k_gemm128<<<dim3(6, 8), 256, 0, stream>>>(yzb, EDIM, outw, EDIM,
                                                  h, hb, HDIM, EDIM, (l == NLAYER - 1) ? 1 : 0);
    }

    // head: out = h @ head_w^T + head_b  (N=256, K=768)
    k_gemm<<<dim3(4, 16), 256, 0, stream>>>(hb, HDIM, head_wb, HDIM, head_b,
                                            out, nullptr, SDIM, HDIM, 1, 0);
}

// Round 14
// 404.864 us; speedup vs baseline: 1.2149x; 1.0627x over previous
//
#include <hip/hip_runtime.h>
#include <hip/hip_bf16.h>
#include <math.h>

// Problem dims
#define SDIM 256
#define HDIM 768
#define EDIM 1536
#define NDIM 16
#define KCONV 4
#define RDIM 48
#define NLAYER 2
#define LSEQ 1024

#define NCHUNK 128
#define CHLEN (LSEQ / NCHUNK)   // 8
#define XSPLIT 4
#define XKCH (EDIM / XSPLIT)    // 384

typedef __hip_bfloat16 bf16;
typedef __attribute__((ext_vector_type(8))) short short8;
typedef __attribute__((ext_vector_type(4))) float f32x4;

__device__ __forceinline__ float softplusf(float x) {
    return (x > 20.f) ? x : log1pf(expf(x));
}
__device__ __forceinline__ float siluf(float x) {
    return x / (1.f + expf(-x));
}

// ---------------- combined fp32 -> bf16 conversion: 6 segments, one launch ----------------
struct F2BSegs {
    const float* src[6];
    bf16*        dst[6];
    int          n[6];      // element counts (each % 4 == 0)
};

__global__ __launch_bounds__(256) void f2b_all(F2BSegs segs)
{
    for (int s = 0; s < 6; s++) {
        const float* __restrict__ in = segs.src[s];
        bf16* __restrict__ out = segs.dst[s];
        const int n = segs.n[s];
        for (int i = (blockIdx.x * 256 + threadIdx.x) * 4; i < n; i += gridDim.x * 256 * 4) {
            float4 v = *(const float4*)(in + i);
            out[i + 0] = (bf16)v.x; out[i + 1] = (bf16)v.y;
            out[i + 2] = (bf16)v.z; out[i + 3] = (bf16)v.w;
        }
    }
}

// ---------------- MFMA bf16 GEMM 64x64 tile (emb/head) ----------------
__global__ __launch_bounds__(256) void k_gemm(const bf16* __restrict__ A, int lda,
                                              const bf16* __restrict__ W, int ldw,
                                              const float* __restrict__ bias,
                                              float* __restrict__ out, bf16* __restrict__ outb,
                                              int N, int Kd, int useBias, int useOutb)
{
    __shared__ __align__(16) short As[64][72];
    __shared__ __align__(16) short Ws[64][72];

    const int tid  = threadIdx.x;
    const int lane = tid & 63, wid = tid >> 6;
    const int wm = wid >> 1, wn = wid & 1;
    const int row0 = blockIdx.y * 64, col0 = blockIdx.x * 64;
    const int quad = lane >> 4, l16 = lane & 15;

    f32x4 acc[2][2] = {};
    for (int k0 = 0; k0 < Kd; k0 += 64) {
        #pragma unroll
        for (int i = 0; i < 2; i++) {
            int id = tid + i * 256;
            int r = id >> 3, g = id & 7;
            *(uint4*)&As[r][g * 8] = *(const uint4*)(A + (size_t)(row0 + r) * lda + k0 + g * 8);
            *(uint4*)&Ws[r][g * 8] = *(const uint4*)(W + (size_t)(col0 + r) * ldw + k0 + g * 8);
        }
        __syncthreads();
        #pragma unroll
        for (int ks = 0; ks < 64; ks += 32) {
            short8 af[2], bfr[2];
            #pragma unroll
            for (int i = 0; i < 2; i++) af[i] = *(const short8*)&As[wm * 32 + i * 16 + l16][ks + quad * 8];
            #pragma unroll
            for (int j = 0; j < 2; j++) bfr[j] = *(const short8*)&Ws[wn * 32 + j * 16 + l16][ks + quad * 8];
            #pragma unroll
            for (int i = 0; i < 2; i++)
                #pragma unroll
                for (int j = 0; j < 2; j++)
                    acc[i][j] = __builtin_amdgcn_mfma_f32_16x16x32_bf16(af[i], bfr[j], acc[i][j], 0, 0, 0);
        }
        __syncthreads();
    }
    #pragma unroll
    for (int i = 0; i < 2; i++) {
        #pragma unroll
        for (int j = 0; j < 2; j++) {
            int gn = col0 + wn * 32 + j * 16 + l16;
            int gm0 = row0 + wm * 32 + i * 16 + quad * 4;
            #pragma unroll
            for (int r = 0; r < 4; r++) {
                float v = acc[i][j][r];
                if (useBias) v += bias[gn];
                size_t o = (size_t)(gm0 + r) * N + gn;
                out[o] = v;
                if (useOutb) outb[o] = (bf16)v;
            }
        }
    }
}

// ---------------- MFMA bf16 GEMM 128x128 tile + global_load_lds (in/out_proj) ----------------
__global__ __launch_bounds__(256) void k_gemm128(
    const bf16* __restrict__ A, int lda,
    const bf16* __restrict__ W, int ldw,
    float* __restrict__ out, bf16* __restrict__ outb,
    int N, int Kd, int useOutb)
{
    __shared__ __align__(16) short As[128][64];   // 16 KB, no pad (required by global_load_lds)
    __shared__ __align__(16) short Ws[128][64];

    const int tid  = threadIdx.x;
    const int lane = tid & 63, wid = tid >> 6;
    const int wm = wid >> 1, wn = wid & 1;
    const int row0 = blockIdx.y * 128, col0 = blockIdx.x * 128;
    const int quad = lane >> 4, l16 = lane & 15;
    const int lr = lane >> 3;          // row within 8-row group
    const int lk = (lane & 7) * 8;     // k-col offset (8 bf16 = 16 B)

    f32x4 acc[4][4] = {};

    for (int k0 = 0; k0 < Kd; k0 += 64) {
        #pragma unroll
        for (int j = 0; j < 4; j++) {
            int rg = (wid * 4 + j) * 8;   // wave-uniform row-group base
            const bf16* ga = A + (size_t)(row0 + rg + lr) * lda + k0 + lk;
            const bf16* gw = W + (size_t)(col0 + rg + lr) * ldw + k0 + lk;
            __builtin_amdgcn_global_load_lds(
                (const __attribute__((address_space(1))) void*)ga,
                (__attribute__((address_space(3))) void*)&As[rg][0], 16, 0, 0);
            __builtin_amdgcn_global_load_lds(
                (const __attribute__((address_space(1))) void*)gw,
                (__attribute__((address_space(3))) void*)&Ws[rg][0], 16, 0, 0);
        }
        __syncthreads();

        #pragma unroll
        for (int ks = 0; ks < 64; ks += 32) {
            short8 af[4], bfr[4];
            #pragma unroll
            for (int i = 0; i < 4; i++)
                af[i] = *(const short8*)&As[wm * 64 + i * 16 + l16][ks + quad * 8];
            #pragma unroll
            for (int j = 0; j < 4; j++)
                bfr[j] = *(const short8*)&Ws[wn * 64 + j * 16 + l16][ks + quad * 8];
            #pragma unroll
            for (int i = 0; i < 4; i++)
                #pragma unroll
                for (int j = 0; j < 4; j++)
                    acc[i][j] = __builtin_amdgcn_mfma_f32_16x16x32_bf16(af[i], bfr[j], acc[i][j], 0, 0, 0);
        }
        __syncthreads();
    }

    #pragma unroll
    for (int i = 0; i < 4; i++) {
        #pragma unroll
        for (int j = 0; j < 4; j++) {
            int gn = col0 + wn * 64 + j * 16 + l16;
            int gm0 = row0 + wm * 64 + i * 16 + quad * 4;
            #pragma unroll
            for (int r = 0; r < 4; r++) {
                float v = acc[i][j][r];
                size_t o = (size_t)(gm0 + r) * N + gn;
                out[o] = v;
                if (useOutb) outb[o] = (bf16)v;
            }
        }
    }
}

// ---------------- conv + silu, float4-vectorized; writes u (fp32) and ub (bf16) ----------------
__global__ __launch_bounds__(256) void k_conv(const float* __restrict__ xz,
                                              const float* __restrict__ cw,
                                              const float* __restrict__ cb,
                                              float* __restrict__ u,
                                              bf16* __restrict__ ub)
{
    const int NG = LSEQ * EDIM / 4;
    for (int g = blockIdx.x * 256 + threadIdx.x; g < NG; g += gridDim.x * 256) {
        int t = g / (EDIM / 4);
        int e4 = (g - t * (EDIM / 4)) * 4;
        float4 s = *(const float4*)(cb + e4);
        #pragma unroll
        for (int k = 0; k < KCONV; k++) {
            int tt = t - (KCONV - 1) + k;
            if (tt >= 0) {
                float4 xv = *(const float4*)(xz + (size_t)tt * (2 * EDIM) + e4);
                s.x += cw[(e4 + 0) * KCONV + k] * xv.x;
                s.y += cw[(e4 + 1) * KCONV + k] * xv.y;
                s.z += cw[(e4 + 2) * KCONV + k] * xv.z;
                s.w += cw[(e4 + 3) * KCONV + k] * xv.w;
            }
        }
        float4 uv;
        uv.x = siluf(s.x); uv.y = siluf(s.y); uv.z = siluf(s.z); uv.w = siluf(s.w);
        size_t o = (size_t)t * EDIM + e4;
        *(float4*)(u + o) = uv;
        bf16 tmp[4] = {(bf16)uv.x, (bf16)uv.y, (bf16)uv.z, (bf16)uv.w};
        *(uint2*)(ub + o) = *(const uint2*)tmp;
    }
}

// ---------------- x_proj: bf16 MFMA 64-tile, split-K=4, fp32 partials ----------------
// grid (2, 16, XSPLIT); N=80 bounds-guarded.
__global__ __launch_bounds__(256) void k_xproj_mfma(
    const bf16* __restrict__ A,   // ub [1024][1536]
    const bf16* __restrict__ W,   // xwb [80][1536]
    float* __restrict__ part)     // [XSPLIT][1024][80]
{
    __shared__ __align__(16) short As[64][72];
    __shared__ __align__(16) short Ws[64][72];

    const int tid  = threadIdx.x;
    const int lane = tid & 63, wid = tid >> 6;
    const int wm = wid >> 1, wn = wid & 1;
    const int row0 = blockIdx.y * 64, col0 = blockIdx.x * 64;
    const int quad = lane >> 4, l16 = lane & 15;
    const int kbase = blockIdx.z * XKCH;

    f32x4 acc[2][2] = {};
    for (int k0 = 0; k0 < XKCH; k0 += 64) {
        #pragma unroll
        for (int i = 0; i < 2; i++) {
            int id = tid + i * 256;
            int r = id >> 3, g = id & 7;
            *(uint4*)&As[r][g * 8] =
                *(const uint4*)(A + (size_t)(row0 + r) * EDIM + kbase + k0 + g * 8);
            uint4 wv = {0, 0, 0, 0};
            if (col0 + r < 80)
                wv = *(const uint4*)(W + (size_t)(col0 + r) * EDIM + kbase + k0 + g * 8);
            *(uint4*)&Ws[r][g * 8] = wv;
        }
        __syncthreads();
        #pragma unroll
        for (int ks = 0; ks < 64; ks += 32) {
            short8 af[2], bfr[2];
            #pragma unroll
            for (int i = 0; i < 2; i++) af[i] = *(const short8*)&As[wm * 32 + i * 16 + l16][ks + quad * 8];
            #pragma unroll
            for (int j = 0; j < 2; j++) bfr[j] = *(const short8*)&Ws[wn * 32 + j * 16 + l16][ks + quad * 8];
            #pragma unroll
            for (int i = 0; i < 2; i++)
                #pragma unroll
                for (int j = 0; j < 2; j++)
                    acc[i][j] = __builtin_amdgcn_mfma_f32_16x16x32_bf16(af[i], bfr[j], acc[i][j], 0, 0, 0);
        }
        __syncthreads();
    }

    float* pdst = part + (size_t)blockIdx.z * (LSEQ * 80);
    #pragma unroll
    for (int i = 0; i < 2; i++) {
        #pragma unroll
        for (int j = 0; j < 2; j++) {
            int gn = col0 + wn * 32 + j * 16 + l16;
            int gm0 = row0 + wm * 32 + i * 16 + quad * 4;
            if (gn < 80) {
                #pragma unroll
                for (int r = 0; r < 4; r++)
                    pdst[(size_t)(gm0 + r) * 80 + gn] = acc[i][j][r];
            }
        }
    }
}

// ---------------- dt GEMM fused with split-K reduce ----------------
// grid (24, 16). A-tile = sum of XSPLIT partials of dbc[:, :48] (reduced during staging).
// bx==0 blocks also reduce+write dbc[:, 48:80] (B/C) for the scans.
__global__ __launch_bounds__(256) void k_dt_red(
    const float* __restrict__ part, const float* __restrict__ dtw,
    const float* __restrict__ dtbb, float* __restrict__ out,
    float* __restrict__ dbc)
{
    __shared__ float AsF[16][68];
    __shared__ float WsF[16][68];
    const int tid = threadIdx.x;
    const int tx = tid & 15, ty = tid >> 4;
    const int tx4 = tx * 4, ty4 = ty * 4;
    const int row0 = blockIdx.y * 64, col0 = blockIdx.x * 64;

    if (blockIdx.x == 0) {
        for (int idx = tid; idx < 64 * 32; idx += 256) {
            int m = idx >> 5, c = 48 + (idx & 31);
            size_t o = (size_t)(row0 + m) * 80 + c;
            float s = 0.f;
            #pragma unroll
            for (int p = 0; p < XSPLIT; p++) s += part[(size_t)p * (LSEQ * 80) + o];
            dbc[o] = s;
        }
    }

    float acc[4][4] = {};
    for (int k0 = 0; k0 < RDIM; k0 += 16) {
        #pragma unroll
        for (int i = 0; i < 4; i++) {
            int idx = tid + i * 256;
            int m = idx >> 4, kk = idx & 15;
            size_t o = (size_t)(row0 + m) * 80 + k0 + kk;
            float s = 0.f;
            #pragma unroll
            for (int p = 0; p < XSPLIT; p++) s += part[(size_t)p * (LSEQ * 80) + o];
            AsF[kk][m] = s;
        }
        #pragma unroll
        for (int i = 0; i < 4; i++) {
            int idx = tid + i * 256;
            int nn = idx >> 4, kk = idx & 15;
            WsF[kk][nn] = dtw[(size_t)(col0 + nn) * RDIM + k0 + kk];
        }
        __syncthreads();
        #pragma unroll
        for (int kk = 0; kk < 16; kk++) {
            float av[4], bv[4];
            #pragma unroll
            for (int i = 0; i < 4; i++) av[i] = AsF[kk][ty4 + i];
            #pragma unroll
            for (int j = 0; j < 4; j++) bv[j] = WsF[kk][tx4 + j];
            #pragma unroll
            for (int i = 0; i < 4; i++)
                #pragma unroll
                for (int j = 0; j < 4; j++)
                    acc[i][j] += av[i] * bv[j];
        }
        __syncthreads();
    }
    #pragma unroll
    for (int i = 0; i < 4; i++) {
        int gm = row0 + ty4 + i;
        #pragma unroll
        for (int j = 0; j < 4; j++) {
            int gn = col0 + tx4 + j;
            float v = acc[i][j] + dtbb[gn];
            out[(size_t)gm * EDIM + gn] = softplusf(v);
        }
    }
}

// ---------------- residual + rmsnorm ----------------
__global__ __launch_bounds__(256) void k_rms(const float* __restrict__ h, float* __restrict__ res,
                                             bf16* __restrict__ hnb, const float* __restrict__ w,
                                             int first)
{
    __shared__ float red[4];
    __shared__ float tot;
    const int tid = threadIdx.x;
    const int t = blockIdx.x;
    float v[3]; float ss = 0.f;
    #pragma unroll
    for (int r = 0; r < 3; r++) {
        int j = tid + r * 256;
        float xv = h[(size_t)t * HDIM + j];
        if (!first) xv += res[(size_t)t * HDIM + j];
        v[r] = xv;
        res[(size_t)t * HDIM + j] = xv;
        ss += xv * xv;
    }
    #pragma unroll
    for (int m = 32; m >= 1; m >>= 1) ss += __shfl_down(ss, m);
    int wid = tid >> 6;
    if ((tid & 63) == 0) red[wid] = ss;
    __syncthreads();
    if (tid == 0) tot = red[0] + red[1] + red[2] + red[3];
    __syncthreads();
    float scale = rsqrtf(tot / (float)HDIM + 1e-5f);
    #pragma unroll
    for (int r = 0; r < 3; r++) {
        int j = tid + r * 256;
        hnb[(size_t)t * HDIM + j] = (bf16)(v[r] * scale * w[j]);
    }
}

// ---------------- selective scan (thread per e, 16 states in regs) ----------------
__global__ __launch_bounds__(256) void k_scan1(const float* __restrict__ dt,
                                               const float* __restrict__ u,
                                               const float* __restrict__ dbc,
                                               const float* __restrict__ a_log,
                                               float* __restrict__ chunkS,
                                               float* __restrict__ sumdt)
{
    const int ex = blockIdx.x % 6, c = blockIdx.x / 6;
    const int e = ex * 256 + threadIdx.x;
    float A[16];
    #pragma unroll
    for (int q = 0; q < 4; q++) {
        float4 a4 = *(const float4*)(a_log + e * NDIM + q * 4);
        A[q*4+0] = -__expf(a4.x); A[q*4+1] = -__expf(a4.y);
        A[q*4+2] = -__expf(a4.z); A[q*4+3] = -__expf(a4.w);
    }
    float s[16] = {};
    float sd = 0.f;
    const int t0 = c * CHLEN;
    #pragma unroll
    for (int tt = 0; tt < CHLEN; tt++) {
        int t = t0 + tt;
        float dtv = dt[(size_t)t * EDIM + e];
        float uv  = u[(size_t)t * EDIM + e];
        float dtu = dtv * uv;
        sd += dtv;
        float4 B4[4];
        #pragma unroll
        for (int q = 0; q < 4; q++) B4[q] = *(const float4*)(dbc + (size_t)t * 80 + RDIM + q * 4);
        const float* B = (const float*)B4;
        #pragma unroll
        for (int n = 0; n < 16; n++) s[n] = s[n] * __expf(dtv * A[n]) + dtu * B[n];
    }
    float* cs = chunkS + ((size_t)c * EDIM + e) * NDIM;
    #pragma unroll
    for (int q = 0; q < 4; q++)
        *(float4*)(cs + q * 4) = make_float4(s[q*4+0], s[q*4+1], s[q*4+2], s[q*4+3]);
    sumdt[(size_t)c * EDIM + e] = sd;
}

__global__ __launch_bounds__(256) void k_scan2(const float* __restrict__ chunkS,
                                               const float* __restrict__ sumdt,
                                               const float* __restrict__ a_log,
                                               float* __restrict__ sInit)
{
    int gid = blockIdx.x * 256 + threadIdx.x;
    if (gid >= EDIM * NDIM) return;
    int n = gid & 15, e = gid >> 4;
    const float Aen = -__expf(a_log[gid]);
    float s = 0.f;
    for (int c = 0; c < NCHUNK; c++) {
        sInit[((size_t)c * EDIM + e) * NDIM + n] = s;
        float P = __expf(Aen * sumdt[(size_t)c * EDIM + e]);
        s = s * P + chunkS[((size_t)c * EDIM + e) * NDIM + n];
    }
}

__global__ __launch_bounds__(256) void k_scan3(const float* __restrict__ dt,
                                               const float* __restrict__ u,
                                               const float* __restrict__ dbc,
                                               const float* __restrict__ xz,
                                               const float* __restrict__ a_log,
                                               const float* __restrict__ Dp,
                                               const float* __restrict__ sInit,
                                               bf16* __restrict__ yzb)
{
    const int ex = blockIdx.x % 6, c = blockIdx.x / 6;
    const int e = ex * 256 + threadIdx.x;
    float A[16];
    #pragma unroll
    for (int q = 0; q < 4; q++) {
        float4 a4 = *(const float4*)(a_log + e * NDIM + q * 4);
        A[q*4+0] = -__expf(a4.x); A[q*4+1] = -__expf(a4.y);
        A[q*4+2] = -__expf(a4.z); A[q*4+3] = -__expf(a4.w);
    }
    const float dv = Dp[e];
    float s[16];
    const float* si = sInit + ((size_t)c * EDIM + e) * NDIM;
    #pragma unroll
    for (int q = 0; q < 4; q++) {
        float4 s4 = *(const float4*)(si + q * 4);
        s[q*4+0] = s4.x; s[q*4+1] = s4.y; s[q*4+2] = s4.z; s[q*4+3] = s4.w;
    }
    const int t0 = c * CHLEN;
    #pragma unroll
    for (int tt = 0; tt < CHLEN; tt++) {
        int t = t0 + tt;
        float dtv = dt[(size_t)t * EDIM + e];
        float uv  = u[(size_t)t * EDIM + e];
        float zv  = xz[(size_t)t * (2 * EDIM) + EDIM + e];
        float dtu = dtv * uv;
        float4 B4[4], C4[4];
        #pragma unroll
        for (int q = 0; q < 4; q++) {
            B4[q] = *(const float4*)(dbc + (size_t)t * 80 + RDIM + q * 4);
            C4[q] = *(const float4*)(dbc + (size_t)t * 80 + RDIM + NDIM + q * 4);
        }
        const float* B = (const float*)B4;
        const float* C = (const float*)C4;
        float y = 0.f;
        #pragma unroll
        for (int n = 0; n < 16; n++) {
            s[n] = s[n] * __expf(dtv * A[n]) + dtu * B[n];
            y += s[n] * C[n];
        }
        y += uv * dv;
        yzb[(size_t)t * EDIM + e] = (bf16)(y * siluf(zv));
    }
}

extern "C" void kernel_launch(void* const* d_in, const int* in_sizes, int n_in,
                              void* d_out, int out_size, void* d_ws, size_t ws_size,
                              hipStream_t stream)
{
    const float* x        = (const float*)d_in[0];
    const float* emb_w    = (const float*)d_in[1];
    const float* emb_b    = (const float*)d_in[2];
    const float* norm_w   = (const float*)d_in[3];
    const float* in_proj  = (const float*)d_in[4];
    const float* conv_w   = (const float*)d_in[5];
    const float* conv_b   = (const float*)d_in[6];
    const float* x_proj   = (const float*)d_in[7];
    const float* dt_w     = (const float*)d_in[8];
    const float* dt_b     = (const float*)d_in[9];
    const float* A_log    = (const float*)d_in[10];
    const float* Dp       = (const float*)d_in[11];
    const float* out_proj = (const float*)d_in[12];
    const float* head_w   = (const float*)d_in[13];
    const float* head_b   = (const float*)d_in[14];
    float* out = (float*)d_out;

    float* ws = (float*)d_ws;
    size_t off = 0;
    float* h      = ws + off; off += (size_t)LSEQ * HDIM;
    float* res    = ws + off; off += (size_t)LSEQ * HDIM;
    float* xz     = ws + off; off += (size_t)LSEQ * 2 * EDIM;
    float* u      = ws + off; off += (size_t)LSEQ * EDIM;
    float* dbc    = ws + off; off += (size_t)LSEQ * 80;
    float* part   = ws + off; off += (size_t)XSPLIT * LSEQ * 80;
    float* dtb    = ws + off; off += (size_t)LSEQ * EDIM;
    float* chunkS = ws + off; off += (size_t)NCHUNK * EDIM * NDIM;
    float* sumdt  = ws + off; off += (size_t)NCHUNK * EDIM;
    float* sInit  = ws + off; off += (size_t)NCHUNK * EDIM * NDIM;
    bf16* hnb     = (bf16*)(ws + off); off += (size_t)LSEQ * HDIM / 2;
    bf16* yzb     = (bf16*)(ws + off); off += (size_t)LSEQ * EDIM / 2;
    bf16* hb      = (bf16*)(ws + off); off += (size_t)LSEQ * HDIM / 2;
    bf16* ub      = (bf16*)(ws + off); off += (size_t)LSEQ * EDIM / 2;
    bf16* xb      = (bf16*)(ws + off); off += (size_t)LSEQ * SDIM / 2;
    bf16* emb_wb  = (bf16*)(ws + off); off += (size_t)HDIM * SDIM / 2;
    bf16* head_wb = (bf16*)(ws + off); off += (size_t)SDIM * HDIM / 2;
    bf16* in_wb   = (bf16*)(ws + off); off += (size_t)NLAYER * 2 * EDIM * HDIM / 2;
    bf16* out_wb  = (bf16*)(ws + off); off += (size_t)NLAYER * HDIM * EDIM / 2;
    bf16* xwb     = (bf16*)(ws + off); off += (size_t)NLAYER * 80 * EDIM / 2;

    // one launch: all fp32->bf16 conversions (x + all weights incl. x_proj, both layers)
    F2BSegs segs;
    segs.src[0] = x;        segs.dst[0] = xb;      segs.n[0] = LSEQ * SDIM;
    segs.src[1] = emb_w;    segs.dst[1] = emb_wb;  segs.n[1] = HDIM * SDIM;
    segs.src[2] = head_w;   segs.dst[2] = head_wb; segs.n[2] = SDIM * HDIM;
    segs.src[3] = in_proj;  segs.dst[3] = in_wb;   segs.n[3] = NLAYER * 2 * EDIM * HDIM;
    segs.src[4] = out_proj; segs.dst[4] = out_wb;  segs.n[4] = NLAYER * HDIM * EDIM;
    segs.src[5] = x_proj;   segs.dst[5] = xwb;     segs.n[5] = NLAYER * 80 * EDIM;
    f2b_all<<<1024, 256, 0, stream>>>(segs);

    // embed: h = x @ emb_w^T + emb_b  (N=768, K=256)
    k_gemm<<<dim3(12, 16), 256, 0, stream>>>(xb, SDIM, emb_wb, SDIM, emb_b,
                                             h, nullptr, HDIM, SDIM, 1, 0);

    for (int l = 0; l < NLAYER; l++) {
        const bf16*  inw  = in_wb  + (size_t)l * 2 * EDIM * HDIM;
        const bf16*  outw = out_wb + (size_t)l * HDIM * EDIM;
        const bf16*  xwbl = xwb    + (size_t)l * 80 * EDIM;
        const float* cw   = conv_w + (size_t)l * EDIM * KCONV;
        const float* cb   = conv_b + (size_t)l * EDIM;
        const float* dtw  = dt_w   + (size_t)l * EDIM * RDIM;
        const float* dtbb = dt_b   + (size_t)l * EDIM;
        const float* al   = A_log  + (size_t)l * EDIM * NDIM;
        const float* Dpl  = Dp     + (size_t)l * EDIM;

        k_rms<<<LSEQ, 256, 0, stream>>>(h, res, hnb, norm_w + (size_t)l * HDIM, l == 0);
        // in_proj: 128x128 tiles
        k_gemm128<<<dim3(24, 8), 256, 0, stream>>>(hnb, HDIM, inw, HDIM,
                                                   xz, nullptr, 2 * EDIM, HDIM, 0);
        // conv+silu, float4; writes u (fp32, for scan) and ub (bf16, for xproj MFMA)
        k_conv<<<1536, 256, 0, stream>>>(xz, cw, cb, u, ub);
        // xproj: bf16 MFMA, split-K=4
        k_xproj_mfma<<<dim3(2, 16, XSPLIT), 256, 0, stream>>>(ub, xwbl, part);
        k_dt_red<<<dim3(24, 16), 256, 0, stream>>>(part, dtw, dtbb, dtb, dbc);
        k_scan1<<<6 * NCHUNK, 256, 0, stream>>>(dtb, u, dbc, al, chunkS, sumdt);
        k_scan2<<<96, 256, 0, stream>>>(chunkS, sumdt, al, sInit);
        k_scan3<<<6 * NCHUNK, 256, 0, stream>>>(dtb, u, dbc, xz, al, Dpl, sInit, yzb);
        // out_proj: 128x128 tiles
        k_gemm128<<<dim3(6, 8), 256, 0, stream>>>(yzb, EDIM, outw, EDIM,
                                                  h, hb, HDIM, EDIM, (l == NLAYER - 1) ? 1 : 0);
    }

    // head: out = h @ head_w^T + head_b  (N=256, K=768)
    k_gemm<<<dim3(4, 16), 256, 0, stream>>>(hb, HDIM, head_wb, HDIM, head_b,
                                            out, nullptr, SDIM, HDIM, 1, 0);
}

// Round 15
// 400.579 us; speedup vs baseline: 1.2279x; 1.0107x over previous
//
#include <hip/hip_runtime.h>
#include <hip/hip_bf16.h>
#include <math.h>

// Problem dims
#define SDIM 256
#define HDIM 768
#define EDIM 1536
#define NDIM 16
#define KCONV 4
#define RDIM 48
#define NLAYER 2
#define LSEQ 1024

#define NCHUNK 128
#define CHLEN (LSEQ / NCHUNK)   // 8
#define XSPLIT 4
#define XKCH (EDIM / XSPLIT)    // 384

typedef __hip_bfloat16 bf16;
typedef __attribute__((ext_vector_type(8))) short short8;
typedef __attribute__((ext_vector_type(4))) float f32x4;

__device__ __forceinline__ float softplusf(float x) {
    return (x > 20.f) ? x : log1pf(expf(x));
}
__device__ __forceinline__ float siluf(float x) {
    return x / (1.f + expf(-x));
}

// ---------------- combined fp32 -> bf16 conversion: 6 segments, one launch ----------------
struct F2BSegs {
    const float* src[6];
    bf16*        dst[6];
    int          n[6];      // element counts (each % 4 == 0)
};

__global__ __launch_bounds__(256) void f2b_all(F2BSegs segs)
{
    for (int s = 0; s < 6; s++) {
        const float* __restrict__ in = segs.src[s];
        bf16* __restrict__ out = segs.dst[s];
        const int n = segs.n[s];
        for (int i = (blockIdx.x * 256 + threadIdx.x) * 4; i < n; i += gridDim.x * 256 * 4) {
            float4 v = *(const float4*)(in + i);
            out[i + 0] = (bf16)v.x; out[i + 1] = (bf16)v.y;
            out[i + 2] = (bf16)v.z; out[i + 3] = (bf16)v.w;
        }
    }
}

// ---------------- MFMA bf16 GEMM 64x64 tile (emb/head) ----------------
__global__ __launch_bounds__(256) void k_gemm(const bf16* __restrict__ A, int lda,
                                              const bf16* __restrict__ W, int ldw,
                                              const float* __restrict__ bias,
                                              float* __restrict__ out, bf16* __restrict__ outb,
                                              int N, int Kd, int useBias, int useOutb)
{
    __shared__ __align__(16) short As[64][72];
    __shared__ __align__(16) short Ws[64][72];

    const int tid  = threadIdx.x;
    const int lane = tid & 63, wid = tid >> 6;
    const int wm = wid >> 1, wn = wid & 1;
    const int row0 = blockIdx.y * 64, col0 = blockIdx.x * 64;
    const int quad = lane >> 4, l16 = lane & 15;

    f32x4 acc[2][2] = {};
    for (int k0 = 0; k0 < Kd; k0 += 64) {
        #pragma unroll
        for (int i = 0; i < 2; i++) {
            int id = tid + i * 256;
            int r = id >> 3, g = id & 7;
            *(uint4*)&As[r][g * 8] = *(const uint4*)(A + (size_t)(row0 + r) * lda + k0 + g * 8);
            *(uint4*)&Ws[r][g * 8] = *(const uint4*)(W + (size_t)(col0 + r) * ldw + k0 + g * 8);
        }
        __syncthreads();
        #pragma unroll
        for (int ks = 0; ks < 64; ks += 32) {
            short8 af[2], bfr[2];
            #pragma unroll
            for (int i = 0; i < 2; i++) af[i] = *(const short8*)&As[wm * 32 + i * 16 + l16][ks + quad * 8];
            #pragma unroll
            for (int j = 0; j < 2; j++) bfr[j] = *(const short8*)&Ws[wn * 32 + j * 16 + l16][ks + quad * 8];
            #pragma unroll
            for (int i = 0; i < 2; i++)
                #pragma unroll
                for (int j = 0; j < 2; j++)
                    acc[i][j] = __builtin_amdgcn_mfma_f32_16x16x32_bf16(af[i], bfr[j], acc[i][j], 0, 0, 0);
        }
        __syncthreads();
    }
    #pragma unroll
    for (int i = 0; i < 2; i++) {
        #pragma unroll
        for (int j = 0; j < 2; j++) {
            int gn = col0 + wn * 32 + j * 16 + l16;
            int gm0 = row0 + wm * 32 + i * 16 + quad * 4;
            #pragma unroll
            for (int r = 0; r < 4; r++) {
                float v = acc[i][j][r];
                if (useBias) v += bias[gn];
                size_t o = (size_t)(gm0 + r) * N + gn;
                out[o] = v;
                if (useOutb) outb[o] = (bf16)v;
            }
        }
    }
}

// ---------------- MFMA bf16 GEMM 128x128 tile + global_load_lds (in/out_proj) ----------------
// LDS rows are 128 B (exactly 32 banks) so a naive layout would make the 16 l16-lanes
// of each fragment read hit ONE bank (16-way conflict, 5.69x — m136). Fix: XOR swizzle.
// LDS[r][chunk c] holds global k-chunk c ^ (r&7); deposits stay contiguous (wave-uniform
// base + lane*16, as global_load_lds requires); reads index chunk (g ^ (r&7)).
__global__ __launch_bounds__(256) void k_gemm128(
    const bf16* __restrict__ A, int lda,
    const bf16* __restrict__ W, int ldw,
    float* __restrict__ out, bf16* __restrict__ outb,
    int N, int Kd, int useOutb)
{
    __shared__ __align__(16) short As[128][64];   // 16 KB, no pad (deposit-contiguous)
    __shared__ __align__(16) short Ws[128][64];

    const int tid  = threadIdx.x;
    const int lane = tid & 63, wid = tid >> 6;
    const int wm = wid >> 1, wn = wid & 1;
    const int row0 = blockIdx.y * 128, col0 = blockIdx.x * 128;
    const int quad = lane >> 4, l16 = lane & 15;
    const int lr = lane >> 3;                     // row within 8-row group (0..7)
    const int lkc = (lane & 7) ^ lr;              // XOR-swizzled k-chunk this lane loads
    const int lk = lkc * 8;                       // k-col offset (8 bf16 = 16 B)

    f32x4 acc[4][4] = {};

    for (int k0 = 0; k0 < Kd; k0 += 64) {
        #pragma unroll
        for (int j = 0; j < 4; j++) {
            int rg = (wid * 4 + j) * 8;           // wave-uniform row-group base (multiple of 8)
            const bf16* ga = A + (size_t)(row0 + rg + lr) * lda + k0 + lk;
            const bf16* gw = W + (size_t)(col0 + rg + lr) * ldw + k0 + lk;
            __builtin_amdgcn_global_load_lds(
                (const __attribute__((address_space(1))) void*)ga,
                (__attribute__((address_space(3))) void*)&As[rg][0], 16, 0, 0);
            __builtin_amdgcn_global_load_lds(
                (const __attribute__((address_space(1))) void*)gw,
                (__attribute__((address_space(3))) void*)&Ws[rg][0], 16, 0, 0);
        }
        __syncthreads();

        #pragma unroll
        for (int ks = 0; ks < 64; ks += 32) {
            const int g = (ks >> 3) + quad;       // global k-chunk wanted (0..7)
            short8 af[4], bfr[4];
            #pragma unroll
            for (int i = 0; i < 4; i++) {
                int r = wm * 64 + i * 16 + l16;
                af[i] = *(const short8*)&As[r][(g ^ (r & 7)) * 8];
            }
            #pragma unroll
            for (int j = 0; j < 4; j++) {
                int r = wn * 64 + j * 16 + l16;
                bfr[j] = *(const short8*)&Ws[r][(g ^ (r & 7)) * 8];
            }
            #pragma unroll
            for (int i = 0; i < 4; i++)
                #pragma unroll
                for (int j = 0; j < 4; j++)
                    acc[i][j] = __builtin_amdgcn_mfma_f32_16x16x32_bf16(af[i], bfr[j], acc[i][j], 0, 0, 0);
        }
        __syncthreads();
    }

    #pragma unroll
    for (int i = 0; i < 4; i++) {
        #pragma unroll
        for (int j = 0; j < 4; j++) {
            int gn = col0 + wn * 64 + j * 16 + l16;
            int gm0 = row0 + wm * 64 + i * 16 + quad * 4;
            #pragma unroll
            for (int r = 0; r < 4; r++) {
                float v = acc[i][j][r];
                size_t o = (size_t)(gm0 + r) * N + gn;
                out[o] = v;
                if (useOutb) outb[o] = (bf16)v;
            }
        }
    }
}

// ---------------- conv + silu, float4-vectorized; writes u (fp32) and ub (bf16) ----------------
__global__ __launch_bounds__(256) void k_conv(const float* __restrict__ xz,
                                              const float* __restrict__ cw,
                                              const float* __restrict__ cb,
                                              float* __restrict__ u,
                                              bf16* __restrict__ ub)
{
    const int NG = LSEQ * EDIM / 4;
    for (int g = blockIdx.x * 256 + threadIdx.x; g < NG; g += gridDim.x * 256) {
        int t = g / (EDIM / 4);
        int e4 = (g - t * (EDIM / 4)) * 4;
        float4 s = *(const float4*)(cb + e4);
        #pragma unroll
        for (int k = 0; k < KCONV; k++) {
            int tt = t - (KCONV - 1) + k;
            if (tt >= 0) {
                float4 xv = *(const float4*)(xz + (size_t)tt * (2 * EDIM) + e4);
                s.x += cw[(e4 + 0) * KCONV + k] * xv.x;
                s.y += cw[(e4 + 1) * KCONV + k] * xv.y;
                s.z += cw[(e4 + 2) * KCONV + k] * xv.z;
                s.w += cw[(e4 + 3) * KCONV + k] * xv.w;
            }
        }
        float4 uv;
        uv.x = siluf(s.x); uv.y = siluf(s.y); uv.z = siluf(s.z); uv.w = siluf(s.w);
        size_t o = (size_t)t * EDIM + e4;
        *(float4*)(u + o) = uv;
        bf16 tmp[4] = {(bf16)uv.x, (bf16)uv.y, (bf16)uv.z, (bf16)uv.w};
        *(uint2*)(ub + o) = *(const uint2*)tmp;
    }
}

// ---------------- x_proj: bf16 MFMA 64-tile, split-K=4, fp32 partials ----------------
__global__ __launch_bounds__(256) void k_xproj_mfma(
    const bf16* __restrict__ A,   // ub [1024][1536]
    const bf16* __restrict__ W,   // xwb [80][1536]
    float* __restrict__ part)     // [XSPLIT][1024][80]
{
    __shared__ __align__(16) short As[64][72];
    __shared__ __align__(16) short Ws[64][72];

    const int tid  = threadIdx.x;
    const int lane = tid & 63, wid = tid >> 6;
    const int wm = wid >> 1, wn = wid & 1;
    const int row0 = blockIdx.y * 64, col0 = blockIdx.x * 64;
    const int quad = lane >> 4, l16 = lane & 15;
    const int kbase = blockIdx.z * XKCH;

    f32x4 acc[2][2] = {};
    for (int k0 = 0; k0 < XKCH; k0 += 64) {
        #pragma unroll
        for (int i = 0; i < 2; i++) {
            int id = tid + i * 256;
            int r = id >> 3, g = id & 7;
            *(uint4*)&As[r][g * 8] =
                *(const uint4*)(A + (size_t)(row0 + r) * EDIM + kbase + k0 + g * 8);
            uint4 wv = {0, 0, 0, 0};
            if (col0 + r < 80)
                wv = *(const uint4*)(W + (size_t)(col0 + r) * EDIM + kbase + k0 + g * 8);
            *(uint4*)&Ws[r][g * 8] = wv;
        }
        __syncthreads();
        #pragma unroll
        for (int ks = 0; ks < 64; ks += 32) {
            short8 af[2], bfr[2];
            #pragma unroll
            for (int i = 0; i < 2; i++) af[i] = *(const short8*)&As[wm * 32 + i * 16 + l16][ks + quad * 8];
            #pragma unroll
            for (int j = 0; j < 2; j++) bfr[j] = *(const short8*)&Ws[wn * 32 + j * 16 + l16][ks + quad * 8];
            #pragma unroll
            for (int i = 0; i < 2; i++)
                #pragma unroll
                for (int j = 0; j < 2; j++)
                    acc[i][j] = __builtin_amdgcn_mfma_f32_16x16x32_bf16(af[i], bfr[j], acc[i][j], 0, 0, 0);
        }
        __syncthreads();
    }

    float* pdst = part + (size_t)blockIdx.z * (LSEQ * 80);
    #pragma unroll
    for (int i = 0; i < 2; i++) {
        #pragma unroll
        for (int j = 0; j < 2; j++) {
            int gn = col0 + wn * 32 + j * 16 + l16;
            int gm0 = row0 + wm * 32 + i * 16 + quad * 4;
            if (gn < 80) {
                #pragma unroll
                for (int r = 0; r < 4; r++)
                    pdst[(size_t)(gm0 + r) * 80 + gn] = acc[i][j][r];
            }
        }
    }
}

// ---------------- dt GEMM fused with split-K reduce ----------------
__global__ __launch_bounds__(256) void k_dt_red(
    const float* __restrict__ part, const float* __restrict__ dtw,
    const float* __restrict__ dtbb, float* __restrict__ out,
    float* __restrict__ dbc)
{
    __shared__ float AsF[16][68];
    __shared__ float WsF[16][68];
    const int tid = threadIdx.x;
    const int tx = tid & 15, ty = tid >> 4;
    const int tx4 = tx * 4, ty4 = ty * 4;
    const int row0 = blockIdx.y * 64, col0 = blockIdx.x * 64;

    if (blockIdx.x == 0) {
        for (int idx = tid; idx < 64 * 32; idx += 256) {
            int m = idx >> 5, c = 48 + (idx & 31);
            size_t o = (size_t)(row0 + m) * 80 + c;
            float s = 0.f;
            #pragma unroll
            for (int p = 0; p < XSPLIT; p++) s += part[(size_t)p * (LSEQ * 80) + o];
            dbc[o] = s;
        }
    }

    float acc[4][4] = {};
    for (int k0 = 0; k0 < RDIM; k0 += 16) {
        #pragma unroll
        for (int i = 0; i < 4; i++) {
            int idx = tid + i * 256;
            int m = idx >> 4, kk = idx & 15;
            size_t o = (size_t)(row0 + m) * 80 + k0 + kk;
            float s = 0.f;
            #pragma unroll
            for (int p = 0; p < XSPLIT; p++) s += part[(size_t)p * (LSEQ * 80) + o];
            AsF[kk][m] = s;
        }
        #pragma unroll
        for (int i = 0; i < 4; i++) {
            int idx = tid + i * 256;
            int nn = idx >> 4, kk = idx & 15;
            WsF[kk][nn] = dtw[(size_t)(col0 + nn) * RDIM + k0 + kk];
        }
        __syncthreads();
        #pragma unroll
        for (int kk = 0; kk < 16; kk++) {
            float av[4], bv[4];
            #pragma unroll
            for (int i = 0; i < 4; i++) av[i] = AsF[kk][ty4 + i];
            #pragma unroll
            for (int j = 0; j < 4; j++) bv[j] = WsF[kk][tx4 + j];
            #pragma unroll
            for (int i = 0; i < 4; i++)
                #pragma unroll
                for (int j = 0; j < 4; j++)
                    acc[i][j] += av[i] * bv[j];
        }
        __syncthreads();
    }
    #pragma unroll
    for (int i = 0; i < 4; i++) {
        int gm = row0 + ty4 + i;
        #pragma unroll
        for (int j = 0; j < 4; j++) {
            int gn = col0 + tx4 + j;
            float v = acc[i][j] + dtbb[gn];
            out[(size_t)gm * EDIM + gn] = softplusf(v);
        }
    }
}

// ---------------- residual + rmsnorm ----------------
__global__ __launch_bounds__(256) void k_rms(const float* __restrict__ h, float* __restrict__ res,
                                             bf16* __restrict__ hnb, const float* __restrict__ w,
                                             int first)
{
    __shared__ float red[4];
    __shared__ float tot;
    const int tid = threadIdx.x;
    const int t = blockIdx.x;
    float v[3]; float ss = 0.f;
    #pragma unroll
    for (int r = 0; r < 3; r++) {
        int j = tid + r * 256;
        float xv = h[(size_t)t * HDIM + j];
        if (!first) xv += res[(size_t)t * HDIM + j];
        v[r] = xv;
        res[(size_t)t * HDIM + j] = xv;
        ss += xv * xv;
    }
    #pragma unroll
    for (int m = 32; m >= 1; m >>= 1) ss += __shfl_down(ss, m);
    int wid = tid >> 6;
    if ((tid & 63) == 0) red[wid] = ss;
    __syncthreads();
    if (tid == 0) tot = red[0] + red[1] + red[2] + red[3];
    __syncthreads();
    float scale = rsqrtf(tot / (float)HDIM + 1e-5f);
    #pragma unroll
    for (int r = 0; r < 3; r++) {
        int j = tid + r * 256;
        hnb[(size_t)t * HDIM + j] = (bf16)(v[r] * scale * w[j]);
    }
}

// ---------------- selective scan (thread per e, 16 states in regs) ----------------
__global__ __launch_bounds__(256) void k_scan1(const float* __restrict__ dt,
                                               const float* __restrict__ u,
                                               const float* __restrict__ dbc,
                                               const float* __restrict__ a_log,
                                               float* __restrict__ chunkS,
                                               float* __restrict__ sumdt)
{
    const int ex = blockIdx.x % 6, c = blockIdx.x / 6;
    const int e = ex * 256 + threadIdx.x;
    float A[16];
    #pragma unroll
    for (int q = 0; q < 4; q++) {
        float4 a4 = *(const float4*)(a_log + e * NDIM + q * 4);
        A[q*4+0] = -__expf(a4.x); A[q*4+1] = -__expf(a4.y);
        A[q*4+2] = -__expf(a4.z); A[q*4+3] = -__expf(a4.w);
    }
    float s[16] = {};
    float sd = 0.f;
    const int t0 = c * CHLEN;
    #pragma unroll
    for (int tt = 0; tt < CHLEN; tt++) {
        int t = t0 + tt;
        float dtv = dt[(size_t)t * EDIM + e];
        float uv  = u[(size_t)t * EDIM + e];
        float dtu = dtv * uv;
        sd += dtv;
        float4 B4[4];
        #pragma unroll
        for (int q = 0; q < 4; q++) B4[q] = *(const float4*)(dbc + (size_t)t * 80 + RDIM + q * 4);
        const float* B = (const float*)B4;
        #pragma unroll
        for (int n = 0; n < 16; n++) s[n] = s[n] * __expf(dtv * A[n]) + dtu * B[n];
    }
    float* cs = chunkS + ((size_t)c * EDIM + e) * NDIM;
    #pragma unroll
    for (int q = 0; q < 4; q++)
        *(float4*)(cs + q * 4) = make_float4(s[q*4+0], s[q*4+1], s[q*4+2], s[q*4+3]);
    sumdt[(size_t)c * EDIM + e] = sd;
}

__global__ __launch_bounds__(256) void k_scan2(const float* __restrict__ chunkS,
                                               const float* __restrict__ sumdt,
                                               const float* __restrict__ a_log,
                                               float* __restrict__ sInit)
{
    int gid = blockIdx.x * 256 + threadIdx.x;
    if (gid >= EDIM * NDIM) return;
    int n = gid & 15, e = gid >> 4;
    const float Aen = -__expf(a_log[gid]);
    float s = 0.f;
    for (int c = 0; c < NCHUNK; c++) {
        sInit[((size_t)c * EDIM + e) * NDIM + n] = s;
        float P = __expf(Aen * sumdt[(size_t)c * EDIM + e]);
        s = s * P + chunkS[((size_t)c * EDIM + e) * NDIM + n];
    }
}

__global__ __launch_bounds__(256) void k_scan3(const float* __restrict__ dt,
                                               const float* __restrict__ u,
                                               const float* __restrict__ dbc,
                                               const float* __restrict__ xz,
                                               const float* __restrict__ a_log,
                                               const float* __restrict__ Dp,
                                               const float* __restrict__ sInit,
                                               bf16* __restrict__ yzb)
{
    const int ex = blockIdx.x % 6, c = blockIdx.x / 6;
    const int e = ex * 256 + threadIdx.x;
    float A[16];
    #pragma unroll
    for (int q = 0; q < 4; q++) {
        float4 a4 = *(const float4*)(a_log + e * NDIM + q * 4);
        A[q*4+0] = -__expf(a4.x); A[q*4+1] = -__expf(a4.y);
        A[q*4+2] = -__expf(a4.z); A[q*4+3] = -__expf(a4.w);
    }
    const float dv = Dp[e];
    float s[16];
    const float* si = sInit + ((size_t)c * EDIM + e) * NDIM;
    #pragma unroll
    for (int q = 0; q < 4; q++) {
        float4 s4 = *(const float4*)(si + q * 4);
        s[q*4+0] = s4.x; s[q*4+1] = s4.y; s[q*4+2] = s4.z; s[q*4+3] = s4.w;
    }
    const int t0 = c * CHLEN;
    #pragma unroll
    for (int tt = 0; tt < CHLEN; tt++) {
        int t = t0 + tt;
        float dtv = dt[(size_t)t * EDIM + e];
        float uv  = u[(size_t)t * EDIM + e];
        float zv  = xz[(size_t)t * (2 * EDIM) + EDIM + e];
        float dtu = dtv * uv;
        float4 B4[4], C4[4];
        #pragma unroll
        for (int q = 0; q < 4; q++) {
            B4[q] = *(const float4*)(dbc + (size_t)t * 80 + RDIM + q * 4);
            C4[q] = *(const float4*)(dbc + (size_t)t * 80 + RDIM + NDIM + q * 4);
        }
        const float* B = (const float*)B4;
        const float* C = (const float*)C4;
        float y = 0.f;
        #pragma unroll
        for (int n = 0; n < 16; n++) {
            s[n] = s[n] * __expf(dtv * A[n]) + dtu * B[n];
            y += s[n] * C[n];
        }
        y += uv * dv;
        yzb[(size_t)t * EDIM + e] = (bf16)(y * siluf(zv));
    }
}

extern "C" void kernel_launch(void* const* d_in, const int* in_sizes, int n_in,
                              void* d_out, int out_size, void* d_ws, size_t ws_size,
                              hipStream_t stream)
{
    const float* x        = (const float*)d_in[0];
    const float* emb_w    = (const float*)d_in[1];
    const float* emb_b    = (const float*)d_in[2];
    const float* norm_w   = (const float*)d_in[3];
    const float* in_proj  = (const float*)d_in[4];
    const float* conv_w   = (const float*)d_in[5];
    const float* conv_b   = (const float*)d_in[6];
    const float* x_proj   = (const float*)d_in[7];
    const float* dt_w     = (const float*)d_in[8];
    const float* dt_b     = (const float*)d_in[9];
    const float* A_log    = (const float*)d_in[10];
    const float* Dp       = (const float*)d_in[11];
    const float* out_proj = (const float*)d_in[12];
    const float* head_w   = (const float*)d_in[13];
    const float* head_b   = (const float*)d_in[14];
    float* out = (float*)d_out;

    float* ws = (float*)d_ws;
    size_t off = 0;
    float* h      = ws + off; off += (size_t)LSEQ * HDIM;
    float* res    = ws + off; off += (size_t)LSEQ * HDIM;
    float* xz     = ws + off; off += (size_t)LSEQ * 2 * EDIM;
    float* u      = ws + off; off += (size_t)LSEQ * EDIM;
    float* dbc    = ws + off; off += (size_t)LSEQ * 80;
    float* part   = ws + off; off += (size_t)XSPLIT * LSEQ * 80;
    float* dtb    = ws + off; off += (size_t)LSEQ * EDIM;
    float* chunkS = ws + off; off += (size_t)NCHUNK * EDIM * NDIM;
    float* sumdt  = ws + off; off += (size_t)NCHUNK * EDIM;
    float* sInit  = ws + off; off += (size_t)NCHUNK * EDIM * NDIM;
    bf16* hnb     = (bf16*)(ws + off); off += (size_t)LSEQ * HDIM / 2;
    bf16* yzb     = (bf16*)(ws + off); off += (size_t)LSEQ * EDIM / 2;
    bf16* hb      = (bf16*)(ws + off); off += (size_t)LSEQ * HDIM / 2;
    bf16* ub      = (bf16*)(ws + off); off += (size_t)LSEQ * EDIM / 2;
    bf16* xb      = (bf16*)(ws + off); off += (size_t)LSEQ * SDIM / 2;
    bf16* emb_wb  = (bf16*)(ws + off); off += (size_t)HDIM * SDIM / 2;
    bf16* head_wb = (bf16*)(ws + off); off += (size_t)SDIM * HDIM / 2;
    bf16* in_wb   = (bf16*)(ws + off); off += (size_t)NLAYER * 2 * EDIM * HDIM / 2;
    bf16* out_wb  = (bf16*)(ws + off); off += (size_t)NLAYER * HDIM * EDIM / 2;
    bf16* xwb     = (bf16*)(ws + off); off += (size_t)NLAYER * 80 * EDIM / 2;

    // one launch: all fp32->bf16 conversions (x + all weights incl. x_proj, both layers)
    F2BSegs segs;
    segs.src[0] = x;        segs.dst[0] = xb;      segs.n[0] = LSEQ * SDIM;
    segs.src[1] = emb_w;    segs.dst[1] = emb_wb;  segs.n[1] = HDIM * SDIM;
    segs.src[2] = head_w;   segs.dst[2] = head_wb; segs.n[2] = SDIM * HDIM;
    segs.src[3] = in_proj;  segs.dst[3] = in_wb;   segs.n[3] = NLAYER * 2 * EDIM * HDIM;
    segs.src[4] = out_proj; segs.dst[4] = out_wb;  segs.n[4] = NLAYER * HDIM * EDIM;
    segs.src[5] = x_proj;   segs.dst[5] = xwb;     segs.n[5] = NLAYER * 80 * EDIM;
    f2b_all<<<1024, 256, 0, stream>>>(segs);

    // embed: h = x @ emb_w^T + emb_b  (N=768, K=256)
    k_gemm<<<dim3(12, 16), 256, 0, stream>>>(xb, SDIM, emb_wb, SDIM, emb_b,
                                             h, nullptr, HDIM, SDIM, 1, 0);

    for (int l = 0; l < NLAYER; l++) {
        const bf16*  inw  = in_wb  + (size_t)l * 2 * EDIM * HDIM;
        const bf16*  outw = out_wb + (size_t)l * HDIM * EDIM;
        const bf16*  xwbl = xwb    + (size_t)l * 80 * EDIM;
        const float* cw   = conv_w + (size_t)l * EDIM * KCONV;
        const float* cb   = conv_b + (size_t)l * EDIM;
        const float* dtw  = dt_w   + (size_t)l * EDIM * RDIM;
        const float* dtbb = dt_b   + (size_t)l * EDIM;
        const float* al   = A_log  + (size_t)l * EDIM * NDIM;
        const float* Dpl  = Dp     + (size_t)l * EDIM;

        k_rms<<<LSEQ, 256, 0, stream>>>(h, res, hnb, norm_w + (size_t)l * HDIM, l == 0);
        // in_proj: 128x128 tiles (swizzled LDS)
        k_gemm128<<<dim3(24, 8), 256, 0, stream>>>(hnb, HDIM, inw, HDIM,
                                                   xz, nullptr, 2 * EDIM, HDIM, 0);
        k_conv<<<1536, 256, 0, stream>>>(xz, cw, cb, u, ub);
        k_xproj_mfma<<<dim3(2, 16, XSPLIT), 256, 0, stream>>>(ub, xwbl, part);
        k_dt_red<<<dim3(24, 16), 256, 0, stream>>>(part, dtw, dtbb, dtb, dbc);
        k_scan1<<<6 * NCHUNK, 256, 0, stream>>>(dtb, u, dbc, al, chunkS, sumdt);
        k_scan2<<<96, 256, 0, stream>>>(chunkS, sumdt, al, sInit);
        k_scan3<<<6 * NCHUNK, 256, 0, stream>>>(dtb, u, dbc, xz, al, Dpl, sInit, yzb);
        // out_proj: 128x128 tiles (swizzled LDS)
        k_gemm128<<<dim3(6, 8), 256, 0, stream>>>(yzb, EDIM, outw, EDIM,
                                                  h, hb, HDIM, EDIM, (l == NLAYER - 1) ? 1 : 0);
    }

    // head: out = h @ head_w^T + head_b  (N=256, K=768)
    k_gemm<<<dim3(4, 16), 256, 0, stream>>>(hb, HDIM, head_wb, HDIM, head_b,
                                            out, nullptr, SDIM, HDIM, 1, 0);
}

// Round 16
// 375.721 us; speedup vs baseline: 1.3092x; 1.0662x over previous
//
#include <hip/hip_runtime.h>
#include <hip/hip_bf16.h>
#include <math.h>

// Problem dims
#define SDIM 256
#define HDIM 768
#define EDIM 1536
#define NDIM 16
#define KCONV 4
#define RDIM 48
#define NLAYER 2
#define LSEQ 1024

#define NCHUNK 128
#define CHLEN (LSEQ / NCHUNK)   // 8
#define XSPLIT 4
#define XKCH (EDIM / XSPLIT)    // 384

typedef __hip_bfloat16 bf16;
typedef __attribute__((ext_vector_type(8))) short short8;
typedef __attribute__((ext_vector_type(4))) float f32x4;

__device__ __forceinline__ float softplusf(float x) {
    return (x > 20.f) ? x : log1pf(expf(x));
}
__device__ __forceinline__ float siluf(float x) {
    return x / (1.f + expf(-x));
}

// ---------------- combined fp32 -> bf16 conversion: 6 segments, one launch ----------------
struct F2BSegs {
    const float* src[6];
    bf16*        dst[6];
    int          n[6];
};

__global__ __launch_bounds__(256) void f2b_all(F2BSegs segs)
{
    for (int s = 0; s < 6; s++) {
        const float* __restrict__ in = segs.src[s];
        bf16* __restrict__ out = segs.dst[s];
        const int n = segs.n[s];
        for (int i = (blockIdx.x * 256 + threadIdx.x) * 4; i < n; i += gridDim.x * 256 * 4) {
            float4 v = *(const float4*)(in + i);
            out[i + 0] = (bf16)v.x; out[i + 1] = (bf16)v.y;
            out[i + 2] = (bf16)v.z; out[i + 3] = (bf16)v.w;
        }
    }
}

// ---------------- MFMA bf16 GEMM 64x64 tile, split-K=2 (emb, out_proj) ----------------
// blockIdx.z = split; writes fp32 partials part[z][M][N]; bias added in z==0 only.
__global__ __launch_bounds__(256) void k_gemm_sk(const bf16* __restrict__ A, int lda,
                                                 const bf16* __restrict__ W, int ldw,
                                                 const float* __restrict__ bias,
                                                 float* __restrict__ part,
                                                 int N, int Kh, int useBias)
{
    __shared__ __align__(16) short As[64][72];
    __shared__ __align__(16) short Ws[64][72];

    const int tid  = threadIdx.x;
    const int lane = tid & 63, wid = tid >> 6;
    const int wm = wid >> 1, wn = wid & 1;
    const int row0 = blockIdx.y * 64, col0 = blockIdx.x * 64;
    const int quad = lane >> 4, l16 = lane & 15;
    const int kbase = blockIdx.z * Kh;

    f32x4 acc[2][2] = {};
    for (int k0 = 0; k0 < Kh; k0 += 64) {
        #pragma unroll
        for (int i = 0; i < 2; i++) {
            int id = tid + i * 256;
            int r = id >> 3, g = id & 7;
            *(uint4*)&As[r][g * 8] = *(const uint4*)(A + (size_t)(row0 + r) * lda + kbase + k0 + g * 8);
            *(uint4*)&Ws[r][g * 8] = *(const uint4*)(W + (size_t)(col0 + r) * ldw + kbase + k0 + g * 8);
        }
        __syncthreads();
        #pragma unroll
        for (int ks = 0; ks < 64; ks += 32) {
            short8 af[2], bfr[2];
            #pragma unroll
            for (int i = 0; i < 2; i++) af[i] = *(const short8*)&As[wm * 32 + i * 16 + l16][ks + quad * 8];
            #pragma unroll
            for (int j = 0; j < 2; j++) bfr[j] = *(const short8*)&Ws[wn * 32 + j * 16 + l16][ks + quad * 8];
            #pragma unroll
            for (int i = 0; i < 2; i++)
                #pragma unroll
                for (int j = 0; j < 2; j++)
                    acc[i][j] = __builtin_amdgcn_mfma_f32_16x16x32_bf16(af[i], bfr[j], acc[i][j], 0, 0, 0);
        }
        __syncthreads();
    }
    float* pdst = part + (size_t)blockIdx.z * LSEQ * N;
    #pragma unroll
    for (int i = 0; i < 2; i++) {
        #pragma unroll
        for (int j = 0; j < 2; j++) {
            int gn = col0 + wn * 32 + j * 16 + l16;
            int gm0 = row0 + wm * 32 + i * 16 + quad * 4;
            #pragma unroll
            for (int r = 0; r < 4; r++) {
                float v = acc[i][j][r];
                if (useBias && blockIdx.z == 0) v += bias[gn];
                pdst[(size_t)(gm0 + r) * N + gn] = v;
            }
        }
    }
}

// ---------------- head GEMM: A = sum of two fp32 partials, converted to bf16 in staging ----
__global__ __launch_bounds__(256) void k_gemm_h(const float* __restrict__ A0,
                                                const float* __restrict__ A1, int lda,
                                                const bf16* __restrict__ W, int ldw,
                                                const float* __restrict__ bias,
                                                float* __restrict__ out, int N, int Kd)
{
    __shared__ __align__(16) short As[64][72];
    __shared__ __align__(16) short Ws[64][72];

    const int tid  = threadIdx.x;
    const int lane = tid & 63, wid = tid >> 6;
    const int wm = wid >> 1, wn = wid & 1;
    const int row0 = blockIdx.y * 64, col0 = blockIdx.x * 64;
    const int quad = lane >> 4, l16 = lane & 15;

    f32x4 acc[2][2] = {};
    for (int k0 = 0; k0 < Kd; k0 += 64) {
        #pragma unroll
        for (int i = 0; i < 2; i++) {
            int id = tid + i * 256;
            int r = id >> 3, g = id & 7;
            size_t base = (size_t)(row0 + r) * lda + k0 + g * 8;
            float4 a0 = *(const float4*)(A0 + base);
            float4 a1 = *(const float4*)(A0 + base + 4);
            float4 b0 = *(const float4*)(A1 + base);
            float4 b1 = *(const float4*)(A1 + base + 4);
            bf16 tmp[8] = {(bf16)(a0.x + b0.x), (bf16)(a0.y + b0.y),
                           (bf16)(a0.z + b0.z), (bf16)(a0.w + b0.w),
                           (bf16)(a1.x + b1.x), (bf16)(a1.y + b1.y),
                           (bf16)(a1.z + b1.z), (bf16)(a1.w + b1.w)};
            *(uint4*)&As[r][g * 8] = *(const uint4*)tmp;
            *(uint4*)&Ws[r][g * 8] = *(const uint4*)(W + (size_t)(col0 + r) * ldw + k0 + g * 8);
        }
        __syncthreads();
        #pragma unroll
        for (int ks = 0; ks < 64; ks += 32) {
            short8 af[2], bfr[2];
            #pragma unroll
            for (int i = 0; i < 2; i++) af[i] = *(const short8*)&As[wm * 32 + i * 16 + l16][ks + quad * 8];
            #pragma unroll
            for (int j = 0; j < 2; j++) bfr[j] = *(const short8*)&Ws[wn * 32 + j * 16 + l16][ks + quad * 8];
            #pragma unroll
            for (int i = 0; i < 2; i++)
                #pragma unroll
                for (int j = 0; j < 2; j++)
                    acc[i][j] = __builtin_amdgcn_mfma_f32_16x16x32_bf16(af[i], bfr[j], acc[i][j], 0, 0, 0);
        }
        __syncthreads();
    }
    #pragma unroll
    for (int i = 0; i < 2; i++) {
        #pragma unroll
        for (int j = 0; j < 2; j++) {
            int gn = col0 + wn * 32 + j * 16 + l16;
            int gm0 = row0 + wm * 32 + i * 16 + quad * 4;
            #pragma unroll
            for (int r = 0; r < 4; r++)
                out[(size_t)(gm0 + r) * N + gn] = acc[i][j][r] + bias[gn];
        }
    }
}

// ---------------- MFMA bf16 GEMM 128x128 tile + global_load_lds, XOR swizzle (in_proj) ----
__global__ __launch_bounds__(256) void k_gemm128(
    const bf16* __restrict__ A, int lda,
    const bf16* __restrict__ W, int ldw,
    float* __restrict__ out, int N, int Kd)
{
    __shared__ __align__(16) short As[128][64];
    __shared__ __align__(16) short Ws[128][64];

    const int tid  = threadIdx.x;
    const int lane = tid & 63, wid = tid >> 6;
    const int wm = wid >> 1, wn = wid & 1;
    const int row0 = blockIdx.y * 128, col0 = blockIdx.x * 128;
    const int quad = lane >> 4, l16 = lane & 15;
    const int lr = lane >> 3;
    const int lk = ((lane & 7) ^ lr) * 8;

    f32x4 acc[4][4] = {};

    for (int k0 = 0; k0 < Kd; k0 += 64) {
        #pragma unroll
        for (int j = 0; j < 4; j++) {
            int rg = (wid * 4 + j) * 8;
            const bf16* ga = A + (size_t)(row0 + rg + lr) * lda + k0 + lk;
            const bf16* gw = W + (size_t)(col0 + rg + lr) * ldw + k0 + lk;
            __builtin_amdgcn_global_load_lds(
                (const __attribute__((address_space(1))) void*)ga,
                (__attribute__((address_space(3))) void*)&As[rg][0], 16, 0, 0);
            __builtin_amdgcn_global_load_lds(
                (const __attribute__((address_space(1))) void*)gw,
                (__attribute__((address_space(3))) void*)&Ws[rg][0], 16, 0, 0);
        }
        __syncthreads();

        #pragma unroll
        for (int ks = 0; ks < 64; ks += 32) {
            const int g = (ks >> 3) + quad;
            short8 af[4], bfr[4];
            #pragma unroll
            for (int i = 0; i < 4; i++) {
                int r = wm * 64 + i * 16 + l16;
                af[i] = *(const short8*)&As[r][(g ^ (r & 7)) * 8];
            }
            #pragma unroll
            for (int j = 0; j < 4; j++) {
                int r = wn * 64 + j * 16 + l16;
                bfr[j] = *(const short8*)&Ws[r][(g ^ (r & 7)) * 8];
            }
            #pragma unroll
            for (int i = 0; i < 4; i++)
                #pragma unroll
                for (int j = 0; j < 4; j++)
                    acc[i][j] = __builtin_amdgcn_mfma_f32_16x16x32_bf16(af[i], bfr[j], acc[i][j], 0, 0, 0);
        }
        __syncthreads();
    }

    #pragma unroll
    for (int i = 0; i < 4; i++) {
        #pragma unroll
        for (int j = 0; j < 4; j++) {
            int gn = col0 + wn * 64 + j * 16 + l16;
            int gm0 = row0 + wm * 64 + i * 16 + quad * 4;
            #pragma unroll
            for (int r = 0; r < 4; r++)
                out[(size_t)(gm0 + r) * N + gn] = acc[i][j][r];
        }
    }
}

// ---------------- conv + silu, float4-vectorized; writes u (fp32) and ub (bf16) ----------------
__global__ __launch_bounds__(256) void k_conv(const float* __restrict__ xz,
                                              const float* __restrict__ cw,
                                              const float* __restrict__ cb,
                                              float* __restrict__ u,
                                              bf16* __restrict__ ub)
{
    const int NG = LSEQ * EDIM / 4;
    for (int g = blockIdx.x * 256 + threadIdx.x; g < NG; g += gridDim.x * 256) {
        int t = g / (EDIM / 4);
        int e4 = (g - t * (EDIM / 4)) * 4;
        float4 s = *(const float4*)(cb + e4);
        #pragma unroll
        for (int k = 0; k < KCONV; k++) {
            int tt = t - (KCONV - 1) + k;
            if (tt >= 0) {
                float4 xv = *(const float4*)(xz + (size_t)tt * (2 * EDIM) + e4);
                s.x += cw[(e4 + 0) * KCONV + k] * xv.x;
                s.y += cw[(e4 + 1) * KCONV + k] * xv.y;
                s.z += cw[(e4 + 2) * KCONV + k] * xv.z;
                s.w += cw[(e4 + 3) * KCONV + k] * xv.w;
            }
        }
        float4 uv;
        uv.x = siluf(s.x); uv.y = siluf(s.y); uv.z = siluf(s.z); uv.w = siluf(s.w);
        size_t o = (size_t)t * EDIM + e4;
        *(float4*)(u + o) = uv;
        bf16 tmp[4] = {(bf16)uv.x, (bf16)uv.y, (bf16)uv.z, (bf16)uv.w};
        *(uint2*)(ub + o) = *(const uint2*)tmp;
    }
}

// ---------------- x_proj: bf16 MFMA 64-tile, split-K=4, fp32 partials ----------------
__global__ __launch_bounds__(256) void k_xproj_mfma(
    const bf16* __restrict__ A,
    const bf16* __restrict__ W,
    float* __restrict__ part)
{
    __shared__ __align__(16) short As[64][72];
    __shared__ __align__(16) short Ws[64][72];

    const int tid  = threadIdx.x;
    const int lane = tid & 63, wid = tid >> 6;
    const int wm = wid >> 1, wn = wid & 1;
    const int row0 = blockIdx.y * 64, col0 = blockIdx.x * 64;
    const int quad = lane >> 4, l16 = lane & 15;
    const int kbase = blockIdx.z * XKCH;

    f32x4 acc[2][2] = {};
    for (int k0 = 0; k0 < XKCH; k0 += 64) {
        #pragma unroll
        for (int i = 0; i < 2; i++) {
            int id = tid + i * 256;
            int r = id >> 3, g = id & 7;
            *(uint4*)&As[r][g * 8] =
                *(const uint4*)(A + (size_t)(row0 + r) * EDIM + kbase + k0 + g * 8);
            uint4 wv = {0, 0, 0, 0};
            if (col0 + r < 80)
                wv = *(const uint4*)(W + (size_t)(col0 + r) * EDIM + kbase + k0 + g * 8);
            *(uint4*)&Ws[r][g * 8] = wv;
        }
        __syncthreads();
        #pragma unroll
        for (int ks = 0; ks < 64; ks += 32) {
            short8 af[2], bfr[2];
            #pragma unroll
            for (int i = 0; i < 2; i++) af[i] = *(const short8*)&As[wm * 32 + i * 16 + l16][ks + quad * 8];
            #pragma unroll
            for (int j = 0; j < 2; j++) bfr[j] = *(const short8*)&Ws[wn * 32 + j * 16 + l16][ks + quad * 8];
            #pragma unroll
            for (int i = 0; i < 2; i++)
                #pragma unroll
                for (int j = 0; j < 2; j++)
                    acc[i][j] = __builtin_amdgcn_mfma_f32_16x16x32_bf16(af[i], bfr[j], acc[i][j], 0, 0, 0);
        }
        __syncthreads();
    }

    float* pdst = part + (size_t)blockIdx.z * (LSEQ * 80);
    #pragma unroll
    for (int i = 0; i < 2; i++) {
        #pragma unroll
        for (int j = 0; j < 2; j++) {
            int gn = col0 + wn * 32 + j * 16 + l16;
            int gm0 = row0 + wm * 32 + i * 16 + quad * 4;
            if (gn < 80) {
                #pragma unroll
                for (int r = 0; r < 4; r++)
                    pdst[(size_t)(gm0 + r) * 80 + gn] = acc[i][j][r];
            }
        }
    }
}

// ---------------- dt GEMM fused with split-K reduce ----------------
__global__ __launch_bounds__(256) void k_dt_red(
    const float* __restrict__ part, const float* __restrict__ dtw,
    const float* __restrict__ dtbb, float* __restrict__ out,
    float* __restrict__ dbc)
{
    __shared__ float AsF[16][68];
    __shared__ float WsF[16][68];
    const int tid = threadIdx.x;
    const int tx = tid & 15, ty = tid >> 4;
    const int tx4 = tx * 4, ty4 = ty * 4;
    const int row0 = blockIdx.y * 64, col0 = blockIdx.x * 64;

    if (blockIdx.x == 0) {
        for (int idx = tid; idx < 64 * 32; idx += 256) {
            int m = idx >> 5, c = 48 + (idx & 31);
            size_t o = (size_t)(row0 + m) * 80 + c;
            float s = 0.f;
            #pragma unroll
            for (int p = 0; p < XSPLIT; p++) s += part[(size_t)p * (LSEQ * 80) + o];
            dbc[o] = s;
        }
    }

    float acc[4][4] = {};
    for (int k0 = 0; k0 < RDIM; k0 += 16) {
        #pragma unroll
        for (int i = 0; i < 4; i++) {
            int idx = tid + i * 256;
            int m = idx >> 4, kk = idx & 15;
            size_t o = (size_t)(row0 + m) * 80 + k0 + kk;
            float s = 0.f;
            #pragma unroll
            for (int p = 0; p < XSPLIT; p++) s += part[(size_t)p * (LSEQ * 80) + o];
            AsF[kk][m] = s;
        }
        #pragma unroll
        for (int i = 0; i < 4; i++) {
            int idx = tid + i * 256;
            int nn = idx >> 4, kk = idx & 15;
            WsF[kk][nn] = dtw[(size_t)(col0 + nn) * RDIM + k0 + kk];
        }
        __syncthreads();
        #pragma unroll
        for (int kk = 0; kk < 16; kk++) {
            float av[4], bv[4];
            #pragma unroll
            for (int i = 0; i < 4; i++) av[i] = AsF[kk][ty4 + i];
            #pragma unroll
            for (int j = 0; j < 4; j++) bv[j] = WsF[kk][tx4 + j];
            #pragma unroll
            for (int i = 0; i < 4; i++)
                #pragma unroll
                for (int j = 0; j < 4; j++)
                    acc[i][j] += av[i] * bv[j];
        }
        __syncthreads();
    }
    #pragma unroll
    for (int i = 0; i < 4; i++) {
        int gm = row0 + ty4 + i;
        #pragma unroll
        for (int j = 0; j < 4; j++) {
            int gn = col0 + tx4 + j;
            float v = acc[i][j] + dtbb[gn];
            out[(size_t)gm * EDIM + gn] = softplusf(v);
        }
    }
}

// ---------------- residual + rmsnorm (h = h0 + h1 split-K partials) ----------------
__global__ __launch_bounds__(256) void k_rms(const float* __restrict__ h0,
                                             const float* __restrict__ h1,
                                             float* __restrict__ res,
                                             bf16* __restrict__ hnb, const float* __restrict__ w,
                                             int first)
{
    __shared__ float red[4];
    __shared__ float tot;
    const int tid = threadIdx.x;
    const int t = blockIdx.x;
    float v[3]; float ss = 0.f;
    #pragma unroll
    for (int r = 0; r < 3; r++) {
        int j = tid + r * 256;
        float xv = h0[(size_t)t * HDIM + j] + h1[(size_t)t * HDIM + j];
        if (!first) xv += res[(size_t)t * HDIM + j];
        v[r] = xv;
        res[(size_t)t * HDIM + j] = xv;
        ss += xv * xv;
    }
    #pragma unroll
    for (int m = 32; m >= 1; m >>= 1) ss += __shfl_down(ss, m);
    int wid = tid >> 6;
    if ((tid & 63) == 0) red[wid] = ss;
    __syncthreads();
    if (tid == 0) tot = red[0] + red[1] + red[2] + red[3];
    __syncthreads();
    float scale = rsqrtf(tot / (float)HDIM + 1e-5f);
    #pragma unroll
    for (int r = 0; r < 3; r++) {
        int j = tid + r * 256;
        hnb[(size_t)t * HDIM + j] = (bf16)(v[r] * scale * w[j]);
    }
}

// ---------------- selective scan (thread per e, 16 states in regs) ----------------
__global__ __launch_bounds__(256) void k_scan1(const float* __restrict__ dt,
                                               const float* __restrict__ u,
                                               const float* __restrict__ dbc,
                                               const float* __restrict__ a_log,
                                               float* __restrict__ chunkS,
                                               float* __restrict__ sumdt)
{
    const int ex = blockIdx.x % 6, c = blockIdx.x / 6;
    const int e = ex * 256 + threadIdx.x;
    float A[16];
    #pragma unroll
    for (int q = 0; q < 4; q++) {
        float4 a4 = *(const float4*)(a_log + e * NDIM + q * 4);
        A[q*4+0] = -__expf(a4.x); A[q*4+1] = -__expf(a4.y);
        A[q*4+2] = -__expf(a4.z); A[q*4+3] = -__expf(a4.w);
    }
    float s[16] = {};
    float sd = 0.f;
    const int t0 = c * CHLEN;
    #pragma unroll
    for (int tt = 0; tt < CHLEN; tt++) {
        int t = t0 + tt;
        float dtv = dt[(size_t)t * EDIM + e];
        float uv  = u[(size_t)t * EDIM + e];
        float dtu = dtv * uv;
        sd += dtv;
        float4 B4[4];
        #pragma unroll
        for (int q = 0; q < 4; q++) B4[q] = *(const float4*)(dbc + (size_t)t * 80 + RDIM + q * 4);
        const float* B = (const float*)B4;
        #pragma unroll
        for (int n = 0; n < 16; n++) s[n] = s[n] * __expf(dtv * A[n]) + dtu * B[n];
    }
    float* cs = chunkS + ((size_t)c * EDIM + e) * NDIM;
    #pragma unroll
    for (int q = 0; q < 4; q++)
        *(float4*)(cs + q * 4) = make_float4(s[q*4+0], s[q*4+1], s[q*4+2], s[q*4+3]);
    sumdt[(size_t)c * EDIM + e] = sd;
}

__global__ __launch_bounds__(256) void k_scan2(const float* __restrict__ chunkS,
                                               const float* __restrict__ sumdt,
                                               const float* __restrict__ a_log,
                                               float* __restrict__ sInit)
{
    int gid = blockIdx.x * 256 + threadIdx.x;
    if (gid >= EDIM * NDIM) return;
    int n = gid & 15, e = gid >> 4;
    const float Aen = -__expf(a_log[gid]);
    float s = 0.f;
    for (int c = 0; c < NCHUNK; c++) {
        sInit[((size_t)c * EDIM + e) * NDIM + n] = s;
        float P = __expf(Aen * sumdt[(size_t)c * EDIM + e]);
        s = s * P + chunkS[((size_t)c * EDIM + e) * NDIM + n];
    }
}

__global__ __launch_bounds__(256) void k_scan3(const float* __restrict__ dt,
                                               const float* __restrict__ u,
                                               const float* __restrict__ dbc,
                                               const float* __restrict__ xz,
                                               const float* __restrict__ a_log,
                                               const float* __restrict__ Dp,
                                               const float* __restrict__ sInit,
                                               bf16* __restrict__ yzb)
{
    const int ex = blockIdx.x % 6, c = blockIdx.x / 6;
    const int e = ex * 256 + threadIdx.x;
    float A[16];
    #pragma unroll
    for (int q = 0; q < 4; q++) {
        float4 a4 = *(const float4*)(a_log + e * NDIM + q * 4);
        A[q*4+0] = -__expf(a4.x); A[q*4+1] = -__expf(a4.y);
        A[q*4+2] = -__expf(a4.z); A[q*4+3] = -__expf(a4.w);
    }
    const float dv = Dp[e];
    float s[16];
    const float* si = sInit + ((size_t)c * EDIM + e) * NDIM;
    #pragma unroll
    for (int q = 0; q < 4; q++) {
        float4 s4 = *(const float4*)(si + q * 4);
        s[q*4+0] = s4.x; s[q*4+1] = s4.y; s[q*4+2] = s4.z; s[q*4+3] = s4.w;
    }
    const int t0 = c * CHLEN;
    #pragma unroll
    for (int tt = 0; tt < CHLEN; tt++) {
        int t = t0 + tt;
        float dtv = dt[(size_t)t * EDIM + e];
        float uv  = u[(size_t)t * EDIM + e];
        float zv  = xz[(size_t)t * (2 * EDIM) + EDIM + e];
        float dtu = dtv * uv;
        float4 B4[4], C4[4];
        #pragma unroll
        for (int q = 0; q < 4; q++) {
            B4[q] = *(const float4*)(dbc + (size_t)t * 80 + RDIM + q * 4);
            C4[q] = *(const float4*)(dbc + (size_t)t * 80 + RDIM + NDIM + q * 4);
        }
        const float* B = (const float*)B4;
        const float* C = (const float*)C4;
        float y = 0.f;
        #pragma unroll
        for (int n = 0; n < 16; n++) {
            s[n] = s[n] * __expf(dtv * A[n]) + dtu * B[n];
            y += s[n] * C[n];
        }
        y += uv * dv;
        yzb[(size_t)t * EDIM + e] = (bf16)(y * siluf(zv));
    }
}

extern "C" void kernel_launch(void* const* d_in, const int* in_sizes, int n_in,
                              void* d_out, int out_size, void* d_ws, size_t ws_size,
                              hipStream_t stream)
{
    const float* x        = (const float*)d_in[0];
    const float* emb_w    = (const float*)d_in[1];
    const float* emb_b    = (const float*)d_in[2];
    const float* norm_w   = (const float*)d_in[3];
    const float* in_proj  = (const float*)d_in[4];
    const float* conv_w   = (const float*)d_in[5];
    const float* conv_b   = (const float*)d_in[6];
    const float* x_proj   = (const float*)d_in[7];
    const float* dt_w     = (const float*)d_in[8];
    const float* dt_b     = (const float*)d_in[9];
    const float* A_log    = (const float*)d_in[10];
    const float* Dp       = (const float*)d_in[11];
    const float* out_proj = (const float*)d_in[12];
    const float* head_w   = (const float*)d_in[13];
    const float* head_b   = (const float*)d_in[14];
    float* out = (float*)d_out;

    float* ws = (float*)d_ws;
    size_t off = 0;
    float* hpart  = ws + off; off += (size_t)2 * LSEQ * HDIM;   // split-K partials (emb/out_proj)
    float* res    = ws + off; off += (size_t)LSEQ * HDIM;
    float* xz     = ws + off; off += (size_t)LSEQ * 2 * EDIM;
    float* u      = ws + off; off += (size_t)LSEQ * EDIM;
    float* dbc    = ws + off; off += (size_t)LSEQ * 80;
    float* part   = ws + off; off += (size_t)XSPLIT * LSEQ * 80;
    float* dtb    = ws + off; off += (size_t)LSEQ * EDIM;
    float* chunkS = ws + off; off += (size_t)NCHUNK * EDIM * NDIM;
    float* sumdt  = ws + off; off += (size_t)NCHUNK * EDIM;
    float* sInit  = ws + off; off += (size_t)NCHUNK * EDIM * NDIM;
    bf16* hnb     = (bf16*)(ws + off); off += (size_t)LSEQ * HDIM / 2;
    bf16* yzb     = (bf16*)(ws + off); off += (size_t)LSEQ * EDIM / 2;
    bf16* ub      = (bf16*)(ws + off); off += (size_t)LSEQ * EDIM / 2;
    bf16* xb      = (bf16*)(ws + off); off += (size_t)LSEQ * SDIM / 2;
    bf16* emb_wb  = (bf16*)(ws + off); off += (size_t)HDIM * SDIM / 2;
    bf16* head_wb = (bf16*)(ws + off); off += (size_t)SDIM * HDIM / 2;
    bf16* in_wb   = (bf16*)(ws + off); off += (size_t)NLAYER * 2 * EDIM * HDIM / 2;
    bf16* out_wb  = (bf16*)(ws + off); off += (size_t)NLAYER * HDIM * EDIM / 2;
    bf16* xwb     = (bf16*)(ws + off); off += (size_t)NLAYER * 80 * EDIM / 2;

    // one launch: all fp32->bf16 conversions
    F2BSegs segs;
    segs.src[0] = x;        segs.dst[0] = xb;      segs.n[0] = LSEQ * SDIM;
    segs.src[1] = emb_w;    segs.dst[1] = emb_wb;  segs.n[1] = HDIM * SDIM;
    segs.src[2] = head_w;   segs.dst[2] = head_wb; segs.n[2] = SDIM * HDIM;
    segs.src[3] = in_proj;  segs.dst[3] = in_wb;   segs.n[3] = NLAYER * 2 * EDIM * HDIM;
    segs.src[4] = out_proj; segs.dst[4] = out_wb;  segs.n[4] = NLAYER * HDIM * EDIM;
    segs.src[5] = x_proj;   segs.dst[5] = xwb;     segs.n[5] = NLAYER * 80 * EDIM;
    f2b_all<<<1024, 256, 0, stream>>>(segs);

    // embed: split-K=2 (Kh=128) -> hpart[2]; 384 blocks
    k_gemm_sk<<<dim3(12, 16, 2), 256, 0, stream>>>(xb, SDIM, emb_wb, SDIM, emb_b,
                                                   hpart, HDIM, SDIM / 2, 1);

    for (int l = 0; l < NLAYER; l++) {
        const bf16*  inw  = in_wb  + (size_t)l * 2 * EDIM * HDIM;
        const bf16*  outw = out_wb + (size_t)l * HDIM * EDIM;
        const bf16*  xwbl = xwb    + (size_t)l * 80 * EDIM;
        const float* cw   = conv_w + (size_t)l * EDIM * KCONV;
        const float* cb   = conv_b + (size_t)l * EDIM;
        const float* dtw  = dt_w   + (size_t)l * EDIM * RDIM;
        const float* dtbb = dt_b   + (size_t)l * EDIM;
        const float* al   = A_log  + (size_t)l * EDIM * NDIM;
        const float* Dpl  = Dp     + (size_t)l * EDIM;

        // rms sums the two hpart partials (+res)
        k_rms<<<LSEQ, 256, 0, stream>>>(hpart, hpart + (size_t)LSEQ * HDIM, res,
                                        hnb, norm_w + (size_t)l * HDIM, l == 0);
        // in_proj: 128x128 tiles (swizzled LDS + global_load_lds)
        k_gemm128<<<dim3(24, 8), 256, 0, stream>>>(hnb, HDIM, inw, HDIM,
                                                   xz, 2 * EDIM, HDIM);
        k_conv<<<1536, 256, 0, stream>>>(xz, cw, cb, u, ub);
        k_xproj_mfma<<<dim3(2, 16, XSPLIT), 256, 0, stream>>>(ub, xwbl, part);
        k_dt_red<<<dim3(24, 16), 256, 0, stream>>>(part, dtw, dtbb, dtb, dbc);
        k_scan1<<<6 * NCHUNK, 256, 0, stream>>>(dtb, u, dbc, al, chunkS, sumdt);
        k_scan2<<<96, 256, 0, stream>>>(chunkS, sumdt, al, sInit);
        k_scan3<<<6 * NCHUNK, 256, 0, stream>>>(dtb, u, dbc, xz, al, Dpl, sInit, yzb);
        // out_proj: split-K=2 (Kh=768) -> hpart[2]; 384 blocks
        k_gemm_sk<<<dim3(12, 16, 2), 256, 0, stream>>>(yzb, EDIM, outw, EDIM, nullptr,
                                                       hpart, HDIM, EDIM / 2, 0);
    }

    // head: A = hpart0 + hpart1, converted to bf16 in staging
    k_gemm_h<<<dim3(4, 16), 256, 0, stream>>>(hpart, hpart + (size_t)LSEQ * HDIM, HDIM,
                                              head_wb, HDIM, head_b, out, SDIM, HDIM);
}

// Round 17
// 372.599 us; speedup vs baseline: 1.3201x; 1.0084x over previous
//
#include <hip/hip_runtime.h>
#include <hip/hip_bf16.h>
#include <math.h>

// Problem dims
#define SDIM 256
#define HDIM 768
#define EDIM 1536
#define NDIM 16
#define KCONV 4
#define RDIM 48
#define NLAYER 2
#define LSEQ 1024

#define NCHUNK 64
#define CHLEN (LSEQ / NCHUNK)   // 16
#define XSPLIT 4
#define XKCH (EDIM / XSPLIT)    // 384

typedef __hip_bfloat16 bf16;
typedef __attribute__((ext_vector_type(8))) short short8;
typedef __attribute__((ext_vector_type(4))) float f32x4;

__device__ __forceinline__ float softplusf(float x) {
    return (x > 20.f) ? x : log1pf(expf(x));
}
__device__ __forceinline__ float siluf(float x) {
    return x / (1.f + expf(-x));
}

// ---------------- combined fp32 -> bf16 conversion: 6 segments, one launch ----------------
struct F2BSegs {
    const float* src[6];
    bf16*        dst[6];
    int          n[6];
};

__global__ __launch_bounds__(256) void f2b_all(F2BSegs segs)
{
    for (int s = 0; s < 6; s++) {
        const float* __restrict__ in = segs.src[s];
        bf16* __restrict__ out = segs.dst[s];
        const int n = segs.n[s];
        for (int i = (blockIdx.x * 256 + threadIdx.x) * 4; i < n; i += gridDim.x * 256 * 4) {
            float4 v = *(const float4*)(in + i);
            out[i + 0] = (bf16)v.x; out[i + 1] = (bf16)v.y;
            out[i + 2] = (bf16)v.z; out[i + 3] = (bf16)v.w;
        }
    }
}

// ---------------- MFMA bf16 GEMM 64x64 tile, split-K=2 (emb, in_proj, out_proj) --------
// blockIdx.z = split; writes fp32 partials part[z][M][N]; bias added in z==0 only.
__global__ __launch_bounds__(256) void k_gemm_sk(const bf16* __restrict__ A, int lda,
                                                 const bf16* __restrict__ W, int ldw,
                                                 const float* __restrict__ bias,
                                                 float* __restrict__ part,
                                                 int N, int Kh, int useBias)
{
    __shared__ __align__(16) short As[64][72];
    __shared__ __align__(16) short Ws[64][72];

    const int tid  = threadIdx.x;
    const int lane = tid & 63, wid = tid >> 6;
    const int wm = wid >> 1, wn = wid & 1;
    const int row0 = blockIdx.y * 64, col0 = blockIdx.x * 64;
    const int quad = lane >> 4, l16 = lane & 15;
    const int kbase = blockIdx.z * Kh;

    f32x4 acc[2][2] = {};
    for (int k0 = 0; k0 < Kh; k0 += 64) {
        #pragma unroll
        for (int i = 0; i < 2; i++) {
            int id = tid + i * 256;
            int r = id >> 3, g = id & 7;
            *(uint4*)&As[r][g * 8] = *(const uint4*)(A + (size_t)(row0 + r) * lda + kbase + k0 + g * 8);
            *(uint4*)&Ws[r][g * 8] = *(const uint4*)(W + (size_t)(col0 + r) * ldw + kbase + k0 + g * 8);
        }
        __syncthreads();
        #pragma unroll
        for (int ks = 0; ks < 64; ks += 32) {
            short8 af[2], bfr[2];
            #pragma unroll
            for (int i = 0; i < 2; i++) af[i] = *(const short8*)&As[wm * 32 + i * 16 + l16][ks + quad * 8];
            #pragma unroll
            for (int j = 0; j < 2; j++) bfr[j] = *(const short8*)&Ws[wn * 32 + j * 16 + l16][ks + quad * 8];
            #pragma unroll
            for (int i = 0; i < 2; i++)
                #pragma unroll
                for (int j = 0; j < 2; j++)
                    acc[i][j] = __builtin_amdgcn_mfma_f32_16x16x32_bf16(af[i], bfr[j], acc[i][j], 0, 0, 0);
        }
        __syncthreads();
    }
    float* pdst = part + (size_t)blockIdx.z * LSEQ * N;
    #pragma unroll
    for (int i = 0; i < 2; i++) {
        #pragma unroll
        for (int j = 0; j < 2; j++) {
            int gn = col0 + wn * 32 + j * 16 + l16;
            int gm0 = row0 + wm * 32 + i * 16 + quad * 4;
            #pragma unroll
            for (int r = 0; r < 4; r++) {
                float v = acc[i][j][r];
                if (useBias && blockIdx.z == 0) v += bias[gn];
                pdst[(size_t)(gm0 + r) * N + gn] = v;
            }
        }
    }
}

// ---------------- head GEMM: A = sum of two fp32 partials, converted to bf16 in staging ----
__global__ __launch_bounds__(256) void k_gemm_h(const float* __restrict__ A0,
                                                const float* __restrict__ A1, int lda,
                                                const bf16* __restrict__ W, int ldw,
                                                const float* __restrict__ bias,
                                                float* __restrict__ out, int N, int Kd)
{
    __shared__ __align__(16) short As[64][72];
    __shared__ __align__(16) short Ws[64][72];

    const int tid  = threadIdx.x;
    const int lane = tid & 63, wid = tid >> 6;
    const int wm = wid >> 1, wn = wid & 1;
    const int row0 = blockIdx.y * 64, col0 = blockIdx.x * 64;
    const int quad = lane >> 4, l16 = lane & 15;

    f32x4 acc[2][2] = {};
    for (int k0 = 0; k0 < Kd; k0 += 64) {
        #pragma unroll
        for (int i = 0; i < 2; i++) {
            int id = tid + i * 256;
            int r = id >> 3, g = id & 7;
            size_t base = (size_t)(row0 + r) * lda + k0 + g * 8;
            float4 a0 = *(const float4*)(A0 + base);
            float4 a1 = *(const float4*)(A0 + base + 4);
            float4 b0 = *(const float4*)(A1 + base);
            float4 b1 = *(const float4*)(A1 + base + 4);
            bf16 tmp[8] = {(bf16)(a0.x + b0.x), (bf16)(a0.y + b0.y),
                           (bf16)(a0.z + b0.z), (bf16)(a0.w + b0.w),
                           (bf16)(a1.x + b1.x), (bf16)(a1.y + b1.y),
                           (bf16)(a1.z + b1.z), (bf16)(a1.w + b1.w)};
            *(uint4*)&As[r][g * 8] = *(const uint4*)tmp;
            *(uint4*)&Ws[r][g * 8] = *(const uint4*)(W + (size_t)(col0 + r) * ldw + k0 + g * 8);
        }
        __syncthreads();
        #pragma unroll
        for (int ks = 0; ks < 64; ks += 32) {
            short8 af[2], bfr[2];
            #pragma unroll
            for (int i = 0; i < 2; i++) af[i] = *(const short8*)&As[wm * 32 + i * 16 + l16][ks + quad * 8];
            #pragma unroll
            for (int j = 0; j < 2; j++) bfr[j] = *(const short8*)&Ws[wn * 32 + j * 16 + l16][ks + quad * 8];
            #pragma unroll
            for (int i = 0; i < 2; i++)
                #pragma unroll
                for (int j = 0; j < 2; j++)
                    acc[i][j] = __builtin_amdgcn_mfma_f32_16x16x32_bf16(af[i], bfr[j], acc[i][j], 0, 0, 0);
        }
        __syncthreads();
    }
    #pragma unroll
    for (int i = 0; i < 2; i++) {
        #pragma unroll
        for (int j = 0; j < 2; j++) {
            int gn = col0 + wn * 32 + j * 16 + l16;
            int gm0 = row0 + wm * 32 + i * 16 + quad * 4;
            #pragma unroll
            for (int r = 0; r < 4; r++)
                out[(size_t)(gm0 + r) * N + gn] = acc[i][j][r] + bias[gn];
        }
    }
}

// ---------------- conv + silu: xin = xzp0 + xzp1 (in_proj split-K partials); writes ub ----
__global__ __launch_bounds__(256) void k_conv(const float* __restrict__ xzp0,
                                              const float* __restrict__ xzp1,
                                              const float* __restrict__ cw,
                                              const float* __restrict__ cb,
                                              bf16* __restrict__ ub)
{
    const int NG = LSEQ * EDIM / 4;
    for (int g = blockIdx.x * 256 + threadIdx.x; g < NG; g += gridDim.x * 256) {
        int t = g / (EDIM / 4);
        int e4 = (g - t * (EDIM / 4)) * 4;
        float4 s = *(const float4*)(cb + e4);
        #pragma unroll
        for (int k = 0; k < KCONV; k++) {
            int tt = t - (KCONV - 1) + k;
            if (tt >= 0) {
                size_t o = (size_t)tt * (2 * EDIM) + e4;
                float4 xa = *(const float4*)(xzp0 + o);
                float4 xb2 = *(const float4*)(xzp1 + o);
                s.x += cw[(e4 + 0) * KCONV + k] * (xa.x + xb2.x);
                s.y += cw[(e4 + 1) * KCONV + k] * (xa.y + xb2.y);
                s.z += cw[(e4 + 2) * KCONV + k] * (xa.z + xb2.z);
                s.w += cw[(e4 + 3) * KCONV + k] * (xa.w + xb2.w);
            }
        }
        bf16 tmp[4] = {(bf16)siluf(s.x), (bf16)siluf(s.y), (bf16)siluf(s.z), (bf16)siluf(s.w)};
        *(uint2*)(ub + (size_t)t * EDIM + e4) = *(const uint2*)tmp;
    }
}

// ---------------- x_proj: bf16 MFMA 64-tile, split-K=4, fp32 partials ----------------
__global__ __launch_bounds__(256) void k_xproj_mfma(
    const bf16* __restrict__ A,
    const bf16* __restrict__ W,
    float* __restrict__ part)
{
    __shared__ __align__(16) short As[64][72];
    __shared__ __align__(16) short Ws[64][72];

    const int tid  = threadIdx.x;
    const int lane = tid & 63, wid = tid >> 6;
    const int wm = wid >> 1, wn = wid & 1;
    const int row0 = blockIdx.y * 64, col0 = blockIdx.x * 64;
    const int quad = lane >> 4, l16 = lane & 15;
    const int kbase = blockIdx.z * XKCH;

    f32x4 acc[2][2] = {};
    for (int k0 = 0; k0 < XKCH; k0 += 64) {
        #pragma unroll
        for (int i = 0; i < 2; i++) {
            int id = tid + i * 256;
            int r = id >> 3, g = id & 7;
            *(uint4*)&As[r][g * 8] =
                *(const uint4*)(A + (size_t)(row0 + r) * EDIM + kbase + k0 + g * 8);
            uint4 wv = {0, 0, 0, 0};
            if (col0 + r < 80)
                wv = *(const uint4*)(W + (size_t)(col0 + r) * EDIM + kbase + k0 + g * 8);
            *(uint4*)&Ws[r][g * 8] = wv;
        }
        __syncthreads();
        #pragma unroll
        for (int ks = 0; ks < 64; ks += 32) {
            short8 af[2], bfr[2];
            #pragma unroll
            for (int i = 0; i < 2; i++) af[i] = *(const short8*)&As[wm * 32 + i * 16 + l16][ks + quad * 8];
            #pragma unroll
            for (int j = 0; j < 2; j++) bfr[j] = *(const short8*)&Ws[wn * 32 + j * 16 + l16][ks + quad * 8];
            #pragma unroll
            for (int i = 0; i < 2; i++)
                #pragma unroll
                for (int j = 0; j < 2; j++)
                    acc[i][j] = __builtin_amdgcn_mfma_f32_16x16x32_bf16(af[i], bfr[j], acc[i][j], 0, 0, 0);
        }
        __syncthreads();
    }

    float* pdst = part + (size_t)blockIdx.z * (LSEQ * 80);
    #pragma unroll
    for (int i = 0; i < 2; i++) {
        #pragma unroll
        for (int j = 0; j < 2; j++) {
            int gn = col0 + wn * 32 + j * 16 + l16;
            int gm0 = row0 + wm * 32 + i * 16 + quad * 4;
            if (gn < 80) {
                #pragma unroll
                for (int r = 0; r < 4; r++)
                    pdst[(size_t)(gm0 + r) * 80 + gn] = acc[i][j][r];
            }
        }
    }
}

// ---------------- dt GEMM fused with split-K reduce ----------------
__global__ __launch_bounds__(256) void k_dt_red(
    const float* __restrict__ part, const float* __restrict__ dtw,
    const float* __restrict__ dtbb, float* __restrict__ out,
    float* __restrict__ dbc)
{
    __shared__ float AsF[16][68];
    __shared__ float WsF[16][68];
    const int tid = threadIdx.x;
    const int tx = tid & 15, ty = tid >> 4;
    const int tx4 = tx * 4, ty4 = ty * 4;
    const int row0 = blockIdx.y * 64, col0 = blockIdx.x * 64;

    if (blockIdx.x == 0) {
        for (int idx = tid; idx < 64 * 32; idx += 256) {
            int m = idx >> 5, c = 48 + (idx & 31);
            size_t o = (size_t)(row0 + m) * 80 + c;
            float s = 0.f;
            #pragma unroll
            for (int p = 0; p < XSPLIT; p++) s += part[(size_t)p * (LSEQ * 80) + o];
            dbc[o] = s;
        }
    }

    float acc[4][4] = {};
    for (int k0 = 0; k0 < RDIM; k0 += 16) {
        #pragma unroll
        for (int i = 0; i < 4; i++) {
            int idx = tid + i * 256;
            int m = idx >> 4, kk = idx & 15;
            size_t o = (size_t)(row0 + m) * 80 + k0 + kk;
            float s = 0.f;
            #pragma unroll
            for (int p = 0; p < XSPLIT; p++) s += part[(size_t)p * (LSEQ * 80) + o];
            AsF[kk][m] = s;
        }
        #pragma unroll
        for (int i = 0; i < 4; i++) {
            int idx = tid + i * 256;
            int nn = idx >> 4, kk = idx & 15;
            WsF[kk][nn] = dtw[(size_t)(col0 + nn) * RDIM + k0 + kk];
        }
        __syncthreads();
        #pragma unroll
        for (int kk = 0; kk < 16; kk++) {
            float av[4], bv[4];
            #pragma unroll
            for (int i = 0; i < 4; i++) av[i] = AsF[kk][ty4 + i];
            #pragma unroll
            for (int j = 0; j < 4; j++) bv[j] = WsF[kk][tx4 + j];
            #pragma unroll
            for (int i = 0; i < 4; i++)
                #pragma unroll
                for (int j = 0; j < 4; j++)
                    acc[i][j] += av[i] * bv[j];
        }
        __syncthreads();
    }
    #pragma unroll
    for (int i = 0; i < 4; i++) {
        int gm = row0 + ty4 + i;
        #pragma unroll
        for (int j = 0; j < 4; j++) {
            int gn = col0 + tx4 + j;
            float v = acc[i][j] + dtbb[gn];
            out[(size_t)gm * EDIM + gn] = softplusf(v);
        }
    }
}

// ---------------- residual + rmsnorm (h = h0 + h1 split-K partials) ----------------
__global__ __launch_bounds__(256) void k_rms(const float* __restrict__ h0,
                                             const float* __restrict__ h1,
                                             float* __restrict__ res,
                                             bf16* __restrict__ hnb, const float* __restrict__ w,
                                             int first)
{
    __shared__ float red[4];
    __shared__ float tot;
    const int tid = threadIdx.x;
    const int t = blockIdx.x;
    float v[3]; float ss = 0.f;
    #pragma unroll
    for (int r = 0; r < 3; r++) {
        int j = tid + r * 256;
        float xv = h0[(size_t)t * HDIM + j] + h1[(size_t)t * HDIM + j];
        if (!first) xv += res[(size_t)t * HDIM + j];
        v[r] = xv;
        res[(size_t)t * HDIM + j] = xv;
        ss += xv * xv;
    }
    #pragma unroll
    for (int m = 32; m >= 1; m >>= 1) ss += __shfl_down(ss, m);
    int wid = tid >> 6;
    if ((tid & 63) == 0) red[wid] = ss;
    __syncthreads();
    if (tid == 0) tot = red[0] + red[1] + red[2] + red[3];
    __syncthreads();
    float scale = rsqrtf(tot / (float)HDIM + 1e-5f);
    #pragma unroll
    for (int r = 0; r < 3; r++) {
        int j = tid + r * 256;
        hnb[(size_t)t * HDIM + j] = (bf16)(v[r] * scale * w[j]);
    }
}

// ---------------- selective scan (thread per e, 16 states in regs; u in bf16) ----------
__global__ __launch_bounds__(256) void k_scan1(const float* __restrict__ dt,
                                               const bf16* __restrict__ ub,
                                               const float* __restrict__ dbc,
                                               const float* __restrict__ a_log,
                                               float* __restrict__ chunkS,
                                               float* __restrict__ sumdt)
{
    const int ex = blockIdx.x % 6, c = blockIdx.x / 6;
    const int e = ex * 256 + threadIdx.x;
    float A[16];
    #pragma unroll
    for (int q = 0; q < 4; q++) {
        float4 a4 = *(const float4*)(a_log + e * NDIM + q * 4);
        A[q*4+0] = -__expf(a4.x); A[q*4+1] = -__expf(a4.y);
        A[q*4+2] = -__expf(a4.z); A[q*4+3] = -__expf(a4.w);
    }
    float s[16] = {};
    float sd = 0.f;
    const int t0 = c * CHLEN;
    #pragma unroll 2
    for (int tt = 0; tt < CHLEN; tt++) {
        int t = t0 + tt;
        float dtv = dt[(size_t)t * EDIM + e];
        float uv  = (float)ub[(size_t)t * EDIM + e];
        float dtu = dtv * uv;
        sd += dtv;
        float4 B4[4];
        #pragma unroll
        for (int q = 0; q < 4; q++) B4[q] = *(const float4*)(dbc + (size_t)t * 80 + RDIM + q * 4);
        const float* B = (const float*)B4;
        #pragma unroll
        for (int n = 0; n < 16; n++) s[n] = s[n] * __expf(dtv * A[n]) + dtu * B[n];
    }
    float* cs = chunkS + ((size_t)c * EDIM + e) * NDIM;
    #pragma unroll
    for (int q = 0; q < 4; q++)
        *(float4*)(cs + q * 4) = make_float4(s[q*4+0], s[q*4+1], s[q*4+2], s[q*4+3]);
    sumdt[(size_t)c * EDIM + e] = sd;
}

__global__ __launch_bounds__(256) void k_scan2(const float* __restrict__ chunkS,
                                               const float* __restrict__ sumdt,
                                               const float* __restrict__ a_log,
                                               float* __restrict__ sInit)
{
    int gid = blockIdx.x * 256 + threadIdx.x;
    if (gid >= EDIM * NDIM) return;
    int n = gid & 15, e = gid >> 4;
    const float Aen = -__expf(a_log[gid]);
    float s = 0.f;
    for (int c = 0; c < NCHUNK; c++) {
        sInit[((size_t)c * EDIM + e) * NDIM + n] = s;
        float P = __expf(Aen * sumdt[(size_t)c * EDIM + e]);
        s = s * P + chunkS[((size_t)c * EDIM + e) * NDIM + n];
    }
}

__global__ __launch_bounds__(256) void k_scan3(const float* __restrict__ dt,
                                               const bf16* __restrict__ ub,
                                               const float* __restrict__ dbc,
                                               const float* __restrict__ xzp0,
                                               const float* __restrict__ xzp1,
                                               const float* __restrict__ a_log,
                                               const float* __restrict__ Dp,
                                               const float* __restrict__ sInit,
                                               bf16* __restrict__ yzb)
{
    const int ex = blockIdx.x % 6, c = blockIdx.x / 6;
    const int e = ex * 256 + threadIdx.x;
    float A[16];
    #pragma unroll
    for (int q = 0; q < 4; q++) {
        float4 a4 = *(const float4*)(a_log + e * NDIM + q * 4);
        A[q*4+0] = -__expf(a4.x); A[q*4+1] = -__expf(a4.y);
        A[q*4+2] = -__expf(a4.z); A[q*4+3] = -__expf(a4.w);
    }
    const float dv = Dp[e];
    float s[16];
    const float* si = sInit + ((size_t)c * EDIM + e) * NDIM;
    #pragma unroll
    for (int q = 0; q < 4; q++) {
        float4 s4 = *(const float4*)(si + q * 4);
        s[q*4+0] = s4.x; s[q*4+1] = s4.y; s[q*4+2] = s4.z; s[q*4+3] = s4.w;
    }
    const int t0 = c * CHLEN;
    #pragma unroll 2
    for (int tt = 0; tt < CHLEN; tt++) {
        int t = t0 + tt;
        float dtv = dt[(size_t)t * EDIM + e];
        float uv  = (float)ub[(size_t)t * EDIM + e];
        size_t zo = (size_t)t * (2 * EDIM) + EDIM + e;
        float zv  = xzp0[zo] + xzp1[zo];
        float dtu = dtv * uv;
        float4 B4[4], C4[4];
        #pragma unroll
        for (int q = 0; q < 4; q++) {
            B4[q] = *(const float4*)(dbc + (size_t)t * 80 + RDIM + q * 4);
            C4[q] = *(const float4*)(dbc + (size_t)t * 80 + RDIM + NDIM + q * 4);
        }
        const float* B = (const float*)B4;
        const float* C = (const float*)C4;
        float y = 0.f;
        #pragma unroll
        for (int n = 0; n < 16; n++) {
            s[n] = s[n] * __expf(dtv * A[n]) + dtu * B[n];
            y += s[n] * C[n];
        }
        y += uv * dv;
        yzb[(size_t)t * EDIM + e] = (bf16)(y * siluf(zv));
    }
}

extern "C" void kernel_launch(void* const* d_in, const int* in_sizes, int n_in,
                              void* d_out, int out_size, void* d_ws, size_t ws_size,
                              hipStream_t stream)
{
    const float* x        = (const float*)d_in[0];
    const float* emb_w    = (const float*)d_in[1];
    const float* emb_b    = (const float*)d_in[2];
    const float* norm_w   = (const float*)d_in[3];
    const float* in_proj  = (const float*)d_in[4];
    const float* conv_w   = (const float*)d_in[5];
    const float* conv_b   = (const float*)d_in[6];
    const float* x_proj   = (const float*)d_in[7];
    const float* dt_w     = (const float*)d_in[8];
    const float* dt_b     = (const float*)d_in[9];
    const float* A_log    = (const float*)d_in[10];
    const float* Dp       = (const float*)d_in[11];
    const float* out_proj = (const float*)d_in[12];
    const float* head_w   = (const float*)d_in[13];
    const float* head_b   = (const float*)d_in[14];
    float* out = (float*)d_out;

    float* ws = (float*)d_ws;
    size_t off = 0;
    float* hpart  = ws + off; off += (size_t)2 * LSEQ * HDIM;      // emb/out_proj split-K partials
    float* xzpart = ws + off; off += (size_t)2 * LSEQ * 2 * EDIM;  // in_proj split-K partials
    float* res    = ws + off; off += (size_t)LSEQ * HDIM;
    float* dbc    = ws + off; off += (size_t)LSEQ * 80;
    float* part   = ws + off; off += (size_t)XSPLIT * LSEQ * 80;
    float* dtb    = ws + off; off += (size_t)LSEQ * EDIM;
    float* chunkS = ws + off; off += (size_t)NCHUNK * EDIM * NDIM;
    float* sumdt  = ws + off; off += (size_t)NCHUNK * EDIM;
    float* sInit  = ws + off; off += (size_t)NCHUNK * EDIM * NDIM;
    bf16* hnb     = (bf16*)(ws + off); off += (size_t)LSEQ * HDIM / 2;
    bf16* yzb     = (bf16*)(ws + off); off += (size_t)LSEQ * EDIM / 2;
    bf16* ub      = (bf16*)(ws + off); off += (size_t)LSEQ * EDIM / 2;
    bf16* xb      = (bf16*)(ws + off); off += (size_t)LSEQ * SDIM / 2;
    bf16* emb_wb  = (bf16*)(ws + off); off += (size_t)HDIM * SDIM / 2;
    bf16* head_wb = (bf16*)(ws + off); off += (size_t)SDIM * HDIM / 2;
    bf16* in_wb   = (bf16*)(ws + off); off += (size_t)NLAYER * 2 * EDIM * HDIM / 2;
    bf16* out_wb  = (bf16*)(ws + off); off += (size_t)NLAYER * HDIM * EDIM / 2;
    bf16* xwb     = (bf16*)(ws + off); off += (size_t)NLAYER * 80 * EDIM / 2;

    // one launch: all fp32->bf16 conversions
    F2BSegs segs;
    segs.src[0] = x;        segs.dst[0] = xb;      segs.n[0] = LSEQ * SDIM;
    segs.src[1] = emb_w;    segs.dst[1] = emb_wb;  segs.n[1] = HDIM * SDIM;
    segs.src[2] = head_w;   segs.dst[2] = head_wb; segs.n[2] = SDIM * HDIM;
    segs.src[3] = in_proj;  segs.dst[3] = in_wb;   segs.n[3] = NLAYER * 2 * EDIM * HDIM;
    segs.src[4] = out_proj; segs.dst[4] = out_wb;  segs.n[4] = NLAYER * HDIM * EDIM;
    segs.src[5] = x_proj;   segs.dst[5] = xwb;     segs.n[5] = NLAYER * 80 * EDIM;
    f2b_all<<<1024, 256, 0, stream>>>(segs);

    // embed: split-K=2 (Kh=128) -> hpart[2]; 384 blocks
    k_gemm_sk<<<dim3(12, 16, 2), 256, 0, stream>>>(xb, SDIM, emb_wb, SDIM, emb_b,
                                                   hpart, HDIM, SDIM / 2, 1);

    for (int l = 0; l < NLAYER; l++) {
        const bf16*  inw  = in_wb  + (size_t)l * 2 * EDIM * HDIM;
        const bf16*  outw = out_wb + (size_t)l * HDIM * EDIM;
        const bf16*  xwbl = xwb    + (size_t)l * 80 * EDIM;
        const float* cw   = conv_w + (size_t)l * EDIM * KCONV;
        const float* cb   = conv_b + (size_t)l * EDIM;
        const float* dtw  = dt_w   + (size_t)l * EDIM * RDIM;
        const float* dtbb = dt_b   + (size_t)l * EDIM;
        const float* al   = A_log  + (size_t)l * EDIM * NDIM;
        const float* Dpl  = Dp     + (size_t)l * EDIM;

        k_rms<<<LSEQ, 256, 0, stream>>>(hpart, hpart + (size_t)LSEQ * HDIM, res,
                                        hnb, norm_w + (size_t)l * HDIM, l == 0);
        // in_proj: split-K=2 (Kh=384) -> xzpart[2]; 1536 blocks
        k_gemm_sk<<<dim3(48, 16, 2), 256, 0, stream>>>(hnb, HDIM, inw, HDIM, nullptr,
                                                       xzpart, 2 * EDIM, HDIM / 2, 0);
        k_conv<<<1536, 256, 0, stream>>>(xzpart, xzpart + (size_t)LSEQ * 2 * EDIM,
                                         cw, cb, ub);
        k_xproj_mfma<<<dim3(2, 16, XSPLIT), 256, 0, stream>>>(ub, xwbl, part);
        k_dt_red<<<dim3(24, 16), 256, 0, stream>>>(part, dtw, dtbb, dtb, dbc);
        k_scan1<<<6 * NCHUNK, 256, 0, stream>>>(dtb, ub, dbc, al, chunkS, sumdt);
        k_scan2<<<96, 256, 0, stream>>>(chunkS, sumdt, al, sInit);
        k_scan3<<<6 * NCHUNK, 256, 0, stream>>>(dtb, ub, dbc,
                                                xzpart, xzpart + (size_t)LSEQ * 2 * EDIM,
                                                al, Dpl, sInit, yzb);
        // out_proj: split-K=2 (Kh=768) -> hpart[2]; 384 blocks
        k_gemm_sk<<<dim3(12, 16, 2), 256, 0, stream>>>(yzb, EDIM, outw, EDIM, nullptr,
                                                       hpart, HDIM, EDIM / 2, 0);
    }

    // head: A = hpart0 + hpart1, converted to bf16 in staging
    k_gemm_h<<<dim3(4, 16), 256, 0, stream>>>(hpart, hpart + (size_t)LSEQ * HDIM, HDIM,
                                              head_wb, HDIM, head_b, out, SDIM, HDIM);
}

// Round 18
// 361.174 us; speedup vs baseline: 1.3619x; 1.0316x over previous
//
#include <hip/hip_runtime.h>
#include <hip/hip_bf16.h>
#include <math.h>

// Problem dims
#define SDIM 256
#define HDIM 768
#define EDIM 1536
#define NDIM 16
#define KCONV 4
#define RDIM 48
#define NLAYER 2
#define LSEQ 1024

#define NCHUNK 64
#define CHLEN (LSEQ / NCHUNK)   // 16
#define XSPLIT 8
#define XKCH (EDIM / XSPLIT)    // 192

typedef __hip_bfloat16 bf16;
typedef __attribute__((ext_vector_type(8))) short short8;
typedef __attribute__((ext_vector_type(4))) float f32x4;

__device__ __forceinline__ float softplusf(float x) {
    return (x > 20.f) ? x : log1pf(expf(x));
}
__device__ __forceinline__ float siluf(float x) {
    return x / (1.f + expf(-x));
}

// ---------------- combined fp32 -> bf16 conversion: 6 segments, one launch ----------------
struct F2BSegs {
    const float* src[6];
    bf16*        dst[6];
    int          n[6];
};

__global__ __launch_bounds__(256) void f2b_all(F2BSegs segs)
{
    for (int s = 0; s < 6; s++) {
        const float* __restrict__ in = segs.src[s];
        bf16* __restrict__ out = segs.dst[s];
        const int n = segs.n[s];
        for (int i = (blockIdx.x * 256 + threadIdx.x) * 4; i < n; i += gridDim.x * 256 * 4) {
            float4 v = *(const float4*)(in + i);
            out[i + 0] = (bf16)v.x; out[i + 1] = (bf16)v.y;
            out[i + 2] = (bf16)v.z; out[i + 3] = (bf16)v.w;
        }
    }
}

// ---------------- MFMA bf16 GEMM 64x64 tile, split-K=2, fp32 partials (emb, out_proj) ----
__global__ __launch_bounds__(256) void k_gemm_sk(const bf16* __restrict__ A, int lda,
                                                 const bf16* __restrict__ W, int ldw,
                                                 const float* __restrict__ bias,
                                                 float* __restrict__ part,
                                                 int N, int Kh, int useBias)
{
    __shared__ __align__(16) short As[64][72];
    __shared__ __align__(16) short Ws[64][72];

    const int tid  = threadIdx.x;
    const int lane = tid & 63, wid = tid >> 6;
    const int wm = wid >> 1, wn = wid & 1;
    const int row0 = blockIdx.y * 64, col0 = blockIdx.x * 64;
    const int quad = lane >> 4, l16 = lane & 15;
    const int kbase = blockIdx.z * Kh;

    f32x4 acc[2][2] = {};
    for (int k0 = 0; k0 < Kh; k0 += 64) {
        #pragma unroll
        for (int i = 0; i < 2; i++) {
            int id = tid + i * 256;
            int r = id >> 3, g = id & 7;
            *(uint4*)&As[r][g * 8] = *(const uint4*)(A + (size_t)(row0 + r) * lda + kbase + k0 + g * 8);
            *(uint4*)&Ws[r][g * 8] = *(const uint4*)(W + (size_t)(col0 + r) * ldw + kbase + k0 + g * 8);
        }
        __syncthreads();
        #pragma unroll
        for (int ks = 0; ks < 64; ks += 32) {
            short8 af[2], bfr[2];
            #pragma unroll
            for (int i = 0; i < 2; i++) af[i] = *(const short8*)&As[wm * 32 + i * 16 + l16][ks + quad * 8];
            #pragma unroll
            for (int j = 0; j < 2; j++) bfr[j] = *(const short8*)&Ws[wn * 32 + j * 16 + l16][ks + quad * 8];
            #pragma unroll
            for (int i = 0; i < 2; i++)
                #pragma unroll
                for (int j = 0; j < 2; j++)
                    acc[i][j] = __builtin_amdgcn_mfma_f32_16x16x32_bf16(af[i], bfr[j], acc[i][j], 0, 0, 0);
        }
        __syncthreads();
    }
    float* pdst = part + (size_t)blockIdx.z * LSEQ * N;
    #pragma unroll
    for (int i = 0; i < 2; i++) {
        #pragma unroll
        for (int j = 0; j < 2; j++) {
            int gn = col0 + wn * 32 + j * 16 + l16;
            int gm0 = row0 + wm * 32 + i * 16 + quad * 4;
            #pragma unroll
            for (int r = 0; r < 4; r++) {
                float v = acc[i][j][r];
                if (useBias && blockIdx.z == 0) v += bias[gn];
                pdst[(size_t)(gm0 + r) * N + gn] = v;
            }
        }
    }
}

// ---------------- same, but bf16 partials (in_proj: feeds conv/z-gate) ----------------
__global__ __launch_bounds__(256) void k_gemm_skb(const bf16* __restrict__ A, int lda,
                                                  const bf16* __restrict__ W, int ldw,
                                                  bf16* __restrict__ part,
                                                  int N, int Kh)
{
    __shared__ __align__(16) short As[64][72];
    __shared__ __align__(16) short Ws[64][72];

    const int tid  = threadIdx.x;
    const int lane = tid & 63, wid = tid >> 6;
    const int wm = wid >> 1, wn = wid & 1;
    const int row0 = blockIdx.y * 64, col0 = blockIdx.x * 64;
    const int quad = lane >> 4, l16 = lane & 15;
    const int kbase = blockIdx.z * Kh;

    f32x4 acc[2][2] = {};
    for (int k0 = 0; k0 < Kh; k0 += 64) {
        #pragma unroll
        for (int i = 0; i < 2; i++) {
            int id = tid + i * 256;
            int r = id >> 3, g = id & 7;
            *(uint4*)&As[r][g * 8] = *(const uint4*)(A + (size_t)(row0 + r) * lda + kbase + k0 + g * 8);
            *(uint4*)&Ws[r][g * 8] = *(const uint4*)(W + (size_t)(col0 + r) * ldw + kbase + k0 + g * 8);
        }
        __syncthreads();
        #pragma unroll
        for (int ks = 0; ks < 64; ks += 32) {
            short8 af[2], bfr[2];
            #pragma unroll
            for (int i = 0; i < 2; i++) af[i] = *(const short8*)&As[wm * 32 + i * 16 + l16][ks + quad * 8];
            #pragma unroll
            for (int j = 0; j < 2; j++) bfr[j] = *(const short8*)&Ws[wn * 32 + j * 16 + l16][ks + quad * 8];
            #pragma unroll
            for (int i = 0; i < 2; i++)
                #pragma unroll
                for (int j = 0; j < 2; j++)
                    acc[i][j] = __builtin_amdgcn_mfma_f32_16x16x32_bf16(af[i], bfr[j], acc[i][j], 0, 0, 0);
        }
        __syncthreads();
    }
    bf16* pdst = part + (size_t)blockIdx.z * LSEQ * N;
    #pragma unroll
    for (int i = 0; i < 2; i++) {
        #pragma unroll
        for (int j = 0; j < 2; j++) {
            int gn = col0 + wn * 32 + j * 16 + l16;
            int gm0 = row0 + wm * 32 + i * 16 + quad * 4;
            #pragma unroll
            for (int r = 0; r < 4; r++)
                pdst[(size_t)(gm0 + r) * N + gn] = (bf16)acc[i][j][r];
        }
    }
}

// ---------------- head GEMM: A = sum of two fp32 partials, converted to bf16 in staging ----
__global__ __launch_bounds__(256) void k_gemm_h(const float* __restrict__ A0,
                                                const float* __restrict__ A1, int lda,
                                                const bf16* __restrict__ W, int ldw,
                                                const float* __restrict__ bias,
                                                float* __restrict__ out, int N, int Kd)
{
    __shared__ __align__(16) short As[64][72];
    __shared__ __align__(16) short Ws[64][72];

    const int tid  = threadIdx.x;
    const int lane = tid & 63, wid = tid >> 6;
    const int wm = wid >> 1, wn = wid & 1;
    const int row0 = blockIdx.y * 64, col0 = blockIdx.x * 64;
    const int quad = lane >> 4, l16 = lane & 15;

    f32x4 acc[2][2] = {};
    for (int k0 = 0; k0 < Kd; k0 += 64) {
        #pragma unroll
        for (int i = 0; i < 2; i++) {
            int id = tid + i * 256;
            int r = id >> 3, g = id & 7;
            size_t base = (size_t)(row0 + r) * lda + k0 + g * 8;
            float4 a0 = *(const float4*)(A0 + base);
            float4 a1 = *(const float4*)(A0 + base + 4);
            float4 b0 = *(const float4*)(A1 + base);
            float4 b1 = *(const float4*)(A1 + base + 4);
            bf16 tmp[8] = {(bf16)(a0.x + b0.x), (bf16)(a0.y + b0.y),
                           (bf16)(a0.z + b0.z), (bf16)(a0.w + b0.w),
                           (bf16)(a1.x + b1.x), (bf16)(a1.y + b1.y),
                           (bf16)(a1.z + b1.z), (bf16)(a1.w + b1.w)};
            *(uint4*)&As[r][g * 8] = *(const uint4*)tmp;
            *(uint4*)&Ws[r][g * 8] = *(const uint4*)(W + (size_t)(col0 + r) * ldw + k0 + g * 8);
        }
        __syncthreads();
        #pragma unroll
        for (int ks = 0; ks < 64; ks += 32) {
            short8 af[2], bfr[2];
            #pragma unroll
            for (int i = 0; i < 2; i++) af[i] = *(const short8*)&As[wm * 32 + i * 16 + l16][ks + quad * 8];
            #pragma unroll
            for (int j = 0; j < 2; j++) bfr[j] = *(const short8*)&Ws[wn * 32 + j * 16 + l16][ks + quad * 8];
            #pragma unroll
            for (int i = 0; i < 2; i++)
                #pragma unroll
                for (int j = 0; j < 2; j++)
                    acc[i][j] = __builtin_amdgcn_mfma_f32_16x16x32_bf16(af[i], bfr[j], acc[i][j], 0, 0, 0);
        }
        __syncthreads();
    }
    #pragma unroll
    for (int i = 0; i < 2; i++) {
        #pragma unroll
        for (int j = 0; j < 2; j++) {
            int gn = col0 + wn * 32 + j * 16 + l16;
            int gm0 = row0 + wm * 32 + i * 16 + quad * 4;
            #pragma unroll
            for (int r = 0; r < 4; r++)
                out[(size_t)(gm0 + r) * N + gn] = acc[i][j][r] + bias[gn];
        }
    }
}

// ---------------- conv + silu: xin = bf16 partials p0+p1; writes ub ----------------
__global__ __launch_bounds__(256) void k_conv(const bf16* __restrict__ xzp0,
                                              const bf16* __restrict__ xzp1,
                                              const float* __restrict__ cw,
                                              const float* __restrict__ cb,
                                              bf16* __restrict__ ub)
{
    const int NG = LSEQ * EDIM / 4;
    for (int g = blockIdx.x * 256 + threadIdx.x; g < NG; g += gridDim.x * 256) {
        int t = g / (EDIM / 4);
        int e4 = (g - t * (EDIM / 4)) * 4;
        float4 s = *(const float4*)(cb + e4);
        #pragma unroll
        for (int k = 0; k < KCONV; k++) {
            int tt = t - (KCONV - 1) + k;
            if (tt >= 0) {
                size_t o = (size_t)tt * (2 * EDIM) + e4;
                const bf16* pa = xzp0 + o;
                const bf16* pb = xzp1 + o;
                s.x += cw[(e4 + 0) * KCONV + k] * ((float)pa[0] + (float)pb[0]);
                s.y += cw[(e4 + 1) * KCONV + k] * ((float)pa[1] + (float)pb[1]);
                s.z += cw[(e4 + 2) * KCONV + k] * ((float)pa[2] + (float)pb[2]);
                s.w += cw[(e4 + 3) * KCONV + k] * ((float)pa[3] + (float)pb[3]);
            }
        }
        bf16 tmp[4] = {(bf16)siluf(s.x), (bf16)siluf(s.y), (bf16)siluf(s.z), (bf16)siluf(s.w)};
        *(uint2*)(ub + (size_t)t * EDIM + e4) = *(const uint2*)tmp;
    }
}

// ---------------- x_proj: bf16 MFMA 64-tile, split-K=8, fp32 partials ----------------
__global__ __launch_bounds__(256) void k_xproj_mfma(
    const bf16* __restrict__ A,
    const bf16* __restrict__ W,
    float* __restrict__ part)
{
    __shared__ __align__(16) short As[64][72];
    __shared__ __align__(16) short Ws[64][72];

    const int tid  = threadIdx.x;
    const int lane = tid & 63, wid = tid >> 6;
    const int wm = wid >> 1, wn = wid & 1;
    const int row0 = blockIdx.y * 64, col0 = blockIdx.x * 64;
    const int quad = lane >> 4, l16 = lane & 15;
    const int kbase = blockIdx.z * XKCH;

    f32x4 acc[2][2] = {};
    for (int k0 = 0; k0 < XKCH; k0 += 64) {
        #pragma unroll
        for (int i = 0; i < 2; i++) {
            int id = tid + i * 256;
            int r = id >> 3, g = id & 7;
            *(uint4*)&As[r][g * 8] =
                *(const uint4*)(A + (size_t)(row0 + r) * EDIM + kbase + k0 + g * 8);
            uint4 wv = {0, 0, 0, 0};
            if (col0 + r < 80)
                wv = *(const uint4*)(W + (size_t)(col0 + r) * EDIM + kbase + k0 + g * 8);
            *(uint4*)&Ws[r][g * 8] = wv;
        }
        __syncthreads();
        #pragma unroll
        for (int ks = 0; ks < 64; ks += 32) {
            short8 af[2], bfr[2];
            #pragma unroll
            for (int i = 0; i < 2; i++) af[i] = *(const short8*)&As[wm * 32 + i * 16 + l16][ks + quad * 8];
            #pragma unroll
            for (int j = 0; j < 2; j++) bfr[j] = *(const short8*)&Ws[wn * 32 + j * 16 + l16][ks + quad * 8];
            #pragma unroll
            for (int i = 0; i < 2; i++)
                #pragma unroll
                for (int j = 0; j < 2; j++)
                    acc[i][j] = __builtin_amdgcn_mfma_f32_16x16x32_bf16(af[i], bfr[j], acc[i][j], 0, 0, 0);
        }
        __syncthreads();
    }

    float* pdst = part + (size_t)blockIdx.z * (LSEQ * 80);
    #pragma unroll
    for (int i = 0; i < 2; i++) {
        #pragma unroll
        for (int j = 0; j < 2; j++) {
            int gn = col0 + wn * 32 + j * 16 + l16;
            int gm0 = row0 + wm * 32 + i * 16 + quad * 4;
            if (gn < 80) {
                #pragma unroll
                for (int r = 0; r < 4; r++)
                    pdst[(size_t)(gm0 + r) * 80 + gn] = acc[i][j][r];
            }
        }
    }
}

// ---------------- dt GEMM fused with split-K reduce ----------------
__global__ __launch_bounds__(256) void k_dt_red(
    const float* __restrict__ part, const float* __restrict__ dtw,
    const float* __restrict__ dtbb, float* __restrict__ out,
    float* __restrict__ dbc)
{
    __shared__ float AsF[16][68];
    __shared__ float WsF[16][68];
    const int tid = threadIdx.x;
    const int tx = tid & 15, ty = tid >> 4;
    const int tx4 = tx * 4, ty4 = ty * 4;
    const int row0 = blockIdx.y * 64, col0 = blockIdx.x * 64;

    if (blockIdx.x == 0) {
        for (int idx = tid; idx < 64 * 32; idx += 256) {
            int m = idx >> 5, c = 48 + (idx & 31);
            size_t o = (size_t)(row0 + m) * 80 + c;
            float s = 0.f;
            #pragma unroll
            for (int p = 0; p < XSPLIT; p++) s += part[(size_t)p * (LSEQ * 80) + o];
            dbc[o] = s;
        }
    }

    float acc[4][4] = {};
    for (int k0 = 0; k0 < RDIM; k0 += 16) {
        #pragma unroll
        for (int i = 0; i < 4; i++) {
            int idx = tid + i * 256;
            int m = idx >> 4, kk = idx & 15;
            size_t o = (size_t)(row0 + m) * 80 + k0 + kk;
            float s = 0.f;
            #pragma unroll
            for (int p = 0; p < XSPLIT; p++) s += part[(size_t)p * (LSEQ * 80) + o];
            AsF[kk][m] = s;
        }
        #pragma unroll
        for (int i = 0; i < 4; i++) {
            int idx = tid + i * 256;
            int nn = idx >> 4, kk = idx & 15;
            WsF[kk][nn] = dtw[(size_t)(col0 + nn) * RDIM + k0 + kk];
        }
        __syncthreads();
        #pragma unroll
        for (int kk = 0; kk < 16; kk++) {
            float av[4], bv[4];
            #pragma unroll
            for (int i = 0; i < 4; i++) av[i] = AsF[kk][ty4 + i];
            #pragma unroll
            for (int j = 0; j < 4; j++) bv[j] = WsF[kk][tx4 + j];
            #pragma unroll
            for (int i = 0; i < 4; i++)
                #pragma unroll
                for (int j = 0; j < 4; j++)
                    acc[i][j] += av[i] * bv[j];
        }
        __syncthreads();
    }
    #pragma unroll
    for (int i = 0; i < 4; i++) {
        int gm = row0 + ty4 + i;
        #pragma unroll
        for (int j = 0; j < 4; j++) {
            int gn = col0 + tx4 + j;
            float v = acc[i][j] + dtbb[gn];
            out[(size_t)gm * EDIM + gn] = softplusf(v);
        }
    }
}

// ---------------- residual + rmsnorm (h = h0 + h1 split-K partials) ----------------
__global__ __launch_bounds__(256) void k_rms(const float* __restrict__ h0,
                                             const float* __restrict__ h1,
                                             float* __restrict__ res,
                                             bf16* __restrict__ hnb, const float* __restrict__ w,
                                             int first)
{
    __shared__ float red[4];
    __shared__ float tot;
    const int tid = threadIdx.x;
    const int t = blockIdx.x;
    float v[3]; float ss = 0.f;
    #pragma unroll
    for (int r = 0; r < 3; r++) {
        int j = tid + r * 256;
        float xv = h0[(size_t)t * HDIM + j] + h1[(size_t)t * HDIM + j];
        if (!first) xv += res[(size_t)t * HDIM + j];
        v[r] = xv;
        res[(size_t)t * HDIM + j] = xv;
        ss += xv * xv;
    }
    #pragma unroll
    for (int m = 32; m >= 1; m >>= 1) ss += __shfl_down(ss, m);
    int wid = tid >> 6;
    if ((tid & 63) == 0) red[wid] = ss;
    __syncthreads();
    if (tid == 0) tot = red[0] + red[1] + red[2] + red[3];
    __syncthreads();
    float scale = rsqrtf(tot / (float)HDIM + 1e-5f);
    #pragma unroll
    for (int r = 0; r < 3; r++) {
        int j = tid + r * 256;
        hnb[(size_t)t * HDIM + j] = (bf16)(v[r] * scale * w[j]);
    }
}

// ---------------- selective scan (thread per e, 16 states in regs; u in bf16) ----------
__global__ __launch_bounds__(256) void k_scan1(const float* __restrict__ dt,
                                               const bf16* __restrict__ ub,
                                               const float* __restrict__ dbc,
                                               const float* __restrict__ a_log,
                                               float* __restrict__ chunkS,
                                               float* __restrict__ sumdt)
{
    const int ex = blockIdx.x % 6, c = blockIdx.x / 6;
    const int e = ex * 256 + threadIdx.x;
    float A[16];
    #pragma unroll
    for (int q = 0; q < 4; q++) {
        float4 a4 = *(const float4*)(a_log + e * NDIM + q * 4);
        A[q*4+0] = -__expf(a4.x); A[q*4+1] = -__expf(a4.y);
        A[q*4+2] = -__expf(a4.z); A[q*4+3] = -__expf(a4.w);
    }
    float s[16] = {};
    float sd = 0.f;
    const int t0 = c * CHLEN;
    #pragma unroll 2
    for (int tt = 0; tt < CHLEN; tt++) {
        int t = t0 + tt;
        float dtv = dt[(size_t)t * EDIM + e];
        float uv  = (float)ub[(size_t)t * EDIM + e];
        float dtu = dtv * uv;
        sd += dtv;
        float4 B4[4];
        #pragma unroll
        for (int q = 0; q < 4; q++) B4[q] = *(const float4*)(dbc + (size_t)t * 80 + RDIM + q * 4);
        const float* B = (const float*)B4;
        #pragma unroll
        for (int n = 0; n < 16; n++) s[n] = s[n] * __expf(dtv * A[n]) + dtu * B[n];
    }
    float* cs = chunkS + ((size_t)c * EDIM + e) * NDIM;
    #pragma unroll
    for (int q = 0; q < 4; q++)
        *(float4*)(cs + q * 4) = make_float4(s[q*4+0], s[q*4+1], s[q*4+2], s[q*4+3]);
    sumdt[(size_t)c * EDIM + e] = sd;
}

__global__ __launch_bounds__(256) void k_scan2(const float* __restrict__ chunkS,
                                               const float* __restrict__ sumdt,
                                               const float* __restrict__ a_log,
                                               float* __restrict__ sInit)
{
    int gid = blockIdx.x * 256 + threadIdx.x;
    if (gid >= EDIM * NDIM) return;
    int n = gid & 15, e = gid >> 4;
    const float Aen = -__expf(a_log[gid]);
    float s = 0.f;
    for (int c = 0; c < NCHUNK; c++) {
        sInit[((size_t)c * EDIM + e) * NDIM + n] = s;
        float P = __expf(Aen * sumdt[(size_t)c * EDIM + e]);
        s = s * P + chunkS[((size_t)c * EDIM + e) * NDIM + n];
    }
}

__global__ __launch_bounds__(256) void k_scan3(const float* __restrict__ dt,
                                               const bf16* __restrict__ ub,
                                               const float* __restrict__ dbc,
                                               const bf16* __restrict__ xzp0,
                                               const bf16* __restrict__ xzp1,
                                               const float* __restrict__ a_log,
                                               const float* __restrict__ Dp,
                                               const float* __restrict__ sInit,
                                               bf16* __restrict__ yzb)
{
    const int ex = blockIdx.x % 6, c = blockIdx.x / 6;
    const int e = ex * 256 + threadIdx.x;
    float A[16];
    #pragma unroll
    for (int q = 0; q < 4; q++) {
        float4 a4 = *(const float4*)(a_log + e * NDIM + q * 4);
        A[q*4+0] = -__expf(a4.x); A[q*4+1] = -__expf(a4.y);
        A[q*4+2] = -__expf(a4.z); A[q*4+3] = -__expf(a4.w);
    }
    const float dv = Dp[e];
    float s[16];
    const float* si = sInit + ((size_t)c * EDIM + e) * NDIM;
    #pragma unroll
    for (int q = 0; q < 4; q++) {
        float4 s4 = *(const float4*)(si + q * 4);
        s[q*4+0] = s4.x; s[q*4+1] = s4.y; s[q*4+2] = s4.z; s[q*4+3] = s4.w;
    }
    const int t0 = c * CHLEN;
    #pragma unroll 2
    for (int tt = 0; tt < CHLEN; tt++) {
        int t = t0 + tt;
        float dtv = dt[(size_t)t * EDIM + e];
        float uv  = (float)ub[(size_t)t * EDIM + e];
        size_t zo = (size_t)t * (2 * EDIM) + EDIM + e;
        float zv  = (float)xzp0[zo] + (float)xzp1[zo];
        float dtu = dtv * uv;
        float4 B4[4], C4[4];
        #pragma unroll
        for (int q = 0; q < 4; q++) {
            B4[q] = *(const float4*)(dbc + (size_t)t * 80 + RDIM + q * 4);
            C4[q] = *(const float4*)(dbc + (size_t)t * 80 + RDIM + NDIM + q * 4);
        }
        const float* B = (const float*)B4;
        const float* C = (const float*)C4;
        float y = 0.f;
        #pragma unroll
        for (int n = 0; n < 16; n++) {
            s[n] = s[n] * __expf(dtv * A[n]) + dtu * B[n];
            y += s[n] * C[n];
        }
        y += uv * dv;
        yzb[(size_t)t * EDIM + e] = (bf16)(y * siluf(zv));
    }
}

extern "C" void kernel_launch(void* const* d_in, const int* in_sizes, int n_in,
                              void* d_out, int out_size, void* d_ws, size_t ws_size,
                              hipStream_t stream)
{
    const float* x        = (const float*)d_in[0];
    const float* emb_w    = (const float*)d_in[1];
    const float* emb_b    = (const float*)d_in[2];
    const float* norm_w   = (const float*)d_in[3];
    const float* in_proj  = (const float*)d_in[4];
    const float* conv_w   = (const float*)d_in[5];
    const float* conv_b   = (const float*)d_in[6];
    const float* x_proj   = (const float*)d_in[7];
    const float* dt_w     = (const float*)d_in[8];
    const float* dt_b     = (const float*)d_in[9];
    const float* A_log    = (const float*)d_in[10];
    const float* Dp       = (const float*)d_in[11];
    const float* out_proj = (const float*)d_in[12];
    const float* head_w   = (const float*)d_in[13];
    const float* head_b   = (const float*)d_in[14];
    float* out = (float*)d_out;

    float* ws = (float*)d_ws;
    size_t off = 0;
    float* hpart  = ws + off; off += (size_t)2 * LSEQ * HDIM;      // emb/out_proj fp32 partials
    float* res    = ws + off; off += (size_t)LSEQ * HDIM;
    float* dbc    = ws + off; off += (size_t)LSEQ * 80;
    float* part   = ws + off; off += (size_t)XSPLIT * LSEQ * 80;
    float* dtb    = ws + off; off += (size_t)LSEQ * EDIM;
    float* chunkS = ws + off; off += (size_t)NCHUNK * EDIM * NDIM;
    float* sumdt  = ws + off; off += (size_t)NCHUNK * EDIM;
    float* sInit  = ws + off; off += (size_t)NCHUNK * EDIM * NDIM;
    bf16* xzpart  = (bf16*)(ws + off); off += (size_t)2 * LSEQ * 2 * EDIM / 2;  // in_proj bf16 partials
    bf16* hnb     = (bf16*)(ws + off); off += (size_t)LSEQ * HDIM / 2;
    bf16* yzb     = (bf16*)(ws + off); off += (size_t)LSEQ * EDIM / 2;
    bf16* ub      = (bf16*)(ws + off); off += (size_t)LSEQ * EDIM / 2;
    bf16* xb      = (bf16*)(ws + off); off += (size_t)LSEQ * SDIM / 2;
    bf16* emb_wb  = (bf16*)(ws + off); off += (size_t)HDIM * SDIM / 2;
    bf16* head_wb = (bf16*)(ws + off); off += (size_t)SDIM * HDIM / 2;
    bf16* in_wb   = (bf16*)(ws + off); off += (size_t)NLAYER * 2 * EDIM * HDIM / 2;
    bf16* out_wb  = (bf16*)(ws + off); off += (size_t)NLAYER * HDIM * EDIM / 2;
    bf16* xwb     = (bf16*)(ws + off); off += (size_t)NLAYER * 80 * EDIM / 2;

    // one launch: all fp32->bf16 conversions
    F2BSegs segs;
    segs.src[0] = x;        segs.dst[0] = xb;      segs.n[0] = LSEQ * SDIM;
    segs.src[1] = emb_w;    segs.dst[1] = emb_wb;  segs.n[1] = HDIM * SDIM;
    segs.src[2] = head_w;   segs.dst[2] = head_wb; segs.n[2] = SDIM * HDIM;
    segs.src[3] = in_proj;  segs.dst[3] = in_wb;   segs.n[3] = NLAYER * 2 * EDIM * HDIM;
    segs.src[4] = out_proj; segs.dst[4] = out_wb;  segs.n[4] = NLAYER * HDIM * EDIM;
    segs.src[5] = x_proj;   segs.dst[5] = xwb;     segs.n[5] = NLAYER * 80 * EDIM;
    f2b_all<<<1024, 256, 0, stream>>>(segs);

    // embed: split-K=2 (Kh=128) -> hpart[2]; 384 blocks
    k_gemm_sk<<<dim3(12, 16, 2), 256, 0, stream>>>(xb, SDIM, emb_wb, SDIM, emb_b,
                                                   hpart, HDIM, SDIM / 2, 1);

    for (int l = 0; l < NLAYER; l++) {
        const bf16*  inw  = in_wb  + (size_t)l * 2 * EDIM * HDIM;
        const bf16*  outw = out_wb + (size_t)l * HDIM * EDIM;
        const bf16*  xwbl = xwb    + (size_t)l * 80 * EDIM;
        const float* cw   = conv_w + (size_t)l * EDIM * KCONV;
        const float* cb   = conv_b + (size_t)l * EDIM;
        const float* dtw  = dt_w   + (size_t)l * EDIM * RDIM;
        const float* dtbb = dt_b   + (size_t)l * EDIM;
        const float* al   = A_log  + (size_t)l * EDIM * NDIM;
        const float* Dpl  = Dp     + (size_t)l * EDIM;

        k_rms<<<LSEQ, 256, 0, stream>>>(hpart, hpart + (size_t)LSEQ * HDIM, res,
                                        hnb, norm_w + (size_t)l * HDIM, l == 0);
        // in_proj: split-K=2 (Kh=384) -> bf16 partials xzpart[2]; 1536 blocks
        k_gemm_skb<<<dim3(48, 16, 2), 256, 0, stream>>>(hnb, HDIM, inw, HDIM,
                                                        xzpart, 2 * EDIM, HDIM / 2);
        k_conv<<<1536, 256, 0, stream>>>(xzpart, xzpart + (size_t)LSEQ * 2 * EDIM,
                                         cw, cb, ub);
        // xproj: split-K=8 -> 256 blocks
        k_xproj_mfma<<<dim3(2, 16, XSPLIT), 256, 0, stream>>>(ub, xwbl, part);
        k_dt_red<<<dim3(24, 16), 256, 0, stream>>>(part, dtw, dtbb, dtb, dbc);
        k_scan1<<<6 * NCHUNK, 256, 0, stream>>>(dtb, ub, dbc, al, chunkS, sumdt);
        k_scan2<<<96, 256, 0, stream>>>(chunkS, sumdt, al, sInit);
        k_scan3<<<6 * NCHUNK, 256, 0, stream>>>(dtb, ub, dbc,
                                                xzpart, xzpart + (size_t)LSEQ * 2 * EDIM,
                                                al, Dpl, sInit, yzb);
        // out_proj: split-K=2 (Kh=768) -> hpart[2]; 384 blocks
        k_gemm_sk<<<dim3(12, 16, 2), 256, 0, stream>>>(yzb, EDIM, outw, EDIM, nullptr,
                                                       hpart, HDIM, EDIM / 2, 0);
    }

    // head: A = hpart0 + hpart1, converted to bf16 in staging
    k_gemm_h<<<dim3(4, 16), 256, 0, stream>>>(hpart, hpart + (size_t)LSEQ * HDIM, HDIM,
                                              head_wb, HDIM, head_b, out, SDIM, HDIM);
}